// Round 1
// baseline (5829.341 us; speedup 1.0000x reference)
//
#include <hip/hip_runtime.h>

// TAGConv L3: N=100000 nodes, E=3200000 edges, K=3 hops
// dims: (16->128)(128->128)(128->128)(128->4), ReLU between, fp32 throughout.

#define WN 100000
#define WE 3200000

// ---------------- degree / norm ----------------
__global__ void k_edge_deg(const int* __restrict__ src, const int* __restrict__ dst,
                           const float* __restrict__ ew, float* __restrict__ deg,
                           int* __restrict__ count, int E) {
    int stride = gridDim.x * blockDim.x;
    for (int e = blockIdx.x * blockDim.x + threadIdx.x; e < E; e += stride) {
        int d = dst[e];
        atomicAdd(&deg[d], ew[e]);
        atomicAdd(&count[d], 1);
    }
}

__global__ void k_dis(float* deg, int N) {
    int i = blockIdx.x * blockDim.x + threadIdx.x;
    if (i < N) { float d = deg[i]; deg[i] = d > 0.f ? rsqrtf(d) : 0.f; }
}

// ---------------- scan for row_ptr (3-phase) ----------------
__global__ void k_scan1(const int* __restrict__ count, int* __restrict__ bsum, int N) {
    __shared__ int s[256];
    int tid = threadIdx.x;
    int base = blockIdx.x * 1024 + tid * 4;
    int t = 0;
    #pragma unroll
    for (int i = 0; i < 4; ++i) { int idx = base + i; if (idx < N) t += count[idx]; }
    s[tid] = t; __syncthreads();
    for (int off = 128; off > 0; off >>= 1) {
        if (tid < off) s[tid] += s[tid + off];
        __syncthreads();
    }
    if (tid == 0) bsum[blockIdx.x] = s[0];
}

__global__ void k_scan2(const int* __restrict__ bsum, int* __restrict__ boff,
                        int nb, int* __restrict__ row_ptr_last) {
    if (threadIdx.x == 0) {
        int run = 0;
        for (int i = 0; i < nb; ++i) { boff[i] = run; run += bsum[i]; }
        *row_ptr_last = run;
    }
}

__global__ void k_scan3(const int* __restrict__ count, const int* __restrict__ boff,
                        int* __restrict__ row_ptr, int N) {
    __shared__ int s[256];
    int tid = threadIdx.x;
    int base = blockIdx.x * 1024 + tid * 4;
    int v[4]; int t = 0;
    #pragma unroll
    for (int i = 0; i < 4; ++i) { int idx = base + i; v[i] = (idx < N) ? count[idx] : 0; t += v[i]; }
    s[tid] = t; __syncthreads();
    for (int off = 1; off < 256; off <<= 1) {
        int add = (tid >= off) ? s[tid - off] : 0;
        __syncthreads();
        s[tid] += add;
        __syncthreads();
    }
    int g = boff[blockIdx.x] + (s[tid] - t);   // exclusive prefix
    #pragma unroll
    for (int i = 0; i < 4; ++i) { int idx = base + i; if (idx < N) row_ptr[idx] = g; g += v[i]; }
}

__global__ void k_copy_int(const int* __restrict__ a, int* __restrict__ b, int n) {
    int i = blockIdx.x * blockDim.x + threadIdx.x;
    if (i < n) b[i] = a[i];
}

__global__ void k_fill_csr(const int* __restrict__ src, const int* __restrict__ dst,
                           const float* __restrict__ ew, const float* __restrict__ dis,
                           int* __restrict__ cursor, int* __restrict__ csr_src,
                           float* __restrict__ csr_w, int E) {
    int stride = gridDim.x * blockDim.x;
    for (int e = blockIdx.x * blockDim.x + threadIdx.x; e < E; e += stride) {
        int d = dst[e];
        int s = src[e];
        int pos = atomicAdd(&cursor[d], 1);
        csr_src[pos] = s;
        csr_w[pos] = dis[s] * ew[e] * dis[d];
    }
}

// ---------------- propagation: h_out[n] = sum_e w_e * h_in[src_e] ----------------
template <int DIN>
__global__ __launch_bounds__(128) void k_prop(const float* __restrict__ hin,
                                              float* __restrict__ hout,
                                              const int* __restrict__ row_ptr,
                                              const int* __restrict__ csr_src,
                                              const float* __restrict__ csr_w, int N) {
    constexpr int NPB = 128 / DIN;
    int node = blockIdx.x * NPB + threadIdx.x / DIN;
    int f = threadIdx.x % DIN;
    if (node >= N) return;
    int s = row_ptr[node], e = row_ptr[node + 1];
    float acc = 0.f;
    for (int i = s; i < e; ++i) {
        acc += csr_w[i] * hin[(size_t)csr_src[i] * DIN + f];
    }
    hout[(size_t)node * DIN + f] = acc;
}

// ---------------- GEMM: C(MxNc) (+)= A(MxK) @ B(KxNc), BM=BN=64, BK=16 ----------------
template <bool ACCUM>
__global__ __launch_bounds__(256) void k_gemm(const float* __restrict__ A,
                                              const float* __restrict__ B,
                                              float* __restrict__ C,
                                              int M, int K, int Nc) {
    __shared__ float As[16][68];
    __shared__ float Bs[16][68];
    int tid = threadIdx.x;
    int row0 = blockIdx.x * 64, col0 = blockIdx.y * 64;
    int arow = tid >> 2, ac4 = (tid & 3) * 4;
    int bk = tid >> 4, bc4 = (tid & 15) * 4;
    int m0 = (tid >> 4) * 4, n0 = (tid & 15) * 4;
    float acc[4][4] = {};
    for (int kt = 0; kt < K; kt += 16) {
        // A tile 64x16 -> As[k][m] (transposed)
        {
            int gr = row0 + arow;
            float4 v = make_float4(0.f, 0.f, 0.f, 0.f);
            if (gr < M) v = *reinterpret_cast<const float4*>(&A[(size_t)gr * K + kt + ac4]);
            As[ac4 + 0][arow] = v.x; As[ac4 + 1][arow] = v.y;
            As[ac4 + 2][arow] = v.z; As[ac4 + 3][arow] = v.w;
        }
        // B tile 16x64
        {
            float4 v = *reinterpret_cast<const float4*>(&B[(size_t)(kt + bk) * Nc + col0 + bc4]);
            Bs[bk][bc4 + 0] = v.x; Bs[bk][bc4 + 1] = v.y;
            Bs[bk][bc4 + 2] = v.z; Bs[bk][bc4 + 3] = v.w;
        }
        __syncthreads();
        #pragma unroll
        for (int kk = 0; kk < 16; ++kk) {
            float a0 = As[kk][m0], a1 = As[kk][m0 + 1], a2 = As[kk][m0 + 2], a3 = As[kk][m0 + 3];
            float b0 = Bs[kk][n0], b1 = Bs[kk][n0 + 1], b2 = Bs[kk][n0 + 2], b3 = Bs[kk][n0 + 3];
            acc[0][0] += a0 * b0; acc[0][1] += a0 * b1; acc[0][2] += a0 * b2; acc[0][3] += a0 * b3;
            acc[1][0] += a1 * b0; acc[1][1] += a1 * b1; acc[1][2] += a1 * b2; acc[1][3] += a1 * b3;
            acc[2][0] += a2 * b0; acc[2][1] += a2 * b1; acc[2][2] += a2 * b2; acc[2][3] += a2 * b3;
            acc[3][0] += a3 * b0; acc[3][1] += a3 * b1; acc[3][2] += a3 * b2; acc[3][3] += a3 * b3;
        }
        __syncthreads();
    }
    #pragma unroll
    for (int i = 0; i < 4; ++i) {
        int gr = row0 + m0 + i;
        if (gr < M) {
            #pragma unroll
            for (int j = 0; j < 4; ++j) {
                size_t idx = (size_t)gr * Nc + col0 + n0 + j;
                C[idx] = (ACCUM ? C[idx] : 0.f) + acc[i][j];
            }
        }
    }
}

// ---------------- small-N GEMM: C(Mx4) (+)= A(Mx128) @ B(128x4) ----------------
template <bool ACCUM>
__global__ __launch_bounds__(256) void k_gemm_n4(const float* __restrict__ A,
                                                 const float* __restrict__ B,
                                                 float* __restrict__ C, int M) {
    __shared__ float hs[64][132];
    __shared__ float ws[512];
    int tid = threadIdx.x;
    int row0 = blockIdx.x * 64;
    for (int i = tid; i < 512; i += 256) ws[i] = B[i];
    #pragma unroll
    for (int it = 0; it < 8; ++it) {
        int f4 = it * 256 + tid;      // 0..2047 float4 index in 64x128 tile
        int r = f4 >> 5;
        int c4 = (f4 & 31) * 4;
        int gr = row0 + r;
        float4 v = make_float4(0.f, 0.f, 0.f, 0.f);
        if (gr < M) v = *reinterpret_cast<const float4*>(&A[(size_t)gr * 128 + c4]);
        hs[r][c4] = v.x; hs[r][c4 + 1] = v.y; hs[r][c4 + 2] = v.z; hs[r][c4 + 3] = v.w;
    }
    __syncthreads();
    int r = tid >> 2, j = tid & 3;
    float acc = 0.f;
    #pragma unroll 8
    for (int i = 0; i < 128; ++i) acc += hs[r][i] * ws[i * 4 + j];
    int gr = row0 + r;
    if (gr < M) {
        size_t idx = (size_t)gr * 4 + j;
        C[idx] = (ACCUM ? C[idx] : 0.f) + acc;
    }
}

// ---------------- epilogues ----------------
__global__ void k_bias_relu(const float* __restrict__ O, const float* __restrict__ b,
                            float* __restrict__ out, int total, int D) {
    int i = blockIdx.x * blockDim.x + threadIdx.x;
    if (i < total) out[i] = fmaxf(O[i] + b[i % D], 0.f);
}

__global__ void k_bias(const float* __restrict__ O, const float* __restrict__ b,
                       float* __restrict__ out, int total, int D) {
    int i = blockIdx.x * blockDim.x + threadIdx.x;
    if (i < total) out[i] = O[i] + b[i % D];
}

// ---------------- launch ----------------
extern "C" void kernel_launch(void* const* d_in, const int* in_sizes, int n_in,
                              void* d_out, int out_size, void* d_ws, size_t ws_size,
                              hipStream_t stream) {
    const float* x  = (const float*)d_in[0];
    const int*   ei = (const int*)d_in[1];
    const float* ew = (const float*)d_in[2];
    const float* W0 = (const float*)d_in[3];
    const float* b0 = (const float*)d_in[4];
    const float* W1 = (const float*)d_in[5];
    const float* b1 = (const float*)d_in[6];
    const float* W2 = (const float*)d_in[7];
    const float* b2 = (const float*)d_in[8];
    const float* W3 = (const float*)d_in[9];
    const float* b3 = (const float*)d_in[10];
    float* out = (float*)d_out;

    const int N = in_sizes[0] / 16;   // 100000
    const int E = in_sizes[2];        // 3200000
    const int* src = ei;
    const int* dst = ei + E;

    // workspace layout
    char* ws = (char*)d_ws;
    size_t off = 0;
    auto take = [&](size_t bytes) -> void* {
        void* p = ws + off;
        off = (off + bytes + 255) & ~(size_t)255;
        return p;
    };
    float* P       = (float*)take((size_t)N * 128 * 4);
    float* Q       = (float*)take((size_t)N * 128 * 4);
    float* O       = (float*)take((size_t)N * 128 * 4);
    int*   csr_src = (int*)  take((size_t)E * 4);
    float* csr_w   = (float*)take((size_t)E * 4);
    float* dis     = (float*)take((size_t)N * 4);   // deg, then rsqrt in place
    int*   count   = (int*)  take((size_t)N * 4);
    int*   row_ptr = (int*)  take((size_t)(N + 1) * 4);
    int*   cursor  = (int*)  take((size_t)N * 4);
    int*   bsum    = (int*)  take(1024);
    int*   boff    = (int*)  take(1024);

    // ---- build norm + CSR ----
    hipMemsetAsync(dis,   0, (size_t)N * 4, stream);
    hipMemsetAsync(count, 0, (size_t)N * 4, stream);
    k_edge_deg<<<2048, 256, 0, stream>>>(src, dst, ew, dis, count, E);
    k_dis<<<(N + 255) / 256, 256, 0, stream>>>(dis, N);
    int nsb = (N + 1023) / 1024;
    k_scan1<<<nsb, 256, 0, stream>>>(count, bsum, N);
    k_scan2<<<1, 64, 0, stream>>>(bsum, boff, nsb, &row_ptr[N]);
    k_scan3<<<nsb, 256, 0, stream>>>(count, boff, row_ptr, N);
    k_copy_int<<<(N + 255) / 256, 256, 0, stream>>>(row_ptr, cursor, N);
    k_fill_csr<<<2048, 256, 0, stream>>>(src, dst, ew, dis, cursor, csr_src, csr_w, E);

    dim3 g64x2((N + 63) / 64, 2);
    dim3 g64((N + 63) / 64, 1);
    int ep_blocks128 = (N * 128 + 255) / 256;

    // ---- layer 0: 16 -> 128 ----
    {
        const float* W = W0; const int DK = 16, KS = 16 * 128;
        k_gemm<false><<<g64x2, 256, 0, stream>>>(x, W, O, N, DK, 128);
        k_prop<16><<<(N + 7) / 8, 128, 0, stream>>>(x, P, row_ptr, csr_src, csr_w, N);
        k_gemm<true><<<g64x2, 256, 0, stream>>>(P, W + 1 * KS, O, N, DK, 128);
        k_prop<16><<<(N + 7) / 8, 128, 0, stream>>>(P, Q, row_ptr, csr_src, csr_w, N);
        k_gemm<true><<<g64x2, 256, 0, stream>>>(Q, W + 2 * KS, O, N, DK, 128);
        k_prop<16><<<(N + 7) / 8, 128, 0, stream>>>(Q, P, row_ptr, csr_src, csr_w, N);
        k_gemm<true><<<g64x2, 256, 0, stream>>>(P, W + 3 * KS, O, N, DK, 128);
        k_bias_relu<<<ep_blocks128, 256, 0, stream>>>(O, b0, Q, N * 128, 128);
    }
    // ---- layers 1,2: 128 -> 128 ----
    const float* Wmid[2] = { W1, W2 };
    const float* bmid[2] = { b1, b2 };
    for (int l = 0; l < 2; ++l) {
        const float* W = Wmid[l]; const int DK = 128, KS = 128 * 128;
        k_gemm<false><<<g64x2, 256, 0, stream>>>(Q, W, O, N, DK, 128);
        k_prop<128><<<N, 128, 0, stream>>>(Q, P, row_ptr, csr_src, csr_w, N);
        k_gemm<true><<<g64x2, 256, 0, stream>>>(P, W + 1 * KS, O, N, DK, 128);
        k_prop<128><<<N, 128, 0, stream>>>(P, Q, row_ptr, csr_src, csr_w, N);
        k_gemm<true><<<g64x2, 256, 0, stream>>>(Q, W + 2 * KS, O, N, DK, 128);
        k_prop<128><<<N, 128, 0, stream>>>(Q, P, row_ptr, csr_src, csr_w, N);
        k_gemm<true><<<g64x2, 256, 0, stream>>>(P, W + 3 * KS, O, N, DK, 128);
        k_bias_relu<<<ep_blocks128, 256, 0, stream>>>(O, bmid[l], Q, N * 128, 128);
    }
    // ---- layer 3: 128 -> 4 ----
    {
        const float* W = W3; const int KS = 128 * 4;
        k_gemm_n4<false><<<g64, 256, 0, stream>>>(Q, W, O, N);
        k_prop<128><<<N, 128, 0, stream>>>(Q, P, row_ptr, csr_src, csr_w, N);
        k_gemm_n4<true><<<g64, 256, 0, stream>>>(P, W + 1 * KS, O, N);
        k_prop<128><<<N, 128, 0, stream>>>(P, Q, row_ptr, csr_src, csr_w, N);
        k_gemm_n4<true><<<g64, 256, 0, stream>>>(Q, W + 2 * KS, O, N);
        k_prop<128><<<N, 128, 0, stream>>>(Q, P, row_ptr, csr_src, csr_w, N);
        k_gemm_n4<true><<<g64, 256, 0, stream>>>(P, W + 3 * KS, O, N);
        k_bias<<<(N * 4 + 255) / 256, 256, 0, stream>>>(O, b3, out, N * 4, 4);
    }
}

// Round 2
// 2918.839 us; speedup vs baseline: 1.9971x; 1.9971x over previous
//
#include <hip/hip_runtime.h>

// TAGConv L3: N=100000 nodes, E=3200000 edges, K=3 hops
// dims: (16->128)(128->128)(128->128)(128->4), ReLU between, fp32 throughout.
// R1: layer-3 computed in projected d=4 space (Horner: out = z0 + A(z1 + A(z2 + A z3)));
//     d=128 prop uses 64 lanes/node x float2, edge-unroll 2.

// ---------------- degree / norm ----------------
__global__ void k_edge_deg(const int* __restrict__ src, const int* __restrict__ dst,
                           const float* __restrict__ ew, float* __restrict__ deg,
                           int* __restrict__ count, int E) {
    int stride = gridDim.x * blockDim.x;
    for (int e = blockIdx.x * blockDim.x + threadIdx.x; e < E; e += stride) {
        int d = dst[e];
        atomicAdd(&deg[d], ew[e]);
        atomicAdd(&count[d], 1);
    }
}

__global__ void k_dis(float* deg, int N) {
    int i = blockIdx.x * blockDim.x + threadIdx.x;
    if (i < N) { float d = deg[i]; deg[i] = d > 0.f ? rsqrtf(d) : 0.f; }
}

// ---------------- scan for row_ptr (3-phase) ----------------
__global__ void k_scan1(const int* __restrict__ count, int* __restrict__ bsum, int N) {
    __shared__ int s[256];
    int tid = threadIdx.x;
    int base = blockIdx.x * 1024 + tid * 4;
    int t = 0;
    #pragma unroll
    for (int i = 0; i < 4; ++i) { int idx = base + i; if (idx < N) t += count[idx]; }
    s[tid] = t; __syncthreads();
    for (int off = 128; off > 0; off >>= 1) {
        if (tid < off) s[tid] += s[tid + off];
        __syncthreads();
    }
    if (tid == 0) bsum[blockIdx.x] = s[0];
}

__global__ void k_scan2(const int* __restrict__ bsum, int* __restrict__ boff,
                        int nb, int* __restrict__ row_ptr_last) {
    if (threadIdx.x == 0) {
        int run = 0;
        for (int i = 0; i < nb; ++i) { boff[i] = run; run += bsum[i]; }
        *row_ptr_last = run;
    }
}

__global__ void k_scan3(const int* __restrict__ count, const int* __restrict__ boff,
                        int* __restrict__ row_ptr, int N) {
    __shared__ int s[256];
    int tid = threadIdx.x;
    int base = blockIdx.x * 1024 + tid * 4;
    int v[4]; int t = 0;
    #pragma unroll
    for (int i = 0; i < 4; ++i) { int idx = base + i; v[i] = (idx < N) ? count[idx] : 0; t += v[i]; }
    s[tid] = t; __syncthreads();
    for (int off = 1; off < 256; off <<= 1) {
        int add = (tid >= off) ? s[tid - off] : 0;
        __syncthreads();
        s[tid] += add;
        __syncthreads();
    }
    int g = boff[blockIdx.x] + (s[tid] - t);   // exclusive prefix
    #pragma unroll
    for (int i = 0; i < 4; ++i) { int idx = base + i; if (idx < N) row_ptr[idx] = g; g += v[i]; }
}

__global__ void k_copy_int(const int* __restrict__ a, int* __restrict__ b, int n) {
    int i = blockIdx.x * blockDim.x + threadIdx.x;
    if (i < n) b[i] = a[i];
}

__global__ void k_fill_csr(const int* __restrict__ src, const int* __restrict__ dst,
                           const float* __restrict__ ew, const float* __restrict__ dis,
                           int* __restrict__ cursor, int* __restrict__ csr_src,
                           float* __restrict__ csr_w, int E) {
    int stride = gridDim.x * blockDim.x;
    for (int e = blockIdx.x * blockDim.x + threadIdx.x; e < E; e += stride) {
        int d = dst[e];
        int s = src[e];
        int pos = atomicAdd(&cursor[d], 1);
        csr_src[pos] = s;
        csr_w[pos] = dis[s] * ew[e] * dis[d];
    }
}

// ---------------- propagation d=16 (layer 0) ----------------
__global__ __launch_bounds__(128) void k_prop16(const float* __restrict__ hin,
                                                float* __restrict__ hout,
                                                const int* __restrict__ row_ptr,
                                                const int* __restrict__ csr_src,
                                                const float* __restrict__ csr_w, int N) {
    int node = blockIdx.x * 8 + threadIdx.x / 16;
    int f = threadIdx.x % 16;
    if (node >= N) return;
    int s = row_ptr[node], e = row_ptr[node + 1];
    float acc = 0.f;
    for (int i = s; i < e; ++i)
        acc += csr_w[i] * hin[(size_t)csr_src[i] * 16 + f];
    hout[(size_t)node * 16 + f] = acc;
}

// ---------------- propagation d=128: 64 lanes/node, float2/lane, unroll 2 ----------------
__global__ __launch_bounds__(256) void k_prop128(const float* __restrict__ hin,
                                                 float* __restrict__ hout,
                                                 const int* __restrict__ row_ptr,
                                                 const int* __restrict__ csr_src,
                                                 const float* __restrict__ csr_w, int N) {
    int node = blockIdx.x * 4 + (threadIdx.x >> 6);
    int f2 = (threadIdx.x & 63) * 2;
    if (node >= N) return;
    int s = row_ptr[node], e = row_ptr[node + 1];
    float ax = 0.f, ay = 0.f;
    int i = s;
    for (; i + 1 < e; i += 2) {
        int s0 = csr_src[i], s1 = csr_src[i + 1];
        float w0 = csr_w[i], w1 = csr_w[i + 1];
        float2 v0 = *reinterpret_cast<const float2*>(&hin[(size_t)s0 * 128 + f2]);
        float2 v1 = *reinterpret_cast<const float2*>(&hin[(size_t)s1 * 128 + f2]);
        ax += w0 * v0.x + w1 * v1.x;
        ay += w0 * v0.y + w1 * v1.y;
    }
    if (i < e) {
        int s0 = csr_src[i];
        float w0 = csr_w[i];
        float2 v0 = *reinterpret_cast<const float2*>(&hin[(size_t)s0 * 128 + f2]);
        ax += w0 * v0.x;
        ay += w0 * v0.y;
    }
    float2 r; r.x = ax; r.y = ay;
    *reinterpret_cast<float2*>(&hout[(size_t)node * 128 + f2]) = r;
}

// ---------------- propagation d=4 with add: out[n][j] = Z[n][zcol+j] (+bias) + sum w*tin[src][j] ----------------
__global__ __launch_bounds__(256) void k_prop4_add(const float* __restrict__ tin, int tin_stride, int tin_off,
                                                   const float* __restrict__ Z, int zcol,
                                                   const float* __restrict__ bias,
                                                   float* __restrict__ tout,
                                                   const int* __restrict__ row_ptr,
                                                   const int* __restrict__ csr_src,
                                                   const float* __restrict__ csr_w, int N) {
    int node = blockIdx.x * 64 + (threadIdx.x >> 2);
    int j = threadIdx.x & 3;
    if (node >= N) return;
    int s = row_ptr[node], e = row_ptr[node + 1];
    float acc = Z[(size_t)node * 16 + zcol + j];
    if (bias) acc += bias[j];
    for (int i = s; i < e; ++i)
        acc += csr_w[i] * tin[(size_t)csr_src[i] * tin_stride + tin_off + j];
    tout[(size_t)node * 4 + j] = acc;
}

// ---------------- GEMM: C(MxNc) (+)= A(MxK) @ B(KxNc), BM=BN=64, BK=16 ----------------
template <bool ACCUM>
__global__ __launch_bounds__(256) void k_gemm(const float* __restrict__ A,
                                              const float* __restrict__ B,
                                              float* __restrict__ C,
                                              int M, int K, int Nc) {
    __shared__ float As[16][68];
    __shared__ float Bs[16][68];
    int tid = threadIdx.x;
    int row0 = blockIdx.x * 64, col0 = blockIdx.y * 64;
    int arow = tid >> 2, ac4 = (tid & 3) * 4;
    int bk = tid >> 4, bc4 = (tid & 15) * 4;
    int m0 = (tid >> 4) * 4, n0 = (tid & 15) * 4;
    float acc[4][4] = {};
    for (int kt = 0; kt < K; kt += 16) {
        {
            int gr = row0 + arow;
            float4 v = make_float4(0.f, 0.f, 0.f, 0.f);
            if (gr < M) v = *reinterpret_cast<const float4*>(&A[(size_t)gr * K + kt + ac4]);
            As[ac4 + 0][arow] = v.x; As[ac4 + 1][arow] = v.y;
            As[ac4 + 2][arow] = v.z; As[ac4 + 3][arow] = v.w;
        }
        {
            float4 v = *reinterpret_cast<const float4*>(&B[(size_t)(kt + bk) * Nc + col0 + bc4]);
            Bs[bk][bc4 + 0] = v.x; Bs[bk][bc4 + 1] = v.y;
            Bs[bk][bc4 + 2] = v.z; Bs[bk][bc4 + 3] = v.w;
        }
        __syncthreads();
        #pragma unroll
        for (int kk = 0; kk < 16; ++kk) {
            float a0 = As[kk][m0], a1 = As[kk][m0 + 1], a2 = As[kk][m0 + 2], a3 = As[kk][m0 + 3];
            float b0 = Bs[kk][n0], b1 = Bs[kk][n0 + 1], b2 = Bs[kk][n0 + 2], b3 = Bs[kk][n0 + 3];
            acc[0][0] += a0 * b0; acc[0][1] += a0 * b1; acc[0][2] += a0 * b2; acc[0][3] += a0 * b3;
            acc[1][0] += a1 * b0; acc[1][1] += a1 * b1; acc[1][2] += a1 * b2; acc[1][3] += a1 * b3;
            acc[2][0] += a2 * b0; acc[2][1] += a2 * b1; acc[2][2] += a2 * b2; acc[2][3] += a2 * b3;
            acc[3][0] += a3 * b0; acc[3][1] += a3 * b1; acc[3][2] += a3 * b2; acc[3][3] += a3 * b3;
        }
        __syncthreads();
    }
    #pragma unroll
    for (int i = 0; i < 4; ++i) {
        int gr = row0 + m0 + i;
        if (gr < M) {
            #pragma unroll
            for (int j = 0; j < 4; ++j) {
                size_t idx = (size_t)gr * Nc + col0 + n0 + j;
                C[idx] = (ACCUM ? C[idx] : 0.f) + acc[i][j];
            }
        }
    }
}

// ---------------- Z GEMM: Z(Mx16) = A(Mx128) @ W3'(128x16); W3'[i][k*4+j] = W3[k][i][j] ----------------
__global__ __launch_bounds__(256) void k_gemm_z(const float* __restrict__ A,
                                                const float* __restrict__ W3,
                                                float* __restrict__ Z, int M) {
    __shared__ float hs[64][132];
    __shared__ float wsm[128][16];
    int tid = threadIdx.x;
    int row0 = blockIdx.x * 64;
    for (int t = tid; t < 2048; t += 256) {
        int k = t >> 9, i = (t >> 2) & 127, j = t & 3;
        wsm[i][k * 4 + j] = W3[t];
    }
    #pragma unroll
    for (int it = 0; it < 8; ++it) {
        int f4 = it * 256 + tid;
        int r = f4 >> 5;
        int c4 = (f4 & 31) * 4;
        int gr = row0 + r;
        float4 v = make_float4(0.f, 0.f, 0.f, 0.f);
        if (gr < M) v = *reinterpret_cast<const float4*>(&A[(size_t)gr * 128 + c4]);
        hs[r][c4] = v.x; hs[r][c4 + 1] = v.y; hs[r][c4 + 2] = v.z; hs[r][c4 + 3] = v.w;
    }
    __syncthreads();
    int r = tid >> 2, c0 = (tid & 3) * 4;
    float acc[4] = {};
    #pragma unroll 4
    for (int i = 0; i < 128; ++i) {
        float a = hs[r][i];
        #pragma unroll
        for (int j = 0; j < 4; ++j) acc[j] += a * wsm[i][c0 + j];
    }
    int gr = row0 + r;
    if (gr < M) {
        float4 v; v.x = acc[0]; v.y = acc[1]; v.z = acc[2]; v.w = acc[3];
        *reinterpret_cast<float4*>(&Z[(size_t)gr * 16 + c0]) = v;
    }
}

// ---------------- epilogues ----------------
__global__ void k_bias_relu(const float* __restrict__ O, const float* __restrict__ b,
                            float* __restrict__ out, int total, int D) {
    int i = blockIdx.x * blockDim.x + threadIdx.x;
    if (i < total) out[i] = fmaxf(O[i] + b[i % D], 0.f);
}

// ---------------- launch ----------------
extern "C" void kernel_launch(void* const* d_in, const int* in_sizes, int n_in,
                              void* d_out, int out_size, void* d_ws, size_t ws_size,
                              hipStream_t stream) {
    const float* x  = (const float*)d_in[0];
    const int*   ei = (const int*)d_in[1];
    const float* ew = (const float*)d_in[2];
    const float* W0 = (const float*)d_in[3];
    const float* b0 = (const float*)d_in[4];
    const float* W1 = (const float*)d_in[5];
    const float* b1 = (const float*)d_in[6];
    const float* W2 = (const float*)d_in[7];
    const float* b2 = (const float*)d_in[8];
    const float* W3 = (const float*)d_in[9];
    const float* b3 = (const float*)d_in[10];
    float* out = (float*)d_out;

    const int N = in_sizes[0] / 16;   // 100000
    const int E = in_sizes[2];        // 3200000
    const int* src = ei;
    const int* dst = ei + E;

    // workspace layout
    char* ws = (char*)d_ws;
    size_t off = 0;
    auto take = [&](size_t bytes) -> void* {
        void* p = ws + off;
        off = (off + bytes + 255) & ~(size_t)255;
        return p;
    };
    float* P       = (float*)take((size_t)N * 128 * 4);
    float* Q       = (float*)take((size_t)N * 128 * 4);
    float* O       = (float*)take((size_t)N * 128 * 4);
    int*   csr_src = (int*)  take((size_t)E * 4);
    float* csr_w   = (float*)take((size_t)E * 4);
    float* dis     = (float*)take((size_t)N * 4);   // deg, then rsqrt in place
    int*   count   = (int*)  take((size_t)N * 4);
    int*   row_ptr = (int*)  take((size_t)(N + 1) * 4);
    int*   cursor  = (int*)  take((size_t)N * 4);
    int*   bsum    = (int*)  take(1024);
    int*   boff    = (int*)  take(1024);
    float* Z       = (float*)take((size_t)N * 16 * 4);
    float* T1      = (float*)take((size_t)N * 4 * 4);
    float* T2      = (float*)take((size_t)N * 4 * 4);

    // ---- build norm + CSR ----
    hipMemsetAsync(dis,   0, (size_t)N * 4, stream);
    hipMemsetAsync(count, 0, (size_t)N * 4, stream);
    k_edge_deg<<<2048, 256, 0, stream>>>(src, dst, ew, dis, count, E);
    k_dis<<<(N + 255) / 256, 256, 0, stream>>>(dis, N);
    int nsb = (N + 1023) / 1024;
    k_scan1<<<nsb, 256, 0, stream>>>(count, bsum, N);
    k_scan2<<<1, 64, 0, stream>>>(bsum, boff, nsb, &row_ptr[N]);
    k_scan3<<<nsb, 256, 0, stream>>>(count, boff, row_ptr, N);
    k_copy_int<<<(N + 255) / 256, 256, 0, stream>>>(row_ptr, cursor, N);
    k_fill_csr<<<2048, 256, 0, stream>>>(src, dst, ew, dis, cursor, csr_src, csr_w, E);

    dim3 g64x2((N + 63) / 64, 2);
    int ep_blocks128 = (N * 128 + 255) / 256;
    int prop128_grid = (N + 3) / 4;

    // ---- layer 0: 16 -> 128 ----
    {
        const float* W = W0; const int DK = 16, KS = 16 * 128;
        k_gemm<false><<<g64x2, 256, 0, stream>>>(x, W, O, N, DK, 128);
        k_prop16<<<(N + 7) / 8, 128, 0, stream>>>(x, P, row_ptr, csr_src, csr_w, N);
        k_gemm<true><<<g64x2, 256, 0, stream>>>(P, W + 1 * KS, O, N, DK, 128);
        k_prop16<<<(N + 7) / 8, 128, 0, stream>>>(P, Q, row_ptr, csr_src, csr_w, N);
        k_gemm<true><<<g64x2, 256, 0, stream>>>(Q, W + 2 * KS, O, N, DK, 128);
        k_prop16<<<(N + 7) / 8, 128, 0, stream>>>(Q, P, row_ptr, csr_src, csr_w, N);
        k_gemm<true><<<g64x2, 256, 0, stream>>>(P, W + 3 * KS, O, N, DK, 128);
        k_bias_relu<<<ep_blocks128, 256, 0, stream>>>(O, b0, Q, N * 128, 128);
    }
    // ---- layers 1,2: 128 -> 128 ----
    const float* Wmid[2] = { W1, W2 };
    const float* bmid[2] = { b1, b2 };
    for (int l = 0; l < 2; ++l) {
        const float* W = Wmid[l]; const int DK = 128, KS = 128 * 128;
        k_gemm<false><<<g64x2, 256, 0, stream>>>(Q, W, O, N, DK, 128);
        k_prop128<<<prop128_grid, 256, 0, stream>>>(Q, P, row_ptr, csr_src, csr_w, N);
        k_gemm<true><<<g64x2, 256, 0, stream>>>(P, W + 1 * KS, O, N, DK, 128);
        k_prop128<<<prop128_grid, 256, 0, stream>>>(P, Q, row_ptr, csr_src, csr_w, N);
        k_gemm<true><<<g64x2, 256, 0, stream>>>(Q, W + 2 * KS, O, N, DK, 128);
        k_prop128<<<prop128_grid, 256, 0, stream>>>(Q, P, row_ptr, csr_src, csr_w, N);
        k_gemm<true><<<g64x2, 256, 0, stream>>>(P, W + 3 * KS, O, N, DK, 128);
        k_bias_relu<<<ep_blocks128, 256, 0, stream>>>(O, bmid[l], Q, N * 128, 128);
    }
    // ---- layer 3: 128 -> 4 via projected Horner ----
    // Z[n][k*4+j] = (Q @ W3[k])[n][j];  out = z0 + b3 + A(z1 + A(z2 + A z3))
    {
        k_gemm_z<<<(N + 63) / 64, 256, 0, stream>>>(Q, W3, Z, N);
        int g = (N + 63) / 64;
        // t1 = z2 + A z3   (z3 lives in Z cols 12..15)
        k_prop4_add<<<g, 256, 0, stream>>>(Z, 16, 12, Z, 8, nullptr, T1,
                                           row_ptr, csr_src, csr_w, N);
        // t2 = z1 + A t1
        k_prop4_add<<<g, 256, 0, stream>>>(T1, 4, 0, Z, 4, nullptr, T2,
                                           row_ptr, csr_src, csr_w, N);
        // out = z0 + b3 + A t2
        k_prop4_add<<<g, 256, 0, stream>>>(T2, 4, 0, Z, 0, b3, out,
                                           row_ptr, csr_src, csr_w, N);
    }
}

// Round 3
// 2214.311 us; speedup vs baseline: 2.6326x; 1.3182x over previous
//
#include <hip/hip_runtime.h>

// TAGConv L3: N=100000, E=3200000, K=3. dims (16->128)(128->128)(128->128)(128->4).
// R2: d=128 props gather from bf16 copies (fp32 accumulate, dual fp32+bf16 output);
//     bias+ReLU+bf16-cast fused into each layer's final GEMM; layer 3 stays d=4 Horner.

__device__ __forceinline__ float bf2f(unsigned short u) {
    return __uint_as_float(((unsigned int)u) << 16);
}
__device__ __forceinline__ unsigned short f2bf(float f) {
    unsigned int u = __float_as_uint(f);
    u = (u + 0x7fff + ((u >> 16) & 1)) >> 16;   // RNE
    return (unsigned short)u;
}

// ---------------- degree / norm ----------------
__global__ void k_edge_deg(const int* __restrict__ src, const int* __restrict__ dst,
                           const float* __restrict__ ew, float* __restrict__ deg,
                           int* __restrict__ count, int E) {
    int stride = gridDim.x * blockDim.x;
    for (int e = blockIdx.x * blockDim.x + threadIdx.x; e < E; e += stride) {
        int d = dst[e];
        atomicAdd(&deg[d], ew[e]);
        atomicAdd(&count[d], 1);
    }
}

__global__ void k_dis(float* deg, int N) {
    int i = blockIdx.x * blockDim.x + threadIdx.x;
    if (i < N) { float d = deg[i]; deg[i] = d > 0.f ? rsqrtf(d) : 0.f; }
}

// ---------------- scan for row_ptr (3-phase) ----------------
__global__ void k_scan1(const int* __restrict__ count, int* __restrict__ bsum, int N) {
    __shared__ int s[256];
    int tid = threadIdx.x;
    int base = blockIdx.x * 1024 + tid * 4;
    int t = 0;
    #pragma unroll
    for (int i = 0; i < 4; ++i) { int idx = base + i; if (idx < N) t += count[idx]; }
    s[tid] = t; __syncthreads();
    for (int off = 128; off > 0; off >>= 1) {
        if (tid < off) s[tid] += s[tid + off];
        __syncthreads();
    }
    if (tid == 0) bsum[blockIdx.x] = s[0];
}

__global__ void k_scan2(const int* __restrict__ bsum, int* __restrict__ boff,
                        int nb, int* __restrict__ row_ptr_last) {
    if (threadIdx.x == 0) {
        int run = 0;
        for (int i = 0; i < nb; ++i) { boff[i] = run; run += bsum[i]; }
        *row_ptr_last = run;
    }
}

__global__ void k_scan3(const int* __restrict__ count, const int* __restrict__ boff,
                        int* __restrict__ row_ptr, int N) {
    __shared__ int s[256];
    int tid = threadIdx.x;
    int base = blockIdx.x * 1024 + tid * 4;
    int v[4]; int t = 0;
    #pragma unroll
    for (int i = 0; i < 4; ++i) { int idx = base + i; v[i] = (idx < N) ? count[idx] : 0; t += v[i]; }
    s[tid] = t; __syncthreads();
    for (int off = 1; off < 256; off <<= 1) {
        int add = (tid >= off) ? s[tid - off] : 0;
        __syncthreads();
        s[tid] += add;
        __syncthreads();
    }
    int g = boff[blockIdx.x] + (s[tid] - t);   // exclusive prefix
    #pragma unroll
    for (int i = 0; i < 4; ++i) { int idx = base + i; if (idx < N) row_ptr[idx] = g; g += v[i]; }
}

__global__ void k_copy_int(const int* __restrict__ a, int* __restrict__ b, int n) {
    int i = blockIdx.x * blockDim.x + threadIdx.x;
    if (i < n) b[i] = a[i];
}

__global__ void k_fill_csr(const int* __restrict__ src, const int* __restrict__ dst,
                           const float* __restrict__ ew, const float* __restrict__ dis,
                           int* __restrict__ cursor, int* __restrict__ csr_src,
                           float* __restrict__ csr_w, int E) {
    int stride = gridDim.x * blockDim.x;
    for (int e = blockIdx.x * blockDim.x + threadIdx.x; e < E; e += stride) {
        int d = dst[e];
        int s = src[e];
        int pos = atomicAdd(&cursor[d], 1);
        csr_src[pos] = s;
        csr_w[pos] = dis[s] * ew[e] * dis[d];
    }
}

// ---------------- propagation d=16 (layer 0, fp32) ----------------
__global__ __launch_bounds__(128) void k_prop16(const float* __restrict__ hin,
                                                float* __restrict__ hout,
                                                const int* __restrict__ row_ptr,
                                                const int* __restrict__ csr_src,
                                                const float* __restrict__ csr_w, int N) {
    int node = blockIdx.x * 8 + threadIdx.x / 16;
    int f = threadIdx.x % 16;
    if (node >= N) return;
    int s = row_ptr[node], e = row_ptr[node + 1];
    float acc = 0.f;
    for (int i = s; i < e; ++i)
        acc += csr_w[i] * hin[(size_t)csr_src[i] * 16 + f];
    hout[(size_t)node * 16 + f] = acc;
}

// ---------------- propagation d=128 bf16-in: 32 lanes/node, bf16x4/lane, unroll 4 ----------------
__global__ __launch_bounds__(256) void k_prop128b(const unsigned short* __restrict__ hin,
                                                  float* __restrict__ hout,
                                                  unsigned short* __restrict__ bout,
                                                  const int* __restrict__ row_ptr,
                                                  const int* __restrict__ csr_src,
                                                  const float* __restrict__ csr_w, int N) {
    int node = blockIdx.x * 8 + (threadIdx.x >> 5);
    int f4 = (threadIdx.x & 31) * 4;
    if (node >= N) return;
    int s = row_ptr[node], e = row_ptr[node + 1];
    float a0 = 0.f, a1 = 0.f, a2 = 0.f, a3 = 0.f;

    int i = s;
    int lim = (s + 3) & ~3;
    if (lim > e) lim = e;
    for (; i < lim; ++i) {
        int s0 = csr_src[i]; float w0 = csr_w[i];
        ushort4 r = *reinterpret_cast<const ushort4*>(&hin[(size_t)s0 * 128 + f4]);
        a0 += w0 * bf2f(r.x); a1 += w0 * bf2f(r.y);
        a2 += w0 * bf2f(r.z); a3 += w0 * bf2f(r.w);
    }
    for (; i + 4 <= e; i += 4) {
        int4   idx = *reinterpret_cast<const int4*>(&csr_src[i]);
        float4 w   = *reinterpret_cast<const float4*>(&csr_w[i]);
        ushort4 r0 = *reinterpret_cast<const ushort4*>(&hin[(size_t)idx.x * 128 + f4]);
        ushort4 r1 = *reinterpret_cast<const ushort4*>(&hin[(size_t)idx.y * 128 + f4]);
        ushort4 r2 = *reinterpret_cast<const ushort4*>(&hin[(size_t)idx.z * 128 + f4]);
        ushort4 r3 = *reinterpret_cast<const ushort4*>(&hin[(size_t)idx.w * 128 + f4]);
        a0 += w.x * bf2f(r0.x) + w.y * bf2f(r1.x) + w.z * bf2f(r2.x) + w.w * bf2f(r3.x);
        a1 += w.x * bf2f(r0.y) + w.y * bf2f(r1.y) + w.z * bf2f(r2.y) + w.w * bf2f(r3.y);
        a2 += w.x * bf2f(r0.z) + w.y * bf2f(r1.z) + w.z * bf2f(r2.z) + w.w * bf2f(r3.z);
        a3 += w.x * bf2f(r0.w) + w.y * bf2f(r1.w) + w.z * bf2f(r2.w) + w.w * bf2f(r3.w);
    }
    for (; i < e; ++i) {
        int s0 = csr_src[i]; float w0 = csr_w[i];
        ushort4 r = *reinterpret_cast<const ushort4*>(&hin[(size_t)s0 * 128 + f4]);
        a0 += w0 * bf2f(r.x); a1 += w0 * bf2f(r.y);
        a2 += w0 * bf2f(r.z); a3 += w0 * bf2f(r.w);
    }

    *reinterpret_cast<float4*>(&hout[(size_t)node * 128 + f4]) = make_float4(a0, a1, a2, a3);
    if (bout) {
        ushort4 b; b.x = f2bf(a0); b.y = f2bf(a1); b.z = f2bf(a2); b.w = f2bf(a3);
        *reinterpret_cast<ushort4*>(&bout[(size_t)node * 128 + f4]) = b;
    }
}

// ---------------- propagation d=4 with add ----------------
__global__ __launch_bounds__(256) void k_prop4_add(const float* __restrict__ tin, int tin_stride, int tin_off,
                                                   const float* __restrict__ Z, int zcol,
                                                   const float* __restrict__ bias,
                                                   float* __restrict__ tout,
                                                   const int* __restrict__ row_ptr,
                                                   const int* __restrict__ csr_src,
                                                   const float* __restrict__ csr_w, int N) {
    int node = blockIdx.x * 64 + (threadIdx.x >> 2);
    int j = threadIdx.x & 3;
    if (node >= N) return;
    int s = row_ptr[node], e = row_ptr[node + 1];
    float acc = Z[(size_t)node * 16 + zcol + j];
    if (bias) acc += bias[j];
    for (int i = s; i < e; ++i)
        acc += csr_w[i] * tin[(size_t)csr_src[i] * tin_stride + tin_off + j];
    tout[(size_t)node * 4 + j] = acc;
}

// ---------------- GEMM: BM=BN=64, BK=16; optional fused bias+ReLU+bf16 epilogue ----------------
template <bool ACCUM, bool FINAL>
__global__ __launch_bounds__(256) void k_gemm(const float* __restrict__ A,
                                              const float* __restrict__ B,
                                              const float* __restrict__ Cin,
                                              float* __restrict__ Cout,
                                              unsigned short* __restrict__ Coutb,
                                              const float* __restrict__ bias,
                                              int M, int K, int Nc) {
    __shared__ float As[16][68];
    __shared__ float Bs[16][68];
    int tid = threadIdx.x;
    int row0 = blockIdx.x * 64, col0 = blockIdx.y * 64;
    int arow = tid >> 2, ac4 = (tid & 3) * 4;
    int bk = tid >> 4, bc4 = (tid & 15) * 4;
    int m0 = (tid >> 4) * 4, n0 = (tid & 15) * 4;
    float acc[4][4] = {};
    for (int kt = 0; kt < K; kt += 16) {
        {
            int gr = row0 + arow;
            float4 v = make_float4(0.f, 0.f, 0.f, 0.f);
            if (gr < M) v = *reinterpret_cast<const float4*>(&A[(size_t)gr * K + kt + ac4]);
            As[ac4 + 0][arow] = v.x; As[ac4 + 1][arow] = v.y;
            As[ac4 + 2][arow] = v.z; As[ac4 + 3][arow] = v.w;
        }
        {
            float4 v = *reinterpret_cast<const float4*>(&B[(size_t)(kt + bk) * Nc + col0 + bc4]);
            Bs[bk][bc4 + 0] = v.x; Bs[bk][bc4 + 1] = v.y;
            Bs[bk][bc4 + 2] = v.z; Bs[bk][bc4 + 3] = v.w;
        }
        __syncthreads();
        #pragma unroll
        for (int kk = 0; kk < 16; ++kk) {
            float a0 = As[kk][m0], a1 = As[kk][m0 + 1], a2 = As[kk][m0 + 2], a3 = As[kk][m0 + 3];
            float b0 = Bs[kk][n0], b1 = Bs[kk][n0 + 1], b2 = Bs[kk][n0 + 2], b3 = Bs[kk][n0 + 3];
            acc[0][0] += a0 * b0; acc[0][1] += a0 * b1; acc[0][2] += a0 * b2; acc[0][3] += a0 * b3;
            acc[1][0] += a1 * b0; acc[1][1] += a1 * b1; acc[1][2] += a1 * b2; acc[1][3] += a1 * b3;
            acc[2][0] += a2 * b0; acc[2][1] += a2 * b1; acc[2][2] += a2 * b2; acc[2][3] += a2 * b3;
            acc[3][0] += a3 * b0; acc[3][1] += a3 * b1; acc[3][2] += a3 * b2; acc[3][3] += a3 * b3;
        }
        __syncthreads();
    }
    #pragma unroll
    for (int i = 0; i < 4; ++i) {
        int gr = row0 + m0 + i;
        if (gr < M) {
            #pragma unroll
            for (int j = 0; j < 4; ++j) {
                int gc = col0 + n0 + j;
                size_t idx = (size_t)gr * Nc + gc;
                float v = acc[i][j];
                if (ACCUM) v += Cin[idx];
                if (FINAL) {
                    v = fmaxf(v + bias[gc], 0.f);
                    Cout[idx] = v;
                    Coutb[idx] = f2bf(v);
                } else {
                    Cout[idx] = v;
                }
            }
        }
    }
}

// ---------------- Z GEMM: Z(Mx16) = A(Mx128) @ W3'(128x16) ----------------
__global__ __launch_bounds__(256) void k_gemm_z(const float* __restrict__ A,
                                                const float* __restrict__ W3,
                                                float* __restrict__ Z, int M) {
    __shared__ float hs[64][132];
    __shared__ float wsm[128][16];
    int tid = threadIdx.x;
    int row0 = blockIdx.x * 64;
    for (int t = tid; t < 2048; t += 256) {
        int k = t >> 9, i = (t >> 2) & 127, j = t & 3;
        wsm[i][k * 4 + j] = W3[t];
    }
    #pragma unroll
    for (int it = 0; it < 8; ++it) {
        int f4 = it * 256 + tid;
        int r = f4 >> 5;
        int c4 = (f4 & 31) * 4;
        int gr = row0 + r;
        float4 v = make_float4(0.f, 0.f, 0.f, 0.f);
        if (gr < M) v = *reinterpret_cast<const float4*>(&A[(size_t)gr * 128 + c4]);
        hs[r][c4] = v.x; hs[r][c4 + 1] = v.y; hs[r][c4 + 2] = v.z; hs[r][c4 + 3] = v.w;
    }
    __syncthreads();
    int r = tid >> 2, c0 = (tid & 3) * 4;
    float acc[4] = {};
    #pragma unroll 4
    for (int i = 0; i < 128; ++i) {
        float a = hs[r][i];
        #pragma unroll
        for (int j = 0; j < 4; ++j) acc[j] += a * wsm[i][c0 + j];
    }
    int gr = row0 + r;
    if (gr < M) {
        float4 v; v.x = acc[0]; v.y = acc[1]; v.z = acc[2]; v.w = acc[3];
        *reinterpret_cast<float4*>(&Z[(size_t)gr * 16 + c0]) = v;
    }
}

// ---------------- launch ----------------
extern "C" void kernel_launch(void* const* d_in, const int* in_sizes, int n_in,
                              void* d_out, int out_size, void* d_ws, size_t ws_size,
                              hipStream_t stream) {
    const float* x  = (const float*)d_in[0];
    const int*   ei = (const int*)d_in[1];
    const float* ew = (const float*)d_in[2];
    const float* W0 = (const float*)d_in[3];
    const float* b0 = (const float*)d_in[4];
    const float* W1 = (const float*)d_in[5];
    const float* b1 = (const float*)d_in[6];
    const float* W2 = (const float*)d_in[7];
    const float* b2 = (const float*)d_in[8];
    const float* W3 = (const float*)d_in[9];
    const float* b3 = (const float*)d_in[10];
    float* out = (float*)d_out;

    const int N = in_sizes[0] / 16;   // 100000
    const int E = in_sizes[2];        // 3200000
    const int* src = ei;
    const int* dst = ei + E;

    char* ws = (char*)d_ws;
    size_t off = 0;
    auto take = [&](size_t bytes) -> void* {
        void* p = ws + off;
        off = (off + bytes + 255) & ~(size_t)255;
        return p;
    };
    float* P       = (float*)take((size_t)N * 128 * 4);
    float* Q       = (float*)take((size_t)N * 128 * 4);
    float* O       = (float*)take((size_t)N * 128 * 4);
    int*   csr_src = (int*)  take((size_t)E * 4);
    float* csr_w   = (float*)take((size_t)E * 4);
    float* dis     = (float*)take((size_t)N * 4);
    int*   count   = (int*)  take((size_t)N * 4);
    int*   row_ptr = (int*)  take((size_t)(N + 1) * 4);
    int*   cursor  = (int*)  take((size_t)N * 4);
    int*   bsum    = (int*)  take(1024);
    int*   boff    = (int*)  take(1024);
    float* Z       = (float*)take((size_t)N * 16 * 4);
    float* T1      = (float*)take((size_t)N * 4 * 4);
    float* T2      = (float*)take((size_t)N * 4 * 4);
    float* P16     = (float*)take((size_t)N * 16 * 4);
    float* Q16     = (float*)take((size_t)N * 16 * 4);
    unsigned short* Qb = (unsigned short*)take((size_t)N * 128 * 2);
    unsigned short* Pb = (unsigned short*)take((size_t)N * 128 * 2);

    // ---- build norm + CSR ----
    hipMemsetAsync(dis,   0, (size_t)N * 4, stream);
    hipMemsetAsync(count, 0, (size_t)N * 4, stream);
    k_edge_deg<<<2048, 256, 0, stream>>>(src, dst, ew, dis, count, E);
    k_dis<<<(N + 255) / 256, 256, 0, stream>>>(dis, N);
    int nsb = (N + 1023) / 1024;
    k_scan1<<<nsb, 256, 0, stream>>>(count, bsum, N);
    k_scan2<<<1, 64, 0, stream>>>(bsum, boff, nsb, &row_ptr[N]);
    k_scan3<<<nsb, 256, 0, stream>>>(count, boff, row_ptr, N);
    k_copy_int<<<(N + 255) / 256, 256, 0, stream>>>(row_ptr, cursor, N);
    k_fill_csr<<<2048, 256, 0, stream>>>(src, dst, ew, dis, cursor, csr_src, csr_w, E);

    dim3 g64x2((N + 63) / 64, 2);
    int gp128 = (N + 7) / 8;

    // ---- layer 0: 16 -> 128 (prop in d=16, then GEMMs; last GEMM fused bias+relu+bf16) ----
    {
        const float* W = W0; const int KS = 16 * 128;
        k_gemm<false, false><<<g64x2, 256, 0, stream>>>(x, W, nullptr, O, nullptr, nullptr, N, 16, 128);
        k_prop16<<<(N + 7) / 8, 128, 0, stream>>>(x, P16, row_ptr, csr_src, csr_w, N);
        k_gemm<true, false><<<g64x2, 256, 0, stream>>>(P16, W + 1 * KS, O, O, nullptr, nullptr, N, 16, 128);
        k_prop16<<<(N + 7) / 8, 128, 0, stream>>>(P16, Q16, row_ptr, csr_src, csr_w, N);
        k_gemm<true, false><<<g64x2, 256, 0, stream>>>(Q16, W + 2 * KS, O, O, nullptr, nullptr, N, 16, 128);
        k_prop16<<<(N + 7) / 8, 128, 0, stream>>>(Q16, P16, row_ptr, csr_src, csr_w, N);
        k_gemm<true, true><<<g64x2, 256, 0, stream>>>(P16, W + 3 * KS, O, Q, Qb, b0, N, 16, 128);
    }
    // ---- layers 1,2: 128 -> 128 ----
    const float* Wmid[2] = { W1, W2 };
    const float* bmid[2] = { b1, b2 };
    for (int l = 0; l < 2; ++l) {
        const float* W = Wmid[l]; const int KS = 128 * 128;
        k_gemm<false, false><<<g64x2, 256, 0, stream>>>(Q, W, nullptr, O, nullptr, nullptr, N, 128, 128);
        k_prop128b<<<gp128, 256, 0, stream>>>(Qb, P, Pb, row_ptr, csr_src, csr_w, N);
        k_gemm<true, false><<<g64x2, 256, 0, stream>>>(P, W + 1 * KS, O, O, nullptr, nullptr, N, 128, 128);
        k_prop128b<<<gp128, 256, 0, stream>>>(Pb, P, Qb, row_ptr, csr_src, csr_w, N);   // Qb dead, reuse
        k_gemm<true, false><<<g64x2, 256, 0, stream>>>(P, W + 2 * KS, O, O, nullptr, nullptr, N, 128, 128);
        k_prop128b<<<gp128, 256, 0, stream>>>(Qb, P, nullptr, row_ptr, csr_src, csr_w, N);
        k_gemm<true, true><<<g64x2, 256, 0, stream>>>(P, W + 3 * KS, O, Q, Qb, bmid[l], N, 128, 128);
    }
    // ---- layer 3: 128 -> 4 via projected Horner ----
    {
        k_gemm_z<<<(N + 63) / 64, 256, 0, stream>>>(Q, W3, Z, N);
        int g = (N + 63) / 64;
        k_prop4_add<<<g, 256, 0, stream>>>(Z, 16, 12, Z, 8, nullptr, T1,
                                           row_ptr, csr_src, csr_w, N);
        k_prop4_add<<<g, 256, 0, stream>>>(T1, 4, 0, Z, 4, nullptr, T2,
                                           row_ptr, csr_src, csr_w, N);
        k_prop4_add<<<g, 256, 0, stream>>>(T2, 4, 0, Z, 0, b3, out,
                                           row_ptr, csr_src, csr_w, N);
    }
}

// Round 4
// 1687.713 us; speedup vs baseline: 3.4540x; 1.3120x over previous
//
#include <hip/hip_runtime.h>

// TAGConv L3: N=100000, E=3200000, K=3. dims (16->128)(128->128)(128->128)(128->4).
// R3: stacked-K bf16 MFMA GEMM (one GEMM/layer, fused bias+relu+bf16 epilogue);
//     interleaved (deg,cnt) and (src,w) pairs to halve atomic/scatter line traffic;
//     props gather bf16, write bf16 only. Layer 3 stays d=4 Horner.

typedef __attribute__((ext_vector_type(8))) short bf16x8v;   // 8 bf16 = 4 VGPR
typedef __attribute__((ext_vector_type(4))) float f32x4v;

__device__ __forceinline__ float bf2f(unsigned short u) {
    return __uint_as_float(((unsigned int)u) << 16);
}
__device__ __forceinline__ unsigned short f2bf(float f) {
    unsigned int u = __float_as_uint(f);
    u = (u + 0x7fff + ((u >> 16) & 1)) >> 16;   // RNE
    return (unsigned short)u;
}

// ---------------- degree+count (interleaved pair: one cacheline per edge) ----------------
__global__ void k_edge_deg(const int* __restrict__ src, const int* __restrict__ dst,
                           const float* __restrict__ ew, int2* __restrict__ dc, int E) {
    int stride = gridDim.x * blockDim.x;
    for (int e = blockIdx.x * blockDim.x + threadIdx.x; e < E; e += stride) {
        int d = dst[e];
        atomicAdd((float*)&dc[d].x, ew[e]);
        atomicAdd(&dc[d].y, 1);
    }
}

__global__ void k_dis(const int2* __restrict__ dc, float* __restrict__ dis, int N) {
    int i = blockIdx.x * blockDim.x + threadIdx.x;
    if (i < N) {
        float d = __int_as_float(dc[i].x);
        dis[i] = d > 0.f ? rsqrtf(d) : 0.f;
    }
}

// ---------------- scan for row_ptr (3-phase) ----------------
__global__ void k_scan1(const int2* __restrict__ dc, int* __restrict__ bsum, int N) {
    __shared__ int s[256];
    int tid = threadIdx.x;
    int base = blockIdx.x * 1024 + tid * 4;
    int t = 0;
    #pragma unroll
    for (int i = 0; i < 4; ++i) { int idx = base + i; if (idx < N) t += dc[idx].y; }
    s[tid] = t; __syncthreads();
    for (int off = 128; off > 0; off >>= 1) {
        if (tid < off) s[tid] += s[tid + off];
        __syncthreads();
    }
    if (tid == 0) bsum[blockIdx.x] = s[0];
}

__global__ void k_scan2(const int* __restrict__ bsum, int* __restrict__ boff,
                        int nb, int* __restrict__ row_ptr_last) {
    if (threadIdx.x == 0) {
        int run = 0;
        for (int i = 0; i < nb; ++i) { boff[i] = run; run += bsum[i]; }
        *row_ptr_last = run;
    }
}

__global__ void k_scan3(const int2* __restrict__ dc, const int* __restrict__ boff,
                        int* __restrict__ row_ptr, int* __restrict__ cursor, int N) {
    __shared__ int s[256];
    int tid = threadIdx.x;
    int base = blockIdx.x * 1024 + tid * 4;
    int v[4]; int t = 0;
    #pragma unroll
    for (int i = 0; i < 4; ++i) { int idx = base + i; v[i] = (idx < N) ? dc[idx].y : 0; t += v[i]; }
    s[tid] = t; __syncthreads();
    for (int off = 1; off < 256; off <<= 1) {
        int add = (tid >= off) ? s[tid - off] : 0;
        __syncthreads();
        s[tid] += add;
        __syncthreads();
    }
    int g = boff[blockIdx.x] + (s[tid] - t);   // exclusive prefix
    #pragma unroll
    for (int i = 0; i < 4; ++i) {
        int idx = base + i;
        if (idx < N) { row_ptr[idx] = g; cursor[idx] = g; }
        g += v[i];
    }
}

// ---------------- fill CSR: interleaved (src, weight) int2 ----------------
__global__ void k_fill_csr(const int* __restrict__ src, const int* __restrict__ dst,
                           const float* __restrict__ ew, const float* __restrict__ dis,
                           int* __restrict__ cursor, int2* __restrict__ csr, int E) {
    int stride = gridDim.x * blockDim.x;
    for (int e = blockIdx.x * blockDim.x + threadIdx.x; e < E; e += stride) {
        int d = dst[e];
        int s = src[e];
        int pos = atomicAdd(&cursor[d], 1);
        float w = dis[s] * ew[e] * dis[d];
        csr[pos] = make_int2(s, __float_as_int(w));
    }
}

// ---------------- x -> bf16 stack slot0 (d=16, stride 64) ----------------
__global__ void k_xcast(const float* __restrict__ x, unsigned short* __restrict__ s64, int N) {
    int i = blockIdx.x * blockDim.x + threadIdx.x;
    if (i < N * 16) {
        int n = i >> 4, f = i & 15;
        s64[n * 64 + f] = f2bf(x[i]);
    }
}

// ---------------- propagation d=16 (fp32 chain + bf16 stack write, stride 64) ----------------
__global__ __launch_bounds__(128) void k_prop16(const float* __restrict__ hin,
                                                float* __restrict__ hout,
                                                unsigned short* __restrict__ bout,
                                                const int* __restrict__ row_ptr,
                                                const int2* __restrict__ csr, int N) {
    int node = blockIdx.x * 8 + threadIdx.x / 16;
    int f = threadIdx.x % 16;
    if (node >= N) return;
    int s = row_ptr[node], e = row_ptr[node + 1];
    float acc = 0.f;
    for (int i = s; i < e; ++i) {
        int2 ed = csr[i];
        acc += __int_as_float(ed.y) * hin[(size_t)ed.x * 16 + f];
    }
    if (hout) hout[(size_t)node * 16 + f] = acc;
    bout[(size_t)node * 64 + f] = f2bf(acc);
}

// ---------------- propagation d=128 bf16: 32 lanes/node, strided in/out ----------------
__global__ __launch_bounds__(256) void k_prop128b(const unsigned short* __restrict__ hin, int gs,
                                                  unsigned short* __restrict__ bout, int os,
                                                  const int* __restrict__ row_ptr,
                                                  const int2* __restrict__ csr, int N) {
    int node = blockIdx.x * 8 + (threadIdx.x >> 5);
    int f4 = (threadIdx.x & 31) * 4;
    if (node >= N) return;
    int s = row_ptr[node], e = row_ptr[node + 1];
    float a0 = 0.f, a1 = 0.f, a2 = 0.f, a3 = 0.f;
    int i = s;
    for (; i + 4 <= e; i += 4) {
        int2 e0 = csr[i], e1 = csr[i + 1], e2 = csr[i + 2], e3 = csr[i + 3];
        float w0 = __int_as_float(e0.y), w1 = __int_as_float(e1.y);
        float w2 = __int_as_float(e2.y), w3 = __int_as_float(e3.y);
        ushort4 r0 = *reinterpret_cast<const ushort4*>(&hin[(size_t)e0.x * gs + f4]);
        ushort4 r1 = *reinterpret_cast<const ushort4*>(&hin[(size_t)e1.x * gs + f4]);
        ushort4 r2 = *reinterpret_cast<const ushort4*>(&hin[(size_t)e2.x * gs + f4]);
        ushort4 r3 = *reinterpret_cast<const ushort4*>(&hin[(size_t)e3.x * gs + f4]);
        a0 += w0 * bf2f(r0.x) + w1 * bf2f(r1.x) + w2 * bf2f(r2.x) + w3 * bf2f(r3.x);
        a1 += w0 * bf2f(r0.y) + w1 * bf2f(r1.y) + w2 * bf2f(r2.y) + w3 * bf2f(r3.y);
        a2 += w0 * bf2f(r0.z) + w1 * bf2f(r1.z) + w2 * bf2f(r2.z) + w3 * bf2f(r3.z);
        a3 += w0 * bf2f(r0.w) + w1 * bf2f(r1.w) + w2 * bf2f(r2.w) + w3 * bf2f(r3.w);
    }
    for (; i < e; ++i) {
        int2 ed = csr[i];
        float w0 = __int_as_float(ed.y);
        ushort4 r = *reinterpret_cast<const ushort4*>(&hin[(size_t)ed.x * gs + f4]);
        a0 += w0 * bf2f(r.x); a1 += w0 * bf2f(r.y);
        a2 += w0 * bf2f(r.z); a3 += w0 * bf2f(r.w);
    }
    ushort4 b;
    b.x = f2bf(a0); b.y = f2bf(a1); b.z = f2bf(a2); b.w = f2bf(a3);
    *reinterpret_cast<ushort4*>(&bout[(size_t)node * os + f4]) = b;
}

// ---------------- propagation d=4 with add (fp32) ----------------
__global__ __launch_bounds__(256) void k_prop4_add(const float* __restrict__ tin, int tin_stride, int tin_off,
                                                   const float* __restrict__ Z, int zcol,
                                                   const float* __restrict__ bias,
                                                   float* __restrict__ tout,
                                                   const int* __restrict__ row_ptr,
                                                   const int2* __restrict__ csr, int N) {
    int node = blockIdx.x * 64 + (threadIdx.x >> 2);
    int j = threadIdx.x & 3;
    if (node >= N) return;
    int s = row_ptr[node], e = row_ptr[node + 1];
    float acc = Z[(size_t)node * 16 + zcol + j];
    if (bias) acc += bias[j];
    for (int i = s; i < e; ++i) {
        int2 ed = csr[i];
        acc += __int_as_float(ed.y) * tin[(size_t)ed.x * tin_stride + tin_off + j];
    }
    tout[(size_t)node * 4 + j] = acc;
}

// ---------------- weight prep: Wt[c][kk*din+i] = bf16(W[kk][i][c]) ----------------
__global__ void k_wprep(const float* __restrict__ W, unsigned short* __restrict__ Wt, int din) {
    int K = 4 * din;
    int total = K * 128;
    int t = blockIdx.x * blockDim.x + threadIdx.x;
    if (t >= total) return;
    int c = t / K, rem = t - c * K;
    int kk = rem / din, i = rem - kk * din;
    Wt[t] = f2bf(W[(size_t)(kk * din + i) * 128 + c]);
}

// ---------------- MFMA GEMM: C(Mx128)bf16 = relu(A(MxK)bf16 @ Bt(128xK)^T + bias) ----------------
// A split: cols [0,ksplit) from A0 (stride as0), cols [ksplit,K) from A1 (stride as1).
__global__ __launch_bounds__(256) void k_mfma_gemm(const unsigned short* __restrict__ A0, int as0,
                                                   const unsigned short* __restrict__ A1, int as1,
                                                   int ksplit, int K,
                                                   const unsigned short* __restrict__ Bt,
                                                   const float* __restrict__ bias,
                                                   unsigned short* __restrict__ Cout, int M) {
    __shared__ unsigned short As[128][72];   // +8 pad: 36 dwords/row -> 2-way max on b128 reads
    __shared__ unsigned short Bs[128][72];
    int tid = threadIdx.x;
    int r0 = blockIdx.x * 128;
    int wid = tid >> 6, lane = tid & 63;
    int wm = (wid >> 1) * 64, wn = (wid & 1) * 64;     // 2x2 wave grid, 64x64 each
    f32x4v acc[4][4];
    #pragma unroll
    for (int a = 0; a < 4; ++a)
        #pragma unroll
        for (int b = 0; b < 4; ++b) acc[a][b] = (f32x4v){0.f, 0.f, 0.f, 0.f};

    int rsel = lane & 15, ksel = (lane >> 4) * 8;

    for (int kt = 0; kt < K; kt += 64) {
        const unsigned short* Abase; int astr, kb;
        if (kt < ksplit) { Abase = A0; astr = as0; kb = kt; }
        else             { Abase = A1; astr = as1; kb = kt - ksplit; }
        #pragma unroll
        for (int i = 0; i < 4; ++i) {
            int c = tid + i * 256;             // 1024 chunks of 16B
            int row = c >> 3, off = (c & 7) * 8;
            int gr = r0 + row;
            int4 v = make_int4(0, 0, 0, 0);
            if (gr < M) v = *reinterpret_cast<const int4*>(Abase + (size_t)gr * astr + kb + off);
            *reinterpret_cast<int4*>(&As[row][off]) = v;
            int4 w = *reinterpret_cast<const int4*>(Bt + (size_t)row * K + kt + off);
            *reinterpret_cast<int4*>(&Bs[row][off]) = w;
        }
        __syncthreads();
        #pragma unroll
        for (int kc = 0; kc < 64; kc += 32) {
            bf16x8v af[4], bf[4];
            #pragma unroll
            for (int f = 0; f < 4; ++f) {
                af[f] = *reinterpret_cast<const bf16x8v*>(&As[wm + f * 16 + rsel][kc + ksel]);
                bf[f] = *reinterpret_cast<const bf16x8v*>(&Bs[wn + f * 16 + rsel][kc + ksel]);
            }
            #pragma unroll
            for (int mf = 0; mf < 4; ++mf)
                #pragma unroll
                for (int nf = 0; nf < 4; ++nf)
                    acc[mf][nf] = __builtin_amdgcn_mfma_f32_16x16x32_bf16(af[mf], bf[nf], acc[mf][nf], 0, 0, 0);
        }
        __syncthreads();
    }
    // epilogue: C/D layout col=lane&15, row=(lane>>4)*4+reg (m89-verified)
    int col_l = lane & 15, rgrp = (lane >> 4) * 4;
    #pragma unroll
    for (int nf = 0; nf < 4; ++nf) {
        int col = wn + nf * 16 + col_l;
        float bv = bias[col];
        #pragma unroll
        for (int mf = 0; mf < 4; ++mf) {
            #pragma unroll
            for (int j = 0; j < 4; ++j) {
                int row = r0 + wm + mf * 16 + rgrp + j;
                if (row < M) {
                    float v = fmaxf(acc[mf][nf][j] + bv, 0.f);
                    Cout[(size_t)row * 128 + col] = f2bf(v);
                }
            }
        }
    }
}

// ---------------- Z GEMM: Z(Mx16) = A(Mx128 bf16) @ W3'(128x16) ----------------
__global__ __launch_bounds__(256) void k_gemm_z(const unsigned short* __restrict__ Ab,
                                                const float* __restrict__ W3,
                                                float* __restrict__ Z, int M) {
    __shared__ float hs[64][132];
    __shared__ float wsm[128][16];
    int tid = threadIdx.x;
    int row0 = blockIdx.x * 64;
    for (int t = tid; t < 2048; t += 256) {
        int k = t >> 9, i = (t >> 2) & 127, j = t & 3;
        wsm[i][k * 4 + j] = W3[t];
    }
    #pragma unroll
    for (int it = 0; it < 8; ++it) {
        int f4 = it * 256 + tid;
        int r = f4 >> 5;
        int c4 = (f4 & 31) * 4;
        int gr = row0 + r;
        float4 v = make_float4(0.f, 0.f, 0.f, 0.f);
        if (gr < M) {
            ushort4 u = *reinterpret_cast<const ushort4*>(&Ab[(size_t)gr * 128 + c4]);
            v = make_float4(bf2f(u.x), bf2f(u.y), bf2f(u.z), bf2f(u.w));
        }
        hs[r][c4] = v.x; hs[r][c4 + 1] = v.y; hs[r][c4 + 2] = v.z; hs[r][c4 + 3] = v.w;
    }
    __syncthreads();
    int r = tid >> 2, c0 = (tid & 3) * 4;
    float acc[4] = {};
    #pragma unroll 4
    for (int i = 0; i < 128; ++i) {
        float a = hs[r][i];
        #pragma unroll
        for (int j = 0; j < 4; ++j) acc[j] += a * wsm[i][c0 + j];
    }
    int gr = row0 + r;
    if (gr < M) {
        float4 v; v.x = acc[0]; v.y = acc[1]; v.z = acc[2]; v.w = acc[3];
        *reinterpret_cast<float4*>(&Z[(size_t)gr * 16 + c0]) = v;
    }
}

// ---------------- launch ----------------
extern "C" void kernel_launch(void* const* d_in, const int* in_sizes, int n_in,
                              void* d_out, int out_size, void* d_ws, size_t ws_size,
                              hipStream_t stream) {
    const float* x  = (const float*)d_in[0];
    const int*   ei = (const int*)d_in[1];
    const float* ew = (const float*)d_in[2];
    const float* W0 = (const float*)d_in[3];
    const float* b0 = (const float*)d_in[4];
    const float* W1 = (const float*)d_in[5];
    const float* b1 = (const float*)d_in[6];
    const float* W2 = (const float*)d_in[7];
    const float* b2 = (const float*)d_in[8];
    const float* W3 = (const float*)d_in[9];
    const float* b3 = (const float*)d_in[10];
    float* out = (float*)d_out;

    const int N = in_sizes[0] / 16;   // 100000
    const int E = in_sizes[2];        // 3200000
    const int* src = ei;
    const int* dst = ei + E;

    char* ws = (char*)d_ws;
    size_t off = 0;
    auto take = [&](size_t bytes) -> void* {
        void* p = ws + off;
        off = (off + bytes + 255) & ~(size_t)255;
        return p;
    };
    unsigned short* S   = (unsigned short*)take((size_t)N * 384 * 2);  // hop slots 1..3 (stride 384)
    unsigned short* Qa  = (unsigned short*)take((size_t)N * 128 * 2);  // compact h
    unsigned short* Qb  = (unsigned short*)take((size_t)N * 128 * 2);
    unsigned short* S64 = (unsigned short*)take((size_t)N * 64 * 2);   // layer0 stack (stride 64)
    int2*  csr     = (int2*) take((size_t)E * 8);
    int2*  dc      = (int2*) take((size_t)N * 8);
    float* dis     = (float*)take((size_t)N * 4);
    int*   row_ptr = (int*)  take((size_t)(N + 1) * 4);
    int*   cursor  = (int*)  take((size_t)N * 4);
    int*   bsum    = (int*)  take(1024);
    int*   boff    = (int*)  take(1024);
    float* P16     = (float*)take((size_t)N * 16 * 4);
    float* Q16     = (float*)take((size_t)N * 16 * 4);
    float* Z       = (float*)take((size_t)N * 16 * 4);
    float* T1      = (float*)take((size_t)N * 4 * 4);
    float* T2      = (float*)take((size_t)N * 4 * 4);
    unsigned short* Wt0 = (unsigned short*)take(64 * 128 * 2);
    unsigned short* Wt1 = (unsigned short*)take(512 * 128 * 2);
    unsigned short* Wt2 = (unsigned short*)take(512 * 128 * 2);

    // ---- build norm + CSR ----
    hipMemsetAsync(dc, 0, (size_t)N * 8, stream);
    k_edge_deg<<<2048, 256, 0, stream>>>(src, dst, ew, dc, E);
    k_dis<<<(N + 255) / 256, 256, 0, stream>>>(dc, dis, N);
    int nsb = (N + 1023) / 1024;
    k_scan1<<<nsb, 256, 0, stream>>>(dc, bsum, N);
    k_scan2<<<1, 64, 0, stream>>>(bsum, boff, nsb, &row_ptr[N]);
    k_scan3<<<nsb, 256, 0, stream>>>(dc, boff, row_ptr, cursor, N);
    k_fill_csr<<<2048, 256, 0, stream>>>(src, dst, ew, dis, cursor, csr, E);

    // ---- weight prep ----
    k_wprep<<<(64 * 128 + 255) / 256, 256, 0, stream>>>(W0, Wt0, 16);
    k_wprep<<<(512 * 128 + 255) / 256, 256, 0, stream>>>(W1, Wt1, 128);
    k_wprep<<<(512 * 128 + 255) / 256, 256, 0, stream>>>(W2, Wt2, 128);

    int gmfma = (N + 127) / 128;
    int gp128 = (N + 7) / 8;
    int gp16  = (N + 7) / 8;

    // ---- layer 0: 16 -> 128 ----
    k_xcast<<<(N * 16 + 255) / 256, 256, 0, stream>>>(x, S64, N);
    k_prop16<<<gp16, 128, 0, stream>>>(x,   P16,     S64 + 16, row_ptr, csr, N);
    k_prop16<<<gp16, 128, 0, stream>>>(P16, Q16,     S64 + 32, row_ptr, csr, N);
    k_prop16<<<gp16, 128, 0, stream>>>(Q16, nullptr, S64 + 48, row_ptr, csr, N);
    k_mfma_gemm<<<gmfma, 256, 0, stream>>>(S64, 64, nullptr, 0, 64, 64, Wt0, b0, Qa, N);

    // ---- layer 1: 128 -> 128 ----
    k_prop128b<<<gp128, 256, 0, stream>>>(Qa, 128,     S + 0,   384, row_ptr, csr, N);
    k_prop128b<<<gp128, 256, 0, stream>>>(S + 0, 384,  S + 128, 384, row_ptr, csr, N);
    k_prop128b<<<gp128, 256, 0, stream>>>(S + 128, 384, S + 256, 384, row_ptr, csr, N);
    k_mfma_gemm<<<gmfma, 256, 0, stream>>>(Qa, 128, S, 384, 128, 512, Wt1, b1, Qb, N);

    // ---- layer 2: 128 -> 128 ----
    k_prop128b<<<gp128, 256, 0, stream>>>(Qb, 128,     S + 0,   384, row_ptr, csr, N);
    k_prop128b<<<gp128, 256, 0, stream>>>(S + 0, 384,  S + 128, 384, row_ptr, csr, N);
    k_prop128b<<<gp128, 256, 0, stream>>>(S + 128, 384, S + 256, 384, row_ptr, csr, N);
    k_mfma_gemm<<<gmfma, 256, 0, stream>>>(Qb, 128, S, 384, 128, 512, Wt2, b2, Qa, N);

    // ---- layer 3: 128 -> 4 via projected Horner ----
    {
        k_gemm_z<<<(N + 63) / 64, 256, 0, stream>>>(Qa, W3, Z, N);
        int g = (N + 63) / 64;
        k_prop4_add<<<g, 256, 0, stream>>>(Z, 16, 12, Z, 8, nullptr, T1, row_ptr, csr, N);
        k_prop4_add<<<g, 256, 0, stream>>>(T1, 4, 0, Z, 4, nullptr, T2, row_ptr, csr, N);
        k_prop4_add<<<g, 256, 0, stream>>>(T2, 4, 0, Z, 0, b3, out, row_ptr, csr, N);
    }
}

// Round 5
// 1475.010 us; speedup vs baseline: 3.9521x; 1.1442x over previous
//
#include <hip/hip_runtime.h>

// TAGConv L3: N=100000, E=3200000, K=3. dims (16->128)(128->128)(128->128)(128->4).
// R4: packed u64 far-atomic (deg fixed-point<<12 | count) whose return value gives each
//     edge's rank within dst -> atomic-free CSR fill; prop128b unroll 8.
//     Stacked-K bf16 MFMA GEMM per layer; layer 3 d=4 Horner.

typedef __attribute__((ext_vector_type(8))) short bf16x8v;   // 8 bf16 = 4 VGPR
typedef __attribute__((ext_vector_type(4))) float f32x4v;

__device__ __forceinline__ float bf2f(unsigned short u) {
    return __uint_as_float(((unsigned int)u) << 16);
}
__device__ __forceinline__ unsigned short f2bf(float f) {
    unsigned int u = __float_as_uint(f);
    u = (u + 0x7fff + ((u >> 16) & 1)) >> 16;   // RNE
    return (unsigned short)u;
}

// ---------------- pass 1: packed deg/count atomic + per-edge rank ----------------
// dc[d] = (sum_fx(ew) << 12) | count ; rank[e] = count before this edge (low 12 bits of old)
__global__ void k_edge_deg(const int* __restrict__ dst, const float* __restrict__ ew,
                           unsigned long long* __restrict__ dc,
                           unsigned short* __restrict__ rank, int E) {
    int stride = gridDim.x * blockDim.x;
    for (int e = blockIdx.x * blockDim.x + threadIdx.x; e < E; e += stride) {
        int d = dst[e];
        // ew in [0,1): fx = trunc(ew * 2^40), exact integer accumulation
        unsigned long long fx = (unsigned long long)(ew[e] * 0x1p40f);
        unsigned long long old = atomicAdd(&dc[d], (fx << 12) | 1ULL);
        rank[e] = (unsigned short)(old & 0xFFFULL);
    }
}

__global__ void k_dis(const unsigned long long* __restrict__ dc, float* __restrict__ dis, int N) {
    int i = blockIdx.x * blockDim.x + threadIdx.x;
    if (i < N) {
        float d = (float)(dc[i] >> 12) * 0x1p-40f;
        dis[i] = d > 0.f ? rsqrtf(d) : 0.f;
    }
}

// ---------------- scan for row_ptr (3-phase) ----------------
__global__ void k_scan1(const unsigned long long* __restrict__ dc, int* __restrict__ bsum, int N) {
    __shared__ int s[256];
    int tid = threadIdx.x;
    int base = blockIdx.x * 1024 + tid * 4;
    int t = 0;
    #pragma unroll
    for (int i = 0; i < 4; ++i) { int idx = base + i; if (idx < N) t += (int)(dc[idx] & 0xFFFULL); }
    s[tid] = t; __syncthreads();
    for (int off = 128; off > 0; off >>= 1) {
        if (tid < off) s[tid] += s[tid + off];
        __syncthreads();
    }
    if (tid == 0) bsum[blockIdx.x] = s[0];
}

__global__ void k_scan2(const int* __restrict__ bsum, int* __restrict__ boff,
                        int nb, int* __restrict__ row_ptr_last) {
    if (threadIdx.x == 0) {
        int run = 0;
        for (int i = 0; i < nb; ++i) { boff[i] = run; run += bsum[i]; }
        *row_ptr_last = run;
    }
}

__global__ void k_scan3(const unsigned long long* __restrict__ dc, const int* __restrict__ boff,
                        int* __restrict__ row_ptr, int N) {
    __shared__ int s[256];
    int tid = threadIdx.x;
    int base = blockIdx.x * 1024 + tid * 4;
    int v[4]; int t = 0;
    #pragma unroll
    for (int i = 0; i < 4; ++i) { int idx = base + i; v[i] = (idx < N) ? (int)(dc[idx] & 0xFFFULL) : 0; t += v[i]; }
    s[tid] = t; __syncthreads();
    for (int off = 1; off < 256; off <<= 1) {
        int add = (tid >= off) ? s[tid - off] : 0;
        __syncthreads();
        s[tid] += add;
        __syncthreads();
    }
    int g = boff[blockIdx.x] + (s[tid] - t);   // exclusive prefix
    #pragma unroll
    for (int i = 0; i < 4; ++i) {
        int idx = base + i;
        if (idx < N) row_ptr[idx] = g;
        g += v[i];
    }
}

// ---------------- pass 2: atomic-free CSR fill via row_ptr[dst]+rank ----------------
__global__ void k_fill_csr(const int* __restrict__ src, const int* __restrict__ dst,
                           const float* __restrict__ ew, const float* __restrict__ dis,
                           const int* __restrict__ row_ptr, const unsigned short* __restrict__ rank,
                           int2* __restrict__ csr, int E) {
    int stride = gridDim.x * blockDim.x;
    for (int e = blockIdx.x * blockDim.x + threadIdx.x; e < E; e += stride) {
        int d = dst[e];
        int s = src[e];
        int pos = row_ptr[d] + rank[e];
        float w = dis[s] * ew[e] * dis[d];
        csr[pos] = make_int2(s, __float_as_int(w));
    }
}

// ---------------- x -> bf16 stack slot0 (d=16, stride 64) ----------------
__global__ void k_xcast(const float* __restrict__ x, unsigned short* __restrict__ s64, int N) {
    int i = blockIdx.x * blockDim.x + threadIdx.x;
    if (i < N * 16) {
        int n = i >> 4, f = i & 15;
        s64[n * 64 + f] = f2bf(x[i]);
    }
}

// ---------------- propagation d=16 (fp32 chain + bf16 stack write, stride 64) ----------------
__global__ __launch_bounds__(128) void k_prop16(const float* __restrict__ hin,
                                                float* __restrict__ hout,
                                                unsigned short* __restrict__ bout,
                                                const int* __restrict__ row_ptr,
                                                const int2* __restrict__ csr, int N) {
    int node = blockIdx.x * 8 + threadIdx.x / 16;
    int f = threadIdx.x % 16;
    if (node >= N) return;
    int s = row_ptr[node], e = row_ptr[node + 1];
    float acc = 0.f;
    for (int i = s; i < e; ++i) {
        int2 ed = csr[i];
        acc += __int_as_float(ed.y) * hin[(size_t)ed.x * 16 + f];
    }
    if (hout) hout[(size_t)node * 16 + f] = acc;
    bout[(size_t)node * 64 + f] = f2bf(acc);
}

// ---------------- propagation d=128 bf16: 32 lanes/node, strided in/out, unroll 8 ----------------
__global__ __launch_bounds__(256) void k_prop128b(const unsigned short* __restrict__ hin, int gs,
                                                  unsigned short* __restrict__ bout, int os,
                                                  const int* __restrict__ row_ptr,
                                                  const int2* __restrict__ csr, int N) {
    int node = blockIdx.x * 8 + (threadIdx.x >> 5);
    int f4 = (threadIdx.x & 31) * 4;
    if (node >= N) return;
    int s = row_ptr[node], e = row_ptr[node + 1];
    float a0 = 0.f, a1 = 0.f, a2 = 0.f, a3 = 0.f;
    int i = s;
    for (; i + 8 <= e; i += 8) {
        int2 ed[8]; ushort4 r[8];
        #pragma unroll
        for (int u = 0; u < 8; ++u) ed[u] = csr[i + u];
        #pragma unroll
        for (int u = 0; u < 8; ++u)
            r[u] = *reinterpret_cast<const ushort4*>(&hin[(size_t)ed[u].x * gs + f4]);
        #pragma unroll
        for (int u = 0; u < 8; ++u) {
            float w = __int_as_float(ed[u].y);
            a0 += w * bf2f(r[u].x); a1 += w * bf2f(r[u].y);
            a2 += w * bf2f(r[u].z); a3 += w * bf2f(r[u].w);
        }
    }
    for (; i < e; ++i) {
        int2 ed = csr[i];
        float w0 = __int_as_float(ed.y);
        ushort4 r = *reinterpret_cast<const ushort4*>(&hin[(size_t)ed.x * gs + f4]);
        a0 += w0 * bf2f(r.x); a1 += w0 * bf2f(r.y);
        a2 += w0 * bf2f(r.z); a3 += w0 * bf2f(r.w);
    }
    ushort4 b;
    b.x = f2bf(a0); b.y = f2bf(a1); b.z = f2bf(a2); b.w = f2bf(a3);
    *reinterpret_cast<ushort4*>(&bout[(size_t)node * os + f4]) = b;
}

// ---------------- propagation d=4 with add (fp32) ----------------
__global__ __launch_bounds__(256) void k_prop4_add(const float* __restrict__ tin, int tin_stride, int tin_off,
                                                   const float* __restrict__ Z, int zcol,
                                                   const float* __restrict__ bias,
                                                   float* __restrict__ tout,
                                                   const int* __restrict__ row_ptr,
                                                   const int2* __restrict__ csr, int N) {
    int node = blockIdx.x * 64 + (threadIdx.x >> 2);
    int j = threadIdx.x & 3;
    if (node >= N) return;
    int s = row_ptr[node], e = row_ptr[node + 1];
    float acc = Z[(size_t)node * 16 + zcol + j];
    if (bias) acc += bias[j];
    for (int i = s; i < e; ++i) {
        int2 ed = csr[i];
        acc += __int_as_float(ed.y) * tin[(size_t)ed.x * tin_stride + tin_off + j];
    }
    tout[(size_t)node * 4 + j] = acc;
}

// ---------------- weight prep: Wt[c][kk*din+i] = bf16(W[kk][i][c]) ----------------
__global__ void k_wprep(const float* __restrict__ W, unsigned short* __restrict__ Wt, int din) {
    int K = 4 * din;
    int total = K * 128;
    int t = blockIdx.x * blockDim.x + threadIdx.x;
    if (t >= total) return;
    int c = t / K, rem = t - c * K;
    int kk = rem / din, i = rem - kk * din;
    Wt[t] = f2bf(W[(size_t)(kk * din + i) * 128 + c]);
}

// ---------------- MFMA GEMM: C(Mx128)bf16 = relu(A(MxK)bf16 @ Bt(128xK)^T + bias) ----------------
__global__ __launch_bounds__(256) void k_mfma_gemm(const unsigned short* __restrict__ A0, int as0,
                                                   const unsigned short* __restrict__ A1, int as1,
                                                   int ksplit, int K,
                                                   const unsigned short* __restrict__ Bt,
                                                   const float* __restrict__ bias,
                                                   unsigned short* __restrict__ Cout, int M) {
    __shared__ unsigned short As[128][72];
    __shared__ unsigned short Bs[128][72];
    int tid = threadIdx.x;
    int r0 = blockIdx.x * 128;
    int wid = tid >> 6, lane = tid & 63;
    int wm = (wid >> 1) * 64, wn = (wid & 1) * 64;
    f32x4v acc[4][4];
    #pragma unroll
    for (int a = 0; a < 4; ++a)
        #pragma unroll
        for (int b = 0; b < 4; ++b) acc[a][b] = (f32x4v){0.f, 0.f, 0.f, 0.f};

    int rsel = lane & 15, ksel = (lane >> 4) * 8;

    for (int kt = 0; kt < K; kt += 64) {
        const unsigned short* Abase; int astr, kb;
        if (kt < ksplit) { Abase = A0; astr = as0; kb = kt; }
        else             { Abase = A1; astr = as1; kb = kt - ksplit; }
        #pragma unroll
        for (int i = 0; i < 4; ++i) {
            int c = tid + i * 256;
            int row = c >> 3, off = (c & 7) * 8;
            int gr = r0 + row;
            int4 v = make_int4(0, 0, 0, 0);
            if (gr < M) v = *reinterpret_cast<const int4*>(Abase + (size_t)gr * astr + kb + off);
            *reinterpret_cast<int4*>(&As[row][off]) = v;
            int4 w = *reinterpret_cast<const int4*>(Bt + (size_t)row * K + kt + off);
            *reinterpret_cast<int4*>(&Bs[row][off]) = w;
        }
        __syncthreads();
        #pragma unroll
        for (int kc = 0; kc < 64; kc += 32) {
            bf16x8v af[4], bfv[4];
            #pragma unroll
            for (int f = 0; f < 4; ++f) {
                af[f]  = *reinterpret_cast<const bf16x8v*>(&As[wm + f * 16 + rsel][kc + ksel]);
                bfv[f] = *reinterpret_cast<const bf16x8v*>(&Bs[wn + f * 16 + rsel][kc + ksel]);
            }
            #pragma unroll
            for (int mf = 0; mf < 4; ++mf)
                #pragma unroll
                for (int nf = 0; nf < 4; ++nf)
                    acc[mf][nf] = __builtin_amdgcn_mfma_f32_16x16x32_bf16(af[mf], bfv[nf], acc[mf][nf], 0, 0, 0);
        }
        __syncthreads();
    }
    int col_l = lane & 15, rgrp = (lane >> 4) * 4;
    #pragma unroll
    for (int nf = 0; nf < 4; ++nf) {
        int col = wn + nf * 16 + col_l;
        float bv = bias[col];
        #pragma unroll
        for (int mf = 0; mf < 4; ++mf) {
            #pragma unroll
            for (int j = 0; j < 4; ++j) {
                int row = r0 + wm + mf * 16 + rgrp + j;
                if (row < M) {
                    float v = fmaxf(acc[mf][nf][j] + bv, 0.f);
                    Cout[(size_t)row * 128 + col] = f2bf(v);
                }
            }
        }
    }
}

// ---------------- Z GEMM: Z(Mx16) = A(Mx128 bf16) @ W3'(128x16) ----------------
__global__ __launch_bounds__(256) void k_gemm_z(const unsigned short* __restrict__ Ab,
                                                const float* __restrict__ W3,
                                                float* __restrict__ Z, int M) {
    __shared__ float hs[64][132];
    __shared__ float wsm[128][16];
    int tid = threadIdx.x;
    int row0 = blockIdx.x * 64;
    for (int t = tid; t < 2048; t += 256) {
        int k = t >> 9, i = (t >> 2) & 127, j = t & 3;
        wsm[i][k * 4 + j] = W3[t];
    }
    #pragma unroll
    for (int it = 0; it < 8; ++it) {
        int f4 = it * 256 + tid;
        int r = f4 >> 5;
        int c4 = (f4 & 31) * 4;
        int gr = row0 + r;
        float4 v = make_float4(0.f, 0.f, 0.f, 0.f);
        if (gr < M) {
            ushort4 u = *reinterpret_cast<const ushort4*>(&Ab[(size_t)gr * 128 + c4]);
            v = make_float4(bf2f(u.x), bf2f(u.y), bf2f(u.z), bf2f(u.w));
        }
        hs[r][c4] = v.x; hs[r][c4 + 1] = v.y; hs[r][c4 + 2] = v.z; hs[r][c4 + 3] = v.w;
    }
    __syncthreads();
    int r = tid >> 2, c0 = (tid & 3) * 4;
    float acc[4] = {};
    #pragma unroll 4
    for (int i = 0; i < 128; ++i) {
        float a = hs[r][i];
        #pragma unroll
        for (int j = 0; j < 4; ++j) acc[j] += a * wsm[i][c0 + j];
    }
    int gr = row0 + r;
    if (gr < M) {
        float4 v; v.x = acc[0]; v.y = acc[1]; v.z = acc[2]; v.w = acc[3];
        *reinterpret_cast<float4*>(&Z[(size_t)gr * 16 + c0]) = v;
    }
}

// ---------------- launch ----------------
extern "C" void kernel_launch(void* const* d_in, const int* in_sizes, int n_in,
                              void* d_out, int out_size, void* d_ws, size_t ws_size,
                              hipStream_t stream) {
    const float* x  = (const float*)d_in[0];
    const int*   ei = (const int*)d_in[1];
    const float* ew = (const float*)d_in[2];
    const float* W0 = (const float*)d_in[3];
    const float* b0 = (const float*)d_in[4];
    const float* W1 = (const float*)d_in[5];
    const float* b1 = (const float*)d_in[6];
    const float* W2 = (const float*)d_in[7];
    const float* b2 = (const float*)d_in[8];
    const float* W3 = (const float*)d_in[9];
    const float* b3 = (const float*)d_in[10];
    float* out = (float*)d_out;

    const int N = in_sizes[0] / 16;   // 100000
    const int E = in_sizes[2];        // 3200000
    const int* src = ei;
    const int* dst = ei + E;

    char* ws = (char*)d_ws;
    size_t off = 0;
    auto take = [&](size_t bytes) -> void* {
        void* p = ws + off;
        off = (off + bytes + 255) & ~(size_t)255;
        return p;
    };
    unsigned short* S   = (unsigned short*)take((size_t)N * 384 * 2);  // hop slots 1..3 (stride 384)
    unsigned short* Qa  = (unsigned short*)take((size_t)N * 128 * 2);
    unsigned short* Qb  = (unsigned short*)take((size_t)N * 128 * 2);
    unsigned short* S64 = (unsigned short*)take((size_t)N * 64 * 2);
    int2*  csr     = (int2*) take((size_t)E * 8);
    unsigned long long* dc = (unsigned long long*)take((size_t)N * 8);
    unsigned short* rank = (unsigned short*)take((size_t)E * 2);
    float* dis     = (float*)take((size_t)N * 4);
    int*   row_ptr = (int*)  take((size_t)(N + 1) * 4);
    int*   bsum    = (int*)  take(1024);
    int*   boff    = (int*)  take(1024);
    float* P16     = (float*)take((size_t)N * 16 * 4);
    float* Q16     = (float*)take((size_t)N * 16 * 4);
    float* Z       = (float*)take((size_t)N * 16 * 4);
    float* T1      = (float*)take((size_t)N * 4 * 4);
    float* T2      = (float*)take((size_t)N * 4 * 4);
    unsigned short* Wt0 = (unsigned short*)take(64 * 128 * 2);
    unsigned short* Wt1 = (unsigned short*)take(512 * 128 * 2);
    unsigned short* Wt2 = (unsigned short*)take(512 * 128 * 2);

    // ---- build norm + CSR (one packed atomic pass, atomic-free fill) ----
    hipMemsetAsync(dc, 0, (size_t)N * 8, stream);
    k_edge_deg<<<2048, 256, 0, stream>>>(dst, ew, dc, rank, E);
    k_dis<<<(N + 255) / 256, 256, 0, stream>>>(dc, dis, N);
    int nsb = (N + 1023) / 1024;
    k_scan1<<<nsb, 256, 0, stream>>>(dc, bsum, N);
    k_scan2<<<1, 64, 0, stream>>>(bsum, boff, nsb, &row_ptr[N]);
    k_scan3<<<nsb, 256, 0, stream>>>(dc, boff, row_ptr, N);
    k_fill_csr<<<2048, 256, 0, stream>>>(src, dst, ew, dis, row_ptr, rank, csr, E);

    // ---- weight prep ----
    k_wprep<<<(64 * 128 + 255) / 256, 256, 0, stream>>>(W0, Wt0, 16);
    k_wprep<<<(512 * 128 + 255) / 256, 256, 0, stream>>>(W1, Wt1, 128);
    k_wprep<<<(512 * 128 + 255) / 256, 256, 0, stream>>>(W2, Wt2, 128);

    int gmfma = (N + 127) / 128;
    int gp128 = (N + 7) / 8;
    int gp16  = (N + 7) / 8;

    // ---- layer 0: 16 -> 128 ----
    k_xcast<<<(N * 16 + 255) / 256, 256, 0, stream>>>(x, S64, N);
    k_prop16<<<gp16, 128, 0, stream>>>(x,   P16,     S64 + 16, row_ptr, csr, N);
    k_prop16<<<gp16, 128, 0, stream>>>(P16, Q16,     S64 + 32, row_ptr, csr, N);
    k_prop16<<<gp16, 128, 0, stream>>>(Q16, nullptr, S64 + 48, row_ptr, csr, N);
    k_mfma_gemm<<<gmfma, 256, 0, stream>>>(S64, 64, nullptr, 0, 64, 64, Wt0, b0, Qa, N);

    // ---- layer 1: 128 -> 128 ----
    k_prop128b<<<gp128, 256, 0, stream>>>(Qa, 128,      S + 0,   384, row_ptr, csr, N);
    k_prop128b<<<gp128, 256, 0, stream>>>(S + 0, 384,   S + 128, 384, row_ptr, csr, N);
    k_prop128b<<<gp128, 256, 0, stream>>>(S + 128, 384, S + 256, 384, row_ptr, csr, N);
    k_mfma_gemm<<<gmfma, 256, 0, stream>>>(Qa, 128, S, 384, 128, 512, Wt1, b1, Qb, N);

    // ---- layer 2: 128 -> 128 ----
    k_prop128b<<<gp128, 256, 0, stream>>>(Qb, 128,      S + 0,   384, row_ptr, csr, N);
    k_prop128b<<<gp128, 256, 0, stream>>>(S + 0, 384,   S + 128, 384, row_ptr, csr, N);
    k_prop128b<<<gp128, 256, 0, stream>>>(S + 128, 384, S + 256, 384, row_ptr, csr, N);
    k_mfma_gemm<<<gmfma, 256, 0, stream>>>(Qb, 128, S, 384, 128, 512, Wt2, b2, Qa, N);

    // ---- layer 3: 128 -> 4 via projected Horner ----
    {
        k_gemm_z<<<(N + 63) / 64, 256, 0, stream>>>(Qa, W3, Z, N);
        int g = (N + 63) / 64;
        k_prop4_add<<<g, 256, 0, stream>>>(Z, 16, 12, Z, 8, nullptr, T1, row_ptr, csr, N);
        k_prop4_add<<<g, 256, 0, stream>>>(T1, 4, 0, Z, 4, nullptr, T2, row_ptr, csr, N);
        k_prop4_add<<<g, 256, 0, stream>>>(T2, 4, 0, Z, 0, b3, out, row_ptr, csr, N);
    }
}

// Round 6
// 1405.415 us; speedup vs baseline: 4.1478x; 1.0495x over previous
//
#include <hip/hip_runtime.h>

// TAGConv L3: N=100000, E=3200000, K=3. dims (16->128)(128->128)(128->128)(128->4).
// R5: prop128b = 16 lanes/node x uint4 (16B) gathers, dword bf16-pair unpack, unroll 4;
//     layer-0 hop chain fully bf16 (4 lanes/node x 8B). R4's packed-u64 atomic CSR build;
//     stacked-K bf16 MFMA GEMM per layer; layer 3 d=4 Horner.

typedef __attribute__((ext_vector_type(8))) short bf16x8v;   // 8 bf16 = 4 VGPR
typedef __attribute__((ext_vector_type(4))) float f32x4v;

__device__ __forceinline__ float bf2f(unsigned short u) {
    return __uint_as_float(((unsigned int)u) << 16);
}
__device__ __forceinline__ float bflo(unsigned int u) {       // low bf16 of dword
    return __uint_as_float(u << 16);
}
__device__ __forceinline__ float bfhi(unsigned int u) {       // high bf16 of dword
    return __uint_as_float(u & 0xffff0000u);
}
__device__ __forceinline__ unsigned short f2bf(float f) {
    unsigned int u = __float_as_uint(f);
    u = (u + 0x7fff + ((u >> 16) & 1)) >> 16;   // RNE
    return (unsigned short)u;
}

// ---------------- pass 1: packed deg/count atomic + per-edge rank ----------------
__global__ void k_edge_deg(const int* __restrict__ dst, const float* __restrict__ ew,
                           unsigned long long* __restrict__ dc,
                           unsigned short* __restrict__ rank, int E) {
    int stride = gridDim.x * blockDim.x;
    for (int e = blockIdx.x * blockDim.x + threadIdx.x; e < E; e += stride) {
        int d = dst[e];
        unsigned long long fx = (unsigned long long)(ew[e] * 0x1p40f);
        unsigned long long old = atomicAdd(&dc[d], (fx << 12) | 1ULL);
        rank[e] = (unsigned short)(old & 0xFFFULL);
    }
}

__global__ void k_dis(const unsigned long long* __restrict__ dc, float* __restrict__ dis, int N) {
    int i = blockIdx.x * blockDim.x + threadIdx.x;
    if (i < N) {
        float d = (float)(dc[i] >> 12) * 0x1p-40f;
        dis[i] = d > 0.f ? rsqrtf(d) : 0.f;
    }
}

// ---------------- scan for row_ptr (3-phase) ----------------
__global__ void k_scan1(const unsigned long long* __restrict__ dc, int* __restrict__ bsum, int N) {
    __shared__ int s[256];
    int tid = threadIdx.x;
    int base = blockIdx.x * 1024 + tid * 4;
    int t = 0;
    #pragma unroll
    for (int i = 0; i < 4; ++i) { int idx = base + i; if (idx < N) t += (int)(dc[idx] & 0xFFFULL); }
    s[tid] = t; __syncthreads();
    for (int off = 128; off > 0; off >>= 1) {
        if (tid < off) s[tid] += s[tid + off];
        __syncthreads();
    }
    if (tid == 0) bsum[blockIdx.x] = s[0];
}

__global__ void k_scan2(const int* __restrict__ bsum, int* __restrict__ boff,
                        int nb, int* __restrict__ row_ptr_last) {
    if (threadIdx.x == 0) {
        int run = 0;
        for (int i = 0; i < nb; ++i) { boff[i] = run; run += bsum[i]; }
        *row_ptr_last = run;
    }
}

__global__ void k_scan3(const unsigned long long* __restrict__ dc, const int* __restrict__ boff,
                        int* __restrict__ row_ptr, int N) {
    __shared__ int s[256];
    int tid = threadIdx.x;
    int base = blockIdx.x * 1024 + tid * 4;
    int v[4]; int t = 0;
    #pragma unroll
    for (int i = 0; i < 4; ++i) { int idx = base + i; v[i] = (idx < N) ? (int)(dc[idx] & 0xFFFULL) : 0; t += v[i]; }
    s[tid] = t; __syncthreads();
    for (int off = 1; off < 256; off <<= 1) {
        int add = (tid >= off) ? s[tid - off] : 0;
        __syncthreads();
        s[tid] += add;
        __syncthreads();
    }
    int g = boff[blockIdx.x] + (s[tid] - t);   // exclusive prefix
    #pragma unroll
    for (int i = 0; i < 4; ++i) {
        int idx = base + i;
        if (idx < N) row_ptr[idx] = g;
        g += v[i];
    }
}

// ---------------- pass 2: atomic-free CSR fill ----------------
__global__ void k_fill_csr(const int* __restrict__ src, const int* __restrict__ dst,
                           const float* __restrict__ ew, const float* __restrict__ dis,
                           const int* __restrict__ row_ptr, const unsigned short* __restrict__ rank,
                           int2* __restrict__ csr, int E) {
    int stride = gridDim.x * blockDim.x;
    for (int e = blockIdx.x * blockDim.x + threadIdx.x; e < E; e += stride) {
        int d = dst[e];
        int s = src[e];
        int pos = row_ptr[d] + rank[e];
        float w = dis[s] * ew[e] * dis[d];
        csr[pos] = make_int2(s, __float_as_int(w));
    }
}

// ---------------- x -> bf16 stack slot0 (d=16, stride 64) ----------------
__global__ void k_xcast(const float* __restrict__ x, unsigned short* __restrict__ s64, int N) {
    int i = blockIdx.x * blockDim.x + threadIdx.x;
    if (i < N * 16) {
        int n = i >> 4, f = i & 15;
        s64[n * 64 + f] = f2bf(x[i]);
    }
}

// ---------------- propagation d=16 bf16: 4 lanes/node, 8B loads, unroll 4 ----------------
__global__ __launch_bounds__(256) void k_prop16b(const unsigned short* __restrict__ hin,
                                                 unsigned short* __restrict__ bout,
                                                 const int* __restrict__ row_ptr,
                                                 const int2* __restrict__ csr, int N) {
    int node = blockIdx.x * 64 + (threadIdx.x >> 2);
    int f4 = (threadIdx.x & 3) * 4;
    if (node >= N) return;
    int s = row_ptr[node], e = row_ptr[node + 1];
    float a0 = 0.f, a1 = 0.f, a2 = 0.f, a3 = 0.f;
    int i = s;
    for (; i + 4 <= e; i += 4) {
        int2 ed[4]; uint2 r[4];
        #pragma unroll
        for (int u = 0; u < 4; ++u) ed[u] = csr[i + u];
        #pragma unroll
        for (int u = 0; u < 4; ++u)
            r[u] = *reinterpret_cast<const uint2*>(&hin[(size_t)ed[u].x * 64 + f4]);
        #pragma unroll
        for (int u = 0; u < 4; ++u) {
            float w = __int_as_float(ed[u].y);
            a0 += w * bflo(r[u].x); a1 += w * bfhi(r[u].x);
            a2 += w * bflo(r[u].y); a3 += w * bfhi(r[u].y);
        }
    }
    for (; i < e; ++i) {
        int2 ed = csr[i];
        float w = __int_as_float(ed.y);
        uint2 r = *reinterpret_cast<const uint2*>(&hin[(size_t)ed.x * 64 + f4]);
        a0 += w * bflo(r.x); a1 += w * bfhi(r.x);
        a2 += w * bflo(r.y); a3 += w * bfhi(r.y);
    }
    ushort4 b;
    b.x = f2bf(a0); b.y = f2bf(a1); b.z = f2bf(a2); b.w = f2bf(a3);
    *reinterpret_cast<ushort4*>(&bout[(size_t)node * 64 + f4]) = b;
}

// ---------------- propagation d=128 bf16: 16 lanes/node, 16B loads, unroll 4 ----------------
__global__ __launch_bounds__(256) void k_prop128b(const unsigned short* __restrict__ hin, int gs,
                                                  unsigned short* __restrict__ bout, int os,
                                                  const int* __restrict__ row_ptr,
                                                  const int2* __restrict__ csr, int N) {
    int node = blockIdx.x * 16 + (threadIdx.x >> 4);
    int f8 = (threadIdx.x & 15) * 8;
    if (node >= N) return;
    int s = row_ptr[node], e = row_ptr[node + 1];
    float a0 = 0.f, a1 = 0.f, a2 = 0.f, a3 = 0.f;
    float a4 = 0.f, a5 = 0.f, a6 = 0.f, a7 = 0.f;
    int i = s;
    for (; i + 4 <= e; i += 4) {
        int2 ed[4]; uint4 r[4];
        #pragma unroll
        for (int u = 0; u < 4; ++u) ed[u] = csr[i + u];
        #pragma unroll
        for (int u = 0; u < 4; ++u)
            r[u] = *reinterpret_cast<const uint4*>(&hin[(size_t)ed[u].x * gs + f8]);
        #pragma unroll
        for (int u = 0; u < 4; ++u) {
            float w = __int_as_float(ed[u].y);
            a0 += w * bflo(r[u].x); a1 += w * bfhi(r[u].x);
            a2 += w * bflo(r[u].y); a3 += w * bfhi(r[u].y);
            a4 += w * bflo(r[u].z); a5 += w * bfhi(r[u].z);
            a6 += w * bflo(r[u].w); a7 += w * bfhi(r[u].w);
        }
    }
    for (; i < e; ++i) {
        int2 ed = csr[i];
        float w = __int_as_float(ed.y);
        uint4 r = *reinterpret_cast<const uint4*>(&hin[(size_t)ed.x * gs + f8]);
        a0 += w * bflo(r.x); a1 += w * bfhi(r.x);
        a2 += w * bflo(r.y); a3 += w * bfhi(r.y);
        a4 += w * bflo(r.z); a5 += w * bfhi(r.z);
        a6 += w * bflo(r.w); a7 += w * bfhi(r.w);
    }
    ushort4 b0, b1;
    b0.x = f2bf(a0); b0.y = f2bf(a1); b0.z = f2bf(a2); b0.w = f2bf(a3);
    b1.x = f2bf(a4); b1.y = f2bf(a5); b1.z = f2bf(a6); b1.w = f2bf(a7);
    *reinterpret_cast<ushort4*>(&bout[(size_t)node * os + f8]) = b0;
    *reinterpret_cast<ushort4*>(&bout[(size_t)node * os + f8 + 4]) = b1;
}

// ---------------- propagation d=4 with add (fp32) ----------------
__global__ __launch_bounds__(256) void k_prop4_add(const float* __restrict__ tin, int tin_stride, int tin_off,
                                                   const float* __restrict__ Z, int zcol,
                                                   const float* __restrict__ bias,
                                                   float* __restrict__ tout,
                                                   const int* __restrict__ row_ptr,
                                                   const int2* __restrict__ csr, int N) {
    int node = blockIdx.x * 64 + (threadIdx.x >> 2);
    int j = threadIdx.x & 3;
    if (node >= N) return;
    int s = row_ptr[node], e = row_ptr[node + 1];
    float acc = Z[(size_t)node * 16 + zcol + j];
    if (bias) acc += bias[j];
    for (int i = s; i < e; ++i) {
        int2 ed = csr[i];
        acc += __int_as_float(ed.y) * tin[(size_t)ed.x * tin_stride + tin_off + j];
    }
    tout[(size_t)node * 4 + j] = acc;
}

// ---------------- weight prep: Wt[c][kk*din+i] = bf16(W[kk][i][c]) ----------------
__global__ void k_wprep(const float* __restrict__ W, unsigned short* __restrict__ Wt, int din) {
    int K = 4 * din;
    int total = K * 128;
    int t = blockIdx.x * blockDim.x + threadIdx.x;
    if (t >= total) return;
    int c = t / K, rem = t - c * K;
    int kk = rem / din, i = rem - kk * din;
    Wt[t] = f2bf(W[(size_t)(kk * din + i) * 128 + c]);
}

// ---------------- MFMA GEMM: C(Mx128)bf16 = relu(A(MxK)bf16 @ Bt(128xK)^T + bias) ----------------
__global__ __launch_bounds__(256) void k_mfma_gemm(const unsigned short* __restrict__ A0, int as0,
                                                   const unsigned short* __restrict__ A1, int as1,
                                                   int ksplit, int K,
                                                   const unsigned short* __restrict__ Bt,
                                                   const float* __restrict__ bias,
                                                   unsigned short* __restrict__ Cout, int M) {
    __shared__ unsigned short As[128][72];
    __shared__ unsigned short Bs[128][72];
    int tid = threadIdx.x;
    int r0 = blockIdx.x * 128;
    int wid = tid >> 6, lane = tid & 63;
    int wm = (wid >> 1) * 64, wn = (wid & 1) * 64;
    f32x4v acc[4][4];
    #pragma unroll
    for (int a = 0; a < 4; ++a)
        #pragma unroll
        for (int b = 0; b < 4; ++b) acc[a][b] = (f32x4v){0.f, 0.f, 0.f, 0.f};

    int rsel = lane & 15, ksel = (lane >> 4) * 8;

    for (int kt = 0; kt < K; kt += 64) {
        const unsigned short* Abase; int astr, kb;
        if (kt < ksplit) { Abase = A0; astr = as0; kb = kt; }
        else             { Abase = A1; astr = as1; kb = kt - ksplit; }
        #pragma unroll
        for (int i = 0; i < 4; ++i) {
            int c = tid + i * 256;
            int row = c >> 3, off = (c & 7) * 8;
            int gr = r0 + row;
            int4 v = make_int4(0, 0, 0, 0);
            if (gr < M) v = *reinterpret_cast<const int4*>(Abase + (size_t)gr * astr + kb + off);
            *reinterpret_cast<int4*>(&As[row][off]) = v;
            int4 w = *reinterpret_cast<const int4*>(Bt + (size_t)row * K + kt + off);
            *reinterpret_cast<int4*>(&Bs[row][off]) = w;
        }
        __syncthreads();
        #pragma unroll
        for (int kc = 0; kc < 64; kc += 32) {
            bf16x8v af[4], bfv[4];
            #pragma unroll
            for (int f = 0; f < 4; ++f) {
                af[f]  = *reinterpret_cast<const bf16x8v*>(&As[wm + f * 16 + rsel][kc + ksel]);
                bfv[f] = *reinterpret_cast<const bf16x8v*>(&Bs[wn + f * 16 + rsel][kc + ksel]);
            }
            #pragma unroll
            for (int mf = 0; mf < 4; ++mf)
                #pragma unroll
                for (int nf = 0; nf < 4; ++nf)
                    acc[mf][nf] = __builtin_amdgcn_mfma_f32_16x16x32_bf16(af[mf], bfv[nf], acc[mf][nf], 0, 0, 0);
        }
        __syncthreads();
    }
    int col_l = lane & 15, rgrp = (lane >> 4) * 4;
    #pragma unroll
    for (int nf = 0; nf < 4; ++nf) {
        int col = wn + nf * 16 + col_l;
        float bv = bias[col];
        #pragma unroll
        for (int mf = 0; mf < 4; ++mf) {
            #pragma unroll
            for (int j = 0; j < 4; ++j) {
                int row = r0 + wm + mf * 16 + rgrp + j;
                if (row < M) {
                    float v = fmaxf(acc[mf][nf][j] + bv, 0.f);
                    Cout[(size_t)row * 128 + col] = f2bf(v);
                }
            }
        }
    }
}

// ---------------- Z GEMM: Z(Mx16) = A(Mx128 bf16) @ W3'(128x16) ----------------
__global__ __launch_bounds__(256) void k_gemm_z(const unsigned short* __restrict__ Ab,
                                                const float* __restrict__ W3,
                                                float* __restrict__ Z, int M) {
    __shared__ float hs[64][132];
    __shared__ float wsm[128][16];
    int tid = threadIdx.x;
    int row0 = blockIdx.x * 64;
    for (int t = tid; t < 2048; t += 256) {
        int k = t >> 9, i = (t >> 2) & 127, j = t & 3;
        wsm[i][k * 4 + j] = W3[t];
    }
    #pragma unroll
    for (int it = 0; it < 8; ++it) {
        int f4 = it * 256 + tid;
        int r = f4 >> 5;
        int c4 = (f4 & 31) * 4;
        int gr = row0 + r;
        float4 v = make_float4(0.f, 0.f, 0.f, 0.f);
        if (gr < M) {
            ushort4 u = *reinterpret_cast<const ushort4*>(&Ab[(size_t)gr * 128 + c4]);
            v = make_float4(bf2f(u.x), bf2f(u.y), bf2f(u.z), bf2f(u.w));
        }
        hs[r][c4] = v.x; hs[r][c4 + 1] = v.y; hs[r][c4 + 2] = v.z; hs[r][c4 + 3] = v.w;
    }
    __syncthreads();
    int r = tid >> 2, c0 = (tid & 3) * 4;
    float acc[4] = {};
    #pragma unroll 4
    for (int i = 0; i < 128; ++i) {
        float a = hs[r][i];
        #pragma unroll
        for (int j = 0; j < 4; ++j) acc[j] += a * wsm[i][c0 + j];
    }
    int gr = row0 + r;
    if (gr < M) {
        float4 v; v.x = acc[0]; v.y = acc[1]; v.z = acc[2]; v.w = acc[3];
        *reinterpret_cast<float4*>(&Z[(size_t)gr * 16 + c0]) = v;
    }
}

// ---------------- launch ----------------
extern "C" void kernel_launch(void* const* d_in, const int* in_sizes, int n_in,
                              void* d_out, int out_size, void* d_ws, size_t ws_size,
                              hipStream_t stream) {
    const float* x  = (const float*)d_in[0];
    const int*   ei = (const int*)d_in[1];
    const float* ew = (const float*)d_in[2];
    const float* W0 = (const float*)d_in[3];
    const float* b0 = (const float*)d_in[4];
    const float* W1 = (const float*)d_in[5];
    const float* b1 = (const float*)d_in[6];
    const float* W2 = (const float*)d_in[7];
    const float* b2 = (const float*)d_in[8];
    const float* W3 = (const float*)d_in[9];
    const float* b3 = (const float*)d_in[10];
    float* out = (float*)d_out;

    const int N = in_sizes[0] / 16;   // 100000
    const int E = in_sizes[2];        // 3200000
    const int* src = ei;
    const int* dst = ei + E;

    char* ws = (char*)d_ws;
    size_t off = 0;
    auto take = [&](size_t bytes) -> void* {
        void* p = ws + off;
        off = (off + bytes + 255) & ~(size_t)255;
        return p;
    };
    unsigned short* S   = (unsigned short*)take((size_t)N * 384 * 2);  // hop slots 1..3 (stride 384)
    unsigned short* Qa  = (unsigned short*)take((size_t)N * 128 * 2);
    unsigned short* Qb  = (unsigned short*)take((size_t)N * 128 * 2);
    unsigned short* S64 = (unsigned short*)take((size_t)N * 64 * 2);
    int2*  csr     = (int2*) take((size_t)E * 8);
    unsigned long long* dc = (unsigned long long*)take((size_t)N * 8);
    unsigned short* rank = (unsigned short*)take((size_t)E * 2);
    float* dis     = (float*)take((size_t)N * 4);
    int*   row_ptr = (int*)  take((size_t)(N + 1) * 4);
    int*   bsum    = (int*)  take(1024);
    int*   boff    = (int*)  take(1024);
    float* Z       = (float*)take((size_t)N * 16 * 4);
    float* T1      = (float*)take((size_t)N * 4 * 4);
    float* T2      = (float*)take((size_t)N * 4 * 4);
    unsigned short* Wt0 = (unsigned short*)take(64 * 128 * 2);
    unsigned short* Wt1 = (unsigned short*)take(512 * 128 * 2);
    unsigned short* Wt2 = (unsigned short*)take(512 * 128 * 2);

    // ---- build norm + CSR (one packed atomic pass, atomic-free fill) ----
    hipMemsetAsync(dc, 0, (size_t)N * 8, stream);
    k_edge_deg<<<2048, 256, 0, stream>>>(dst, ew, dc, rank, E);
    k_dis<<<(N + 255) / 256, 256, 0, stream>>>(dc, dis, N);
    int nsb = (N + 1023) / 1024;
    k_scan1<<<nsb, 256, 0, stream>>>(dc, bsum, N);
    k_scan2<<<1, 64, 0, stream>>>(bsum, boff, nsb, &row_ptr[N]);
    k_scan3<<<nsb, 256, 0, stream>>>(dc, boff, row_ptr, N);
    k_fill_csr<<<2048, 256, 0, stream>>>(src, dst, ew, dis, row_ptr, rank, csr, E);

    // ---- weight prep ----
    k_wprep<<<(64 * 128 + 255) / 256, 256, 0, stream>>>(W0, Wt0, 16);
    k_wprep<<<(512 * 128 + 255) / 256, 256, 0, stream>>>(W1, Wt1, 128);
    k_wprep<<<(512 * 128 + 255) / 256, 256, 0, stream>>>(W2, Wt2, 128);

    int gmfma = (N + 127) / 128;
    int gp128 = (N + 15) / 16;
    int gp16  = (N + 63) / 64;

    // ---- layer 0: 16 -> 128 (bf16 hop chain in S64, stride 64) ----
    k_xcast<<<(N * 16 + 255) / 256, 256, 0, stream>>>(x, S64, N);
    k_prop16b<<<gp16, 256, 0, stream>>>(S64 + 0,  S64 + 16, row_ptr, csr, N);
    k_prop16b<<<gp16, 256, 0, stream>>>(S64 + 16, S64 + 32, row_ptr, csr, N);
    k_prop16b<<<gp16, 256, 0, stream>>>(S64 + 32, S64 + 48, row_ptr, csr, N);
    k_mfma_gemm<<<gmfma, 256, 0, stream>>>(S64, 64, nullptr, 0, 64, 64, Wt0, b0, Qa, N);

    // ---- layer 1: 128 -> 128 ----
    k_prop128b<<<gp128, 256, 0, stream>>>(Qa, 128,      S + 0,   384, row_ptr, csr, N);
    k_prop128b<<<gp128, 256, 0, stream>>>(S + 0, 384,   S + 128, 384, row_ptr, csr, N);
    k_prop128b<<<gp128, 256, 0, stream>>>(S + 128, 384, S + 256, 384, row_ptr, csr, N);
    k_mfma_gemm<<<gmfma, 256, 0, stream>>>(Qa, 128, S, 384, 128, 512, Wt1, b1, Qb, N);

    // ---- layer 2: 128 -> 128 ----
    k_prop128b<<<gp128, 256, 0, stream>>>(Qb, 128,      S + 0,   384, row_ptr, csr, N);
    k_prop128b<<<gp128, 256, 0, stream>>>(S + 0, 384,   S + 128, 384, row_ptr, csr, N);
    k_prop128b<<<gp128, 256, 0, stream>>>(S + 128, 384, S + 256, 384, row_ptr, csr, N);
    k_mfma_gemm<<<gmfma, 256, 0, stream>>>(Qb, 128, S, 384, 128, 512, Wt2, b2, Qa, N);

    // ---- layer 3: 128 -> 4 via projected Horner ----
    {
        k_gemm_z<<<(N + 63) / 64, 256, 0, stream>>>(Qa, W3, Z, N);
        int g = (N + 63) / 64;
        k_prop4_add<<<g, 256, 0, stream>>>(Z, 16, 12, Z, 8, nullptr, T1, row_ptr, csr, N);
        k_prop4_add<<<g, 256, 0, stream>>>(T1, 4, 0, Z, 4, nullptr, T2, row_ptr, csr, N);
        k_prop4_add<<<g, 256, 0, stream>>>(T2, 4, 0, Z, 0, b3, out, row_ptr, csr, N);
    }
}

// Round 7
// 1337.779 us; speedup vs baseline: 4.3575x; 1.0506x over previous
//
#include <hip/hip_runtime.h>

// TAGConv L3: N=100000, E=3200000, K=3. dims (16->128)(128->128)(128->128)(128->4).
// R6: prop128b unroll 8 + packed 16B store; Z-GEMM fused into layer-2 MFMA epilogue
//     (h tile relu'd in regs -> LDS -> 8 extra MFMAs vs bf16 W3^T; Qa write dropped);
//     scan1+dis merged, single wprep kernel. CSR via packed-u64 atomic rank (R4).

typedef __attribute__((ext_vector_type(8))) short bf16x8v;   // 8 bf16 = 4 VGPR
typedef __attribute__((ext_vector_type(4))) float f32x4v;

__device__ __forceinline__ float bflo(unsigned int u) { return __uint_as_float(u << 16); }
__device__ __forceinline__ float bfhi(unsigned int u) { return __uint_as_float(u & 0xffff0000u); }
__device__ __forceinline__ unsigned short f2bf(float f) {
    unsigned int u = __float_as_uint(f);
    u = (u + 0x7fff + ((u >> 16) & 1)) >> 16;   // RNE
    return (unsigned short)u;
}
__device__ __forceinline__ unsigned int pack2bf(float lo, float hi) {
    return (unsigned int)f2bf(lo) | ((unsigned int)f2bf(hi) << 16);
}

// ---------------- pass 1: packed deg/count atomic + per-edge rank ----------------
__global__ void k_edge_deg(const int* __restrict__ dst, const float* __restrict__ ew,
                           unsigned long long* __restrict__ dc,
                           unsigned short* __restrict__ rank, int E) {
    int stride = gridDim.x * blockDim.x;
    for (int e = blockIdx.x * blockDim.x + threadIdx.x; e < E; e += stride) {
        int d = dst[e];
        unsigned long long fx = (unsigned long long)(ew[e] * 0x1p40f);
        unsigned long long old = atomicAdd(&dc[d], (fx << 12) | 1ULL);
        rank[e] = (unsigned short)(old & 0xFFFULL);
    }
}

// ---------------- scan phase 1 (+ dis computation fused) ----------------
__global__ void k_scan1(const unsigned long long* __restrict__ dc, int* __restrict__ bsum,
                        float* __restrict__ dis, int N) {
    __shared__ int s[256];
    int tid = threadIdx.x;
    int base = blockIdx.x * 1024 + tid * 4;
    int t = 0;
    #pragma unroll
    for (int i = 0; i < 4; ++i) {
        int idx = base + i;
        if (idx < N) {
            unsigned long long v = dc[idx];
            t += (int)(v & 0xFFFULL);
            float d = (float)(v >> 12) * 0x1p-40f;
            dis[idx] = d > 0.f ? rsqrtf(d) : 0.f;
        }
    }
    s[tid] = t; __syncthreads();
    for (int off = 128; off > 0; off >>= 1) {
        if (tid < off) s[tid] += s[tid + off];
        __syncthreads();
    }
    if (tid == 0) bsum[blockIdx.x] = s[0];
}

__global__ void k_scan2(const int* __restrict__ bsum, int* __restrict__ boff,
                        int nb, int* __restrict__ row_ptr_last) {
    if (threadIdx.x == 0) {
        int run = 0;
        for (int i = 0; i < nb; ++i) { boff[i] = run; run += bsum[i]; }
        *row_ptr_last = run;
    }
}

__global__ void k_scan3(const unsigned long long* __restrict__ dc, const int* __restrict__ boff,
                        int* __restrict__ row_ptr, int N) {
    __shared__ int s[256];
    int tid = threadIdx.x;
    int base = blockIdx.x * 1024 + tid * 4;
    int v[4]; int t = 0;
    #pragma unroll
    for (int i = 0; i < 4; ++i) { int idx = base + i; v[i] = (idx < N) ? (int)(dc[idx] & 0xFFFULL) : 0; t += v[i]; }
    s[tid] = t; __syncthreads();
    for (int off = 1; off < 256; off <<= 1) {
        int add = (tid >= off) ? s[tid - off] : 0;
        __syncthreads();
        s[tid] += add;
        __syncthreads();
    }
    int g = boff[blockIdx.x] + (s[tid] - t);   // exclusive prefix
    #pragma unroll
    for (int i = 0; i < 4; ++i) {
        int idx = base + i;
        if (idx < N) row_ptr[idx] = g;
        g += v[i];
    }
}

// ---------------- pass 2: atomic-free CSR fill ----------------
__global__ void k_fill_csr(const int* __restrict__ src, const int* __restrict__ dst,
                           const float* __restrict__ ew, const float* __restrict__ dis,
                           const int* __restrict__ row_ptr, const unsigned short* __restrict__ rank,
                           int2* __restrict__ csr, int E) {
    int stride = gridDim.x * blockDim.x;
    for (int e = blockIdx.x * blockDim.x + threadIdx.x; e < E; e += stride) {
        int d = dst[e];
        int s = src[e];
        int pos = row_ptr[d] + rank[e];
        float w = dis[s] * ew[e] * dis[d];
        csr[pos] = make_int2(s, __float_as_int(w));
    }
}

// ---------------- x -> bf16 stack slot0 (d=16, stride 64) ----------------
__global__ void k_xcast(const float* __restrict__ x, unsigned short* __restrict__ s64, int N) {
    int i = blockIdx.x * blockDim.x + threadIdx.x;
    if (i < N * 16) {
        int n = i >> 4, f = i & 15;
        s64[n * 64 + f] = f2bf(x[i]);
    }
}

// ---------------- propagation d=16 bf16: 4 lanes/node, 8B loads, unroll 4 ----------------
__global__ __launch_bounds__(256) void k_prop16b(const unsigned short* __restrict__ hin,
                                                 unsigned short* __restrict__ bout,
                                                 const int* __restrict__ row_ptr,
                                                 const int2* __restrict__ csr, int N) {
    int node = blockIdx.x * 64 + (threadIdx.x >> 2);
    int f4 = (threadIdx.x & 3) * 4;
    if (node >= N) return;
    int s = row_ptr[node], e = row_ptr[node + 1];
    float a0 = 0.f, a1 = 0.f, a2 = 0.f, a3 = 0.f;
    int i = s;
    for (; i + 4 <= e; i += 4) {
        int2 ed[4]; uint2 r[4];
        #pragma unroll
        for (int u = 0; u < 4; ++u) ed[u] = csr[i + u];
        #pragma unroll
        for (int u = 0; u < 4; ++u)
            r[u] = *reinterpret_cast<const uint2*>(&hin[(size_t)ed[u].x * 64 + f4]);
        #pragma unroll
        for (int u = 0; u < 4; ++u) {
            float w = __int_as_float(ed[u].y);
            a0 += w * bflo(r[u].x); a1 += w * bfhi(r[u].x);
            a2 += w * bflo(r[u].y); a3 += w * bfhi(r[u].y);
        }
    }
    for (; i < e; ++i) {
        int2 ed = csr[i];
        float w = __int_as_float(ed.y);
        uint2 r = *reinterpret_cast<const uint2*>(&hin[(size_t)ed.x * 64 + f4]);
        a0 += w * bflo(r.x); a1 += w * bfhi(r.x);
        a2 += w * bflo(r.y); a3 += w * bfhi(r.y);
    }
    uint2 ob; ob.x = pack2bf(a0, a1); ob.y = pack2bf(a2, a3);
    *reinterpret_cast<uint2*>(&bout[(size_t)node * 64 + f4]) = ob;
}

// ---------------- propagation d=128 bf16: 16 lanes/node, 16B loads, unroll 8 ----------------
__global__ __launch_bounds__(256) void k_prop128b(const unsigned short* __restrict__ hin, int gs,
                                                  unsigned short* __restrict__ bout, int os,
                                                  const int* __restrict__ row_ptr,
                                                  const int2* __restrict__ csr, int N) {
    int node = blockIdx.x * 16 + (threadIdx.x >> 4);
    int f8 = (threadIdx.x & 15) * 8;
    if (node >= N) return;
    int s = row_ptr[node], e = row_ptr[node + 1];
    float a0 = 0.f, a1 = 0.f, a2 = 0.f, a3 = 0.f;
    float a4 = 0.f, a5 = 0.f, a6 = 0.f, a7 = 0.f;
    int i = s;
    for (; i + 8 <= e; i += 8) {
        int2 ed[8]; uint4 r[8];
        #pragma unroll
        for (int u = 0; u < 8; ++u) ed[u] = csr[i + u];
        #pragma unroll
        for (int u = 0; u < 8; ++u)
            r[u] = *reinterpret_cast<const uint4*>(&hin[(size_t)ed[u].x * gs + f8]);
        #pragma unroll
        for (int u = 0; u < 8; ++u) {
            float w = __int_as_float(ed[u].y);
            a0 += w * bflo(r[u].x); a1 += w * bfhi(r[u].x);
            a2 += w * bflo(r[u].y); a3 += w * bfhi(r[u].y);
            a4 += w * bflo(r[u].z); a5 += w * bfhi(r[u].z);
            a6 += w * bflo(r[u].w); a7 += w * bfhi(r[u].w);
        }
    }
    for (; i < e; ++i) {
        int2 ed = csr[i];
        float w = __int_as_float(ed.y);
        uint4 r = *reinterpret_cast<const uint4*>(&hin[(size_t)ed.x * gs + f8]);
        a0 += w * bflo(r.x); a1 += w * bfhi(r.x);
        a2 += w * bflo(r.y); a3 += w * bfhi(r.y);
        a4 += w * bflo(r.z); a5 += w * bfhi(r.z);
        a6 += w * bflo(r.w); a7 += w * bfhi(r.w);
    }
    uint4 ob;
    ob.x = pack2bf(a0, a1); ob.y = pack2bf(a2, a3);
    ob.z = pack2bf(a4, a5); ob.w = pack2bf(a6, a7);
    *reinterpret_cast<uint4*>(&bout[(size_t)node * os + f8]) = ob;
}

// ---------------- propagation d=4 with add (fp32) ----------------
__global__ __launch_bounds__(256) void k_prop4_add(const float* __restrict__ tin, int tin_stride, int tin_off,
                                                   const float* __restrict__ Z, int zcol,
                                                   const float* __restrict__ bias,
                                                   float* __restrict__ tout,
                                                   const int* __restrict__ row_ptr,
                                                   const int2* __restrict__ csr, int N) {
    int node = blockIdx.x * 64 + (threadIdx.x >> 2);
    int j = threadIdx.x & 3;
    if (node >= N) return;
    int s = row_ptr[node], e = row_ptr[node + 1];
    float acc = Z[(size_t)node * 16 + zcol + j];
    if (bias) acc += bias[j];
    for (int i = s; i < e; ++i) {
        int2 ed = csr[i];
        acc += __int_as_float(ed.y) * tin[(size_t)ed.x * tin_stride + tin_off + j];
    }
    tout[(size_t)node * 4 + j] = acc;
}

// ---------------- weight prep (all layers in one kernel) ----------------
// Wt[c*K + r] = bf16(W[r*128 + c]);  Wz[c*128 + k] = bf16(W3[(c>>2)*512 + k*4 + (c&3)])
__global__ void k_wprep_all(const float* __restrict__ W0, const float* __restrict__ W1,
                            const float* __restrict__ W2, const float* __restrict__ W3,
                            unsigned short* __restrict__ Wt0, unsigned short* __restrict__ Wt1,
                            unsigned short* __restrict__ Wt2, unsigned short* __restrict__ Wz) {
    int t = blockIdx.x * blockDim.x + threadIdx.x;
    if (t < 8192) {
        int c = t >> 6, r = t & 63;
        Wt0[t] = f2bf(W0[r * 128 + c]);
    } else if (t < 8192 + 65536) {
        int u = t - 8192; int c = u >> 9, r = u & 511;
        Wt1[u] = f2bf(W1[r * 128 + c]);
    } else if (t < 8192 + 131072) {
        int u = t - (8192 + 65536); int c = u >> 9, r = u & 511;
        Wt2[u] = f2bf(W2[r * 128 + c]);
    } else if (t < 8192 + 131072 + 2048) {
        int u = t - (8192 + 131072); int c = u >> 7, k = u & 127;
        Wz[u] = f2bf(W3[(c >> 2) * 512 + k * 4 + (c & 3)]);
    }
}

// ---------------- MFMA GEMM: C(Mx128)bf16 = relu(A(MxK)bf16 @ Bt(128xK)^T + bias) ----------------
// FUSEZ: additionally Z(Mx16) = relu'd-h @ Wz^T via LDS round-trip; Cout write skipped.
template <bool FUSEZ>
__global__ __launch_bounds__(256) void k_mfma_gemm(const unsigned short* __restrict__ A0, int as0,
                                                   const unsigned short* __restrict__ A1, int as1,
                                                   int ksplit, int K,
                                                   const unsigned short* __restrict__ Bt,
                                                   const float* __restrict__ bias,
                                                   unsigned short* __restrict__ Coutb,
                                                   const unsigned short* __restrict__ Wzg,
                                                   float* __restrict__ Zout, int M) {
    __shared__ unsigned short smem[19584];   // As[128][72] | Bs[128][72]; reused as Hs[128][136] + WzS[16][136]
    unsigned short (*As)[72] = reinterpret_cast<unsigned short(*)[72]>(smem);
    unsigned short (*Bs)[72] = reinterpret_cast<unsigned short(*)[72]>(smem + 9216);
    int tid = threadIdx.x;
    int r0 = blockIdx.x * 128;
    int wid = tid >> 6, lane = tid & 63;
    int wm = (wid >> 1) * 64, wn = (wid & 1) * 64;
    f32x4v acc[4][4];
    #pragma unroll
    for (int a = 0; a < 4; ++a)
        #pragma unroll
        for (int b = 0; b < 4; ++b) acc[a][b] = (f32x4v){0.f, 0.f, 0.f, 0.f};

    int rsel = lane & 15, ksel = (lane >> 4) * 8;

    for (int kt = 0; kt < K; kt += 64) {
        const unsigned short* Abase; int astr, kb;
        if (kt < ksplit) { Abase = A0; astr = as0; kb = kt; }
        else             { Abase = A1; astr = as1; kb = kt - ksplit; }
        #pragma unroll
        for (int i = 0; i < 4; ++i) {
            int c = tid + i * 256;
            int row = c >> 3, off = (c & 7) * 8;
            int gr = r0 + row;
            int4 v = make_int4(0, 0, 0, 0);
            if (gr < M) v = *reinterpret_cast<const int4*>(Abase + (size_t)gr * astr + kb + off);
            *reinterpret_cast<int4*>(&As[row][off]) = v;
            int4 w = *reinterpret_cast<const int4*>(Bt + (size_t)row * K + kt + off);
            *reinterpret_cast<int4*>(&Bs[row][off]) = w;
        }
        __syncthreads();
        #pragma unroll
        for (int kc = 0; kc < 64; kc += 32) {
            bf16x8v af[4], bfv[4];
            #pragma unroll
            for (int f = 0; f < 4; ++f) {
                af[f]  = *reinterpret_cast<const bf16x8v*>(&As[wm + f * 16 + rsel][kc + ksel]);
                bfv[f] = *reinterpret_cast<const bf16x8v*>(&Bs[wn + f * 16 + rsel][kc + ksel]);
            }
            #pragma unroll
            for (int mf = 0; mf < 4; ++mf)
                #pragma unroll
                for (int nf = 0; nf < 4; ++nf)
                    acc[mf][nf] = __builtin_amdgcn_mfma_f32_16x16x32_bf16(af[mf], bfv[nf], acc[mf][nf], 0, 0, 0);
        }
        __syncthreads();
    }
    // epilogue: C/D layout col=lane&15, row=(lane>>4)*4+reg
    int col_l = lane & 15, rgrp = (lane >> 4) * 4;
    unsigned short* Hs = smem;              // [128][136]
    unsigned short* WzS = smem + 17408;     // [16][136]
    #pragma unroll
    for (int nf = 0; nf < 4; ++nf) {
        int col = wn + nf * 16 + col_l;
        float bv = bias[col];
        #pragma unroll
        for (int mf = 0; mf < 4; ++mf) {
            #pragma unroll
            for (int j = 0; j < 4; ++j) {
                int lrow = wm + mf * 16 + rgrp + j;
                float v = fmaxf(acc[mf][nf][j] + bv, 0.f);
                unsigned short hb = f2bf(v);
                if (FUSEZ) {
                    Hs[lrow * 136 + col] = hb;
                } else {
                    int row = r0 + lrow;
                    if (row < M) Coutb[(size_t)row * 128 + col] = hb;
                }
            }
        }
    }
    if (FUSEZ) {
        for (int t = tid; t < 2048; t += 256) {
            WzS[(t >> 7) * 136 + (t & 127)] = Wzg[t];
        }
        __syncthreads();
        int wmz = wid * 32;
        f32x4v z0 = (f32x4v){0.f, 0.f, 0.f, 0.f};
        f32x4v z1 = (f32x4v){0.f, 0.f, 0.f, 0.f};
        #pragma unroll
        for (int kt2 = 0; kt2 < 128; kt2 += 32) {
            bf16x8v a0 = *reinterpret_cast<const bf16x8v*>(&Hs[(wmz + rsel) * 136 + kt2 + ksel]);
            bf16x8v a1 = *reinterpret_cast<const bf16x8v*>(&Hs[(wmz + 16 + rsel) * 136 + kt2 + ksel]);
            bf16x8v bz = *reinterpret_cast<const bf16x8v*>(&WzS[rsel * 136 + kt2 + ksel]);
            z0 = __builtin_amdgcn_mfma_f32_16x16x32_bf16(a0, bz, z0, 0, 0, 0);
            z1 = __builtin_amdgcn_mfma_f32_16x16x32_bf16(a1, bz, z1, 0, 0, 0);
        }
        #pragma unroll
        for (int j = 0; j < 4; ++j) {
            int ra = r0 + wmz + rgrp + j;
            if (ra < M) Zout[(size_t)ra * 16 + col_l] = z0[j];
            int rb = r0 + wmz + 16 + rgrp + j;
            if (rb < M) Zout[(size_t)rb * 16 + col_l] = z1[j];
        }
    }
}

// ---------------- launch ----------------
extern "C" void kernel_launch(void* const* d_in, const int* in_sizes, int n_in,
                              void* d_out, int out_size, void* d_ws, size_t ws_size,
                              hipStream_t stream) {
    const float* x  = (const float*)d_in[0];
    const int*   ei = (const int*)d_in[1];
    const float* ew = (const float*)d_in[2];
    const float* W0 = (const float*)d_in[3];
    const float* b0 = (const float*)d_in[4];
    const float* W1 = (const float*)d_in[5];
    const float* b1 = (const float*)d_in[6];
    const float* W2 = (const float*)d_in[7];
    const float* b2 = (const float*)d_in[8];
    const float* W3 = (const float*)d_in[9];
    const float* b3 = (const float*)d_in[10];
    float* out = (float*)d_out;

    const int N = in_sizes[0] / 16;   // 100000
    const int E = in_sizes[2];        // 3200000
    const int* src = ei;
    const int* dst = ei + E;

    char* ws = (char*)d_ws;
    size_t off = 0;
    auto take = [&](size_t bytes) -> void* {
        void* p = ws + off;
        off = (off + bytes + 255) & ~(size_t)255;
        return p;
    };
    unsigned short* S   = (unsigned short*)take((size_t)N * 384 * 2);  // hop slots 1..3 (stride 384)
    unsigned short* Qa  = (unsigned short*)take((size_t)N * 128 * 2);
    unsigned short* Qb  = (unsigned short*)take((size_t)N * 128 * 2);
    unsigned short* S64 = (unsigned short*)take((size_t)N * 64 * 2);
    int2*  csr     = (int2*) take((size_t)E * 8);
    unsigned long long* dc = (unsigned long long*)take((size_t)N * 8);
    unsigned short* rank = (unsigned short*)take((size_t)E * 2);
    float* dis     = (float*)take((size_t)N * 4);
    int*   row_ptr = (int*)  take((size_t)(N + 1) * 4);
    int*   bsum    = (int*)  take(1024);
    int*   boff    = (int*)  take(1024);
    float* Z       = (float*)take((size_t)N * 16 * 4);
    float* T1      = (float*)take((size_t)N * 4 * 4);
    float* T2      = (float*)take((size_t)N * 4 * 4);
    unsigned short* Wt0 = (unsigned short*)take(64 * 128 * 2);
    unsigned short* Wt1 = (unsigned short*)take(512 * 128 * 2);
    unsigned short* Wt2 = (unsigned short*)take(512 * 128 * 2);
    unsigned short* Wz  = (unsigned short*)take(16 * 128 * 2);

    // ---- build norm + CSR (one packed atomic pass, atomic-free fill) ----
    hipMemsetAsync(dc, 0, (size_t)N * 8, stream);
    k_edge_deg<<<2048, 256, 0, stream>>>(dst, ew, dc, rank, E);
    int nsb = (N + 1023) / 1024;
    k_scan1<<<nsb, 256, 0, stream>>>(dc, bsum, dis, N);
    k_scan2<<<1, 64, 0, stream>>>(bsum, boff, nsb, &row_ptr[N]);
    k_scan3<<<nsb, 256, 0, stream>>>(dc, boff, row_ptr, N);
    k_fill_csr<<<2048, 256, 0, stream>>>(src, dst, ew, dis, row_ptr, rank, csr, E);

    // ---- weight prep (one kernel) ----
    k_wprep_all<<<(141312 + 255) / 256, 256, 0, stream>>>(W0, W1, W2, W3, Wt0, Wt1, Wt2, Wz);

    int gmfma = (N + 127) / 128;
    int gp128 = (N + 15) / 16;
    int gp16  = (N + 63) / 64;

    // ---- layer 0: 16 -> 128 (bf16 hop chain in S64, stride 64) ----
    k_xcast<<<(N * 16 + 255) / 256, 256, 0, stream>>>(x, S64, N);
    k_prop16b<<<gp16, 256, 0, stream>>>(S64 + 0,  S64 + 16, row_ptr, csr, N);
    k_prop16b<<<gp16, 256, 0, stream>>>(S64 + 16, S64 + 32, row_ptr, csr, N);
    k_prop16b<<<gp16, 256, 0, stream>>>(S64 + 32, S64 + 48, row_ptr, csr, N);
    k_mfma_gemm<false><<<gmfma, 256, 0, stream>>>(S64, 64, nullptr, 0, 64, 64, Wt0, b0, Qa, nullptr, nullptr, N);

    // ---- layer 1: 128 -> 128 ----
    k_prop128b<<<gp128, 256, 0, stream>>>(Qa, 128,      S + 0,   384, row_ptr, csr, N);
    k_prop128b<<<gp128, 256, 0, stream>>>(S + 0, 384,   S + 128, 384, row_ptr, csr, N);
    k_prop128b<<<gp128, 256, 0, stream>>>(S + 128, 384, S + 256, 384, row_ptr, csr, N);
    k_mfma_gemm<false><<<gmfma, 256, 0, stream>>>(Qa, 128, S, 384, 128, 512, Wt1, b1, Qb, nullptr, nullptr, N);

    // ---- layer 2: 128 -> 128, Z fused into epilogue ----
    k_prop128b<<<gp128, 256, 0, stream>>>(Qb, 128,      S + 0,   384, row_ptr, csr, N);
    k_prop128b<<<gp128, 256, 0, stream>>>(S + 0, 384,   S + 128, 384, row_ptr, csr, N);
    k_prop128b<<<gp128, 256, 0, stream>>>(S + 128, 384, S + 256, 384, row_ptr, csr, N);
    k_mfma_gemm<true><<<gmfma, 256, 0, stream>>>(Qb, 128, S, 384, 128, 512, Wt2, b2, nullptr, Wz, Z, N);

    // ---- layer 3: 128 -> 4 via projected Horner (on Z) ----
    {
        int g = (N + 63) / 64;
        k_prop4_add<<<g, 256, 0, stream>>>(Z, 16, 12, Z, 8, nullptr, T1, row_ptr, csr, N);
        k_prop4_add<<<g, 256, 0, stream>>>(T1, 4, 0, Z, 4, nullptr, T2, row_ptr, csr, N);
        k_prop4_add<<<g, 256, 0, stream>>>(T2, 4, 0, Z, 0, b3, out, row_ptr, csr, N);
    }
}

// Round 8
// 1274.891 us; speedup vs baseline: 4.5724x; 1.0493x over previous
//
#include <hip/hip_runtime.h>

// TAGConv L3: N=100000, E=3200000, K=3. dims (16->128)(128->128)(128->128)(128->4).
// R7: props restructured to ONE NODE PER WAVE (edge-parallel lanes + shfl_xor reduce)
//     to remove deg-divergence (wave loop ran to max(deg) over co-resident nodes).
//     Everything else = R6: Z-fused layer-2 GEMM, packed-u64 atomic CSR, stacked-K MFMA.

typedef __attribute__((ext_vector_type(8))) short bf16x8v;   // 8 bf16 = 4 VGPR
typedef __attribute__((ext_vector_type(4))) float f32x4v;

__device__ __forceinline__ float bflo(unsigned int u) { return __uint_as_float(u << 16); }
__device__ __forceinline__ float bfhi(unsigned int u) { return __uint_as_float(u & 0xffff0000u); }
__device__ __forceinline__ unsigned short f2bf(float f) {
    unsigned int u = __float_as_uint(f);
    u = (u + 0x7fff + ((u >> 16) & 1)) >> 16;   // RNE
    return (unsigned short)u;
}
__device__ __forceinline__ unsigned int pack2bf(float lo, float hi) {
    return (unsigned int)f2bf(lo) | ((unsigned int)f2bf(hi) << 16);
}

// ---------------- pass 1: packed deg/count atomic + per-edge rank ----------------
__global__ void k_edge_deg(const int* __restrict__ dst, const float* __restrict__ ew,
                           unsigned long long* __restrict__ dc,
                           unsigned short* __restrict__ rank, int E) {
    int stride = gridDim.x * blockDim.x;
    for (int e = blockIdx.x * blockDim.x + threadIdx.x; e < E; e += stride) {
        int d = dst[e];
        unsigned long long fx = (unsigned long long)(ew[e] * 0x1p40f);
        unsigned long long old = atomicAdd(&dc[d], (fx << 12) | 1ULL);
        rank[e] = (unsigned short)(old & 0xFFFULL);
    }
}

// ---------------- scan phase 1 (+ dis fused) ----------------
__global__ void k_scan1(const unsigned long long* __restrict__ dc, int* __restrict__ bsum,
                        float* __restrict__ dis, int N) {
    __shared__ int s[256];
    int tid = threadIdx.x;
    int base = blockIdx.x * 1024 + tid * 4;
    int t = 0;
    #pragma unroll
    for (int i = 0; i < 4; ++i) {
        int idx = base + i;
        if (idx < N) {
            unsigned long long v = dc[idx];
            t += (int)(v & 0xFFFULL);
            float d = (float)(v >> 12) * 0x1p-40f;
            dis[idx] = d > 0.f ? rsqrtf(d) : 0.f;
        }
    }
    s[tid] = t; __syncthreads();
    for (int off = 128; off > 0; off >>= 1) {
        if (tid < off) s[tid] += s[tid + off];
        __syncthreads();
    }
    if (tid == 0) bsum[blockIdx.x] = s[0];
}

__global__ void k_scan2(const int* __restrict__ bsum, int* __restrict__ boff,
                        int nb, int* __restrict__ row_ptr_last) {
    if (threadIdx.x == 0) {
        int run = 0;
        for (int i = 0; i < nb; ++i) { boff[i] = run; run += bsum[i]; }
        *row_ptr_last = run;
    }
}

__global__ void k_scan3(const unsigned long long* __restrict__ dc, const int* __restrict__ boff,
                        int* __restrict__ row_ptr, int N) {
    __shared__ int s[256];
    int tid = threadIdx.x;
    int base = blockIdx.x * 1024 + tid * 4;
    int v[4]; int t = 0;
    #pragma unroll
    for (int i = 0; i < 4; ++i) { int idx = base + i; v[i] = (idx < N) ? (int)(dc[idx] & 0xFFFULL) : 0; t += v[i]; }
    s[tid] = t; __syncthreads();
    for (int off = 1; off < 256; off <<= 1) {
        int add = (tid >= off) ? s[tid - off] : 0;
        __syncthreads();
        s[tid] += add;
        __syncthreads();
    }
    int g = boff[blockIdx.x] + (s[tid] - t);   // exclusive prefix
    #pragma unroll
    for (int i = 0; i < 4; ++i) {
        int idx = base + i;
        if (idx < N) row_ptr[idx] = g;
        g += v[i];
    }
}

// ---------------- pass 2: atomic-free CSR fill ----------------
__global__ void k_fill_csr(const int* __restrict__ src, const int* __restrict__ dst,
                           const float* __restrict__ ew, const float* __restrict__ dis,
                           const int* __restrict__ row_ptr, const unsigned short* __restrict__ rank,
                           int2* __restrict__ csr, int E) {
    int stride = gridDim.x * blockDim.x;
    for (int e = blockIdx.x * blockDim.x + threadIdx.x; e < E; e += stride) {
        int d = dst[e];
        int s = src[e];
        int pos = row_ptr[d] + rank[e];
        float w = dis[s] * ew[e] * dis[d];
        csr[pos] = make_int2(s, __float_as_int(w));
    }
}

// ---------------- x -> bf16 stack slot0 (d=16, stride 64) ----------------
__global__ void k_xcast(const float* __restrict__ x, unsigned short* __restrict__ s64, int N) {
    int i = blockIdx.x * blockDim.x + threadIdx.x;
    if (i < N * 16) {
        int n = i >> 4, f = i & 15;
        s64[n * 64 + f] = f2bf(x[i]);
    }
}

// ---------------- prop d=16: ONE NODE PER WAVE, 16 edges x 4 lanes, shfl reduce ----------------
__global__ __launch_bounds__(256) void k_prop16b(const unsigned short* __restrict__ hin,
                                                 unsigned short* __restrict__ bout,
                                                 const int* __restrict__ row_ptr,
                                                 const int2* __restrict__ csr, int N) {
    int node = blockIdx.x * 4 + (threadIdx.x >> 6);
    if (node >= N) return;
    int lane = threadIdx.x & 63;
    int esub = lane >> 2, f4 = (lane & 3) * 4;
    int s = row_ptr[node], e = row_ptr[node + 1];
    float a0 = 0.f, a1 = 0.f, a2 = 0.f, a3 = 0.f;
    for (int i = s; i < e; i += 16) {
        int idx = i + esub;
        bool valid = idx < e;
        int2 ed = valid ? csr[idx] : make_int2(0, 0);
        float w = valid ? __int_as_float(ed.y) : 0.f;
        uint2 r = *reinterpret_cast<const uint2*>(&hin[(size_t)ed.x * 64 + f4]);
        a0 += w * bflo(r.x); a1 += w * bfhi(r.x);
        a2 += w * bflo(r.y); a3 += w * bfhi(r.y);
    }
    #pragma unroll
    for (int m = 4; m <= 32; m <<= 1) {
        a0 += __shfl_xor(a0, m); a1 += __shfl_xor(a1, m);
        a2 += __shfl_xor(a2, m); a3 += __shfl_xor(a3, m);
    }
    if (lane < 4) {
        uint2 ob; ob.x = pack2bf(a0, a1); ob.y = pack2bf(a2, a3);
        *reinterpret_cast<uint2*>(&bout[(size_t)node * 64 + f4]) = ob;
    }
}

// ---------------- prop d=128: ONE NODE PER WAVE, 4 edges x 16 lanes, unroll 2 ----------------
__global__ __launch_bounds__(256) void k_prop128b(const unsigned short* __restrict__ hin, int gs,
                                                  unsigned short* __restrict__ bout, int os,
                                                  const int* __restrict__ row_ptr,
                                                  const int2* __restrict__ csr, int N) {
    int node = blockIdx.x * 4 + (threadIdx.x >> 6);
    if (node >= N) return;
    int lane = threadIdx.x & 63;
    int esub = lane >> 4, f8 = (lane & 15) * 8;
    int s = row_ptr[node], e = row_ptr[node + 1];
    float a0 = 0.f, a1 = 0.f, a2 = 0.f, a3 = 0.f;
    float a4 = 0.f, a5 = 0.f, a6 = 0.f, a7 = 0.f;
    int i = s;
    for (; i + 8 <= e; i += 8) {
        int i0 = i + esub, i1 = i0 + 4;
        int2 e0 = csr[i0], e1 = csr[i1];
        uint4 r0 = *reinterpret_cast<const uint4*>(&hin[(size_t)e0.x * gs + f8]);
        uint4 r1 = *reinterpret_cast<const uint4*>(&hin[(size_t)e1.x * gs + f8]);
        float w0 = __int_as_float(e0.y), w1 = __int_as_float(e1.y);
        a0 += w0 * bflo(r0.x) + w1 * bflo(r1.x);
        a1 += w0 * bfhi(r0.x) + w1 * bfhi(r1.x);
        a2 += w0 * bflo(r0.y) + w1 * bflo(r1.y);
        a3 += w0 * bfhi(r0.y) + w1 * bfhi(r1.y);
        a4 += w0 * bflo(r0.z) + w1 * bflo(r1.z);
        a5 += w0 * bfhi(r0.z) + w1 * bfhi(r1.z);
        a6 += w0 * bflo(r0.w) + w1 * bflo(r1.w);
        a7 += w0 * bfhi(r0.w) + w1 * bfhi(r1.w);
    }
    for (; i < e; i += 4) {
        int idx = i + esub;
        bool valid = idx < e;
        int2 ed = valid ? csr[idx] : make_int2(0, 0);
        float w = valid ? __int_as_float(ed.y) : 0.f;
        uint4 r = *reinterpret_cast<const uint4*>(&hin[(size_t)ed.x * gs + f8]);
        a0 += w * bflo(r.x); a1 += w * bfhi(r.x);
        a2 += w * bflo(r.y); a3 += w * bfhi(r.y);
        a4 += w * bflo(r.z); a5 += w * bfhi(r.z);
        a6 += w * bflo(r.w); a7 += w * bfhi(r.w);
    }
    #pragma unroll
    for (int m = 16; m <= 32; m <<= 1) {
        a0 += __shfl_xor(a0, m); a1 += __shfl_xor(a1, m);
        a2 += __shfl_xor(a2, m); a3 += __shfl_xor(a3, m);
        a4 += __shfl_xor(a4, m); a5 += __shfl_xor(a5, m);
        a6 += __shfl_xor(a6, m); a7 += __shfl_xor(a7, m);
    }
    if (lane < 16) {
        uint4 ob;
        ob.x = pack2bf(a0, a1); ob.y = pack2bf(a2, a3);
        ob.z = pack2bf(a4, a5); ob.w = pack2bf(a6, a7);
        *reinterpret_cast<uint4*>(&bout[(size_t)node * os + f8]) = ob;
    }
}

// ---------------- propagation d=4 with add (fp32) ----------------
__global__ __launch_bounds__(256) void k_prop4_add(const float* __restrict__ tin, int tin_stride, int tin_off,
                                                   const float* __restrict__ Z, int zcol,
                                                   const float* __restrict__ bias,
                                                   float* __restrict__ tout,
                                                   const int* __restrict__ row_ptr,
                                                   const int2* __restrict__ csr, int N) {
    int node = blockIdx.x * 64 + (threadIdx.x >> 2);
    int j = threadIdx.x & 3;
    if (node >= N) return;
    int s = row_ptr[node], e = row_ptr[node + 1];
    float acc = Z[(size_t)node * 16 + zcol + j];
    if (bias) acc += bias[j];
    for (int i = s; i < e; ++i) {
        int2 ed = csr[i];
        acc += __int_as_float(ed.y) * tin[(size_t)ed.x * tin_stride + tin_off + j];
    }
    tout[(size_t)node * 4 + j] = acc;
}

// ---------------- weight prep (all layers in one kernel) ----------------
__global__ void k_wprep_all(const float* __restrict__ W0, const float* __restrict__ W1,
                            const float* __restrict__ W2, const float* __restrict__ W3,
                            unsigned short* __restrict__ Wt0, unsigned short* __restrict__ Wt1,
                            unsigned short* __restrict__ Wt2, unsigned short* __restrict__ Wz) {
    int t = blockIdx.x * blockDim.x + threadIdx.x;
    if (t < 8192) {
        int c = t >> 6, r = t & 63;
        Wt0[t] = f2bf(W0[r * 128 + c]);
    } else if (t < 8192 + 65536) {
        int u = t - 8192; int c = u >> 9, r = u & 511;
        Wt1[u] = f2bf(W1[r * 128 + c]);
    } else if (t < 8192 + 131072) {
        int u = t - (8192 + 65536); int c = u >> 9, r = u & 511;
        Wt2[u] = f2bf(W2[r * 128 + c]);
    } else if (t < 8192 + 131072 + 2048) {
        int u = t - (8192 + 131072); int c = u >> 7, k = u & 127;
        Wz[u] = f2bf(W3[(c >> 2) * 512 + k * 4 + (c & 3)]);
    }
}

// ---------------- MFMA GEMM: C(Mx128)bf16 = relu(A(MxK)bf16 @ Bt(128xK)^T + bias) ----------------
template <bool FUSEZ>
__global__ __launch_bounds__(256) void k_mfma_gemm(const unsigned short* __restrict__ A0, int as0,
                                                   const unsigned short* __restrict__ A1, int as1,
                                                   int ksplit, int K,
                                                   const unsigned short* __restrict__ Bt,
                                                   const float* __restrict__ bias,
                                                   unsigned short* __restrict__ Coutb,
                                                   const unsigned short* __restrict__ Wzg,
                                                   float* __restrict__ Zout, int M) {
    __shared__ unsigned short smem[19584];   // As[128][72] | Bs[128][72]; reused as Hs[128][136] + WzS[16][136]
    unsigned short (*As)[72] = reinterpret_cast<unsigned short(*)[72]>(smem);
    unsigned short (*Bs)[72] = reinterpret_cast<unsigned short(*)[72]>(smem + 9216);
    int tid = threadIdx.x;
    int r0 = blockIdx.x * 128;
    int wid = tid >> 6, lane = tid & 63;
    int wm = (wid >> 1) * 64, wn = (wid & 1) * 64;
    f32x4v acc[4][4];
    #pragma unroll
    for (int a = 0; a < 4; ++a)
        #pragma unroll
        for (int b = 0; b < 4; ++b) acc[a][b] = (f32x4v){0.f, 0.f, 0.f, 0.f};

    int rsel = lane & 15, ksel = (lane >> 4) * 8;

    for (int kt = 0; kt < K; kt += 64) {
        const unsigned short* Abase; int astr, kb;
        if (kt < ksplit) { Abase = A0; astr = as0; kb = kt; }
        else             { Abase = A1; astr = as1; kb = kt - ksplit; }
        #pragma unroll
        for (int i = 0; i < 4; ++i) {
            int c = tid + i * 256;
            int row = c >> 3, off = (c & 7) * 8;
            int gr = r0 + row;
            int4 v = make_int4(0, 0, 0, 0);
            if (gr < M) v = *reinterpret_cast<const int4*>(Abase + (size_t)gr * astr + kb + off);
            *reinterpret_cast<int4*>(&As[row][off]) = v;
            int4 w = *reinterpret_cast<const int4*>(Bt + (size_t)row * K + kt + off);
            *reinterpret_cast<int4*>(&Bs[row][off]) = w;
        }
        __syncthreads();
        #pragma unroll
        for (int kc = 0; kc < 64; kc += 32) {
            bf16x8v af[4], bfv[4];
            #pragma unroll
            for (int f = 0; f < 4; ++f) {
                af[f]  = *reinterpret_cast<const bf16x8v*>(&As[wm + f * 16 + rsel][kc + ksel]);
                bfv[f] = *reinterpret_cast<const bf16x8v*>(&Bs[wn + f * 16 + rsel][kc + ksel]);
            }
            #pragma unroll
            for (int mf = 0; mf < 4; ++mf)
                #pragma unroll
                for (int nf = 0; nf < 4; ++nf)
                    acc[mf][nf] = __builtin_amdgcn_mfma_f32_16x16x32_bf16(af[mf], bfv[nf], acc[mf][nf], 0, 0, 0);
        }
        __syncthreads();
    }
    // epilogue: C/D layout col=lane&15, row=(lane>>4)*4+reg
    int col_l = lane & 15, rgrp = (lane >> 4) * 4;
    unsigned short* Hs = smem;              // [128][136]
    unsigned short* WzS = smem + 17408;     // [16][136]
    #pragma unroll
    for (int nf = 0; nf < 4; ++nf) {
        int col = wn + nf * 16 + col_l;
        float bv = bias[col];
        #pragma unroll
        for (int mf = 0; mf < 4; ++mf) {
            #pragma unroll
            for (int j = 0; j < 4; ++j) {
                int lrow = wm + mf * 16 + rgrp + j;
                float v = fmaxf(acc[mf][nf][j] + bv, 0.f);
                unsigned short hb = f2bf(v);
                if (FUSEZ) {
                    Hs[lrow * 136 + col] = hb;
                } else {
                    int row = r0 + lrow;
                    if (row < M) Coutb[(size_t)row * 128 + col] = hb;
                }
            }
        }
    }
    if (FUSEZ) {
        for (int t = tid; t < 2048; t += 256) {
            WzS[(t >> 7) * 136 + (t & 127)] = Wzg[t];
        }
        __syncthreads();
        int wmz = wid * 32;
        f32x4v z0 = (f32x4v){0.f, 0.f, 0.f, 0.f};
        f32x4v z1 = (f32x4v){0.f, 0.f, 0.f, 0.f};
        #pragma unroll
        for (int kt2 = 0; kt2 < 128; kt2 += 32) {
            bf16x8v a0 = *reinterpret_cast<const bf16x8v*>(&Hs[(wmz + rsel) * 136 + kt2 + ksel]);
            bf16x8v a1 = *reinterpret_cast<const bf16x8v*>(&Hs[(wmz + 16 + rsel) * 136 + kt2 + ksel]);
            bf16x8v bz = *reinterpret_cast<const bf16x8v*>(&WzS[rsel * 136 + kt2 + ksel]);
            z0 = __builtin_amdgcn_mfma_f32_16x16x32_bf16(a0, bz, z0, 0, 0, 0);
            z1 = __builtin_amdgcn_mfma_f32_16x16x32_bf16(a1, bz, z1, 0, 0, 0);
        }
        #pragma unroll
        for (int j = 0; j < 4; ++j) {
            int ra = r0 + wmz + rgrp + j;
            if (ra < M) Zout[(size_t)ra * 16 + col_l] = z0[j];
            int rb = r0 + wmz + 16 + rgrp + j;
            if (rb < M) Zout[(size_t)rb * 16 + col_l] = z1[j];
        }
    }
}

// ---------------- launch ----------------
extern "C" void kernel_launch(void* const* d_in, const int* in_sizes, int n_in,
                              void* d_out, int out_size, void* d_ws, size_t ws_size,
                              hipStream_t stream) {
    const float* x  = (const float*)d_in[0];
    const int*   ei = (const int*)d_in[1];
    const float* ew = (const float*)d_in[2];
    const float* W0 = (const float*)d_in[3];
    const float* b0 = (const float*)d_in[4];
    const float* W1 = (const float*)d_in[5];
    const float* b1 = (const float*)d_in[6];
    const float* W2 = (const float*)d_in[7];
    const float* b2 = (const float*)d_in[8];
    const float* W3 = (const float*)d_in[9];
    const float* b3 = (const float*)d_in[10];
    float* out = (float*)d_out;

    const int N = in_sizes[0] / 16;   // 100000
    const int E = in_sizes[2];        // 3200000
    const int* src = ei;
    const int* dst = ei + E;

    char* ws = (char*)d_ws;
    size_t off = 0;
    auto take = [&](size_t bytes) -> void* {
        void* p = ws + off;
        off = (off + bytes + 255) & ~(size_t)255;
        return p;
    };
    unsigned short* S   = (unsigned short*)take((size_t)N * 384 * 2);  // hop slots 1..3 (stride 384)
    unsigned short* Qa  = (unsigned short*)take((size_t)N * 128 * 2);
    unsigned short* Qb  = (unsigned short*)take((size_t)N * 128 * 2);
    unsigned short* S64 = (unsigned short*)take((size_t)N * 64 * 2);
    int2*  csr     = (int2*) take((size_t)E * 8);
    unsigned long long* dc = (unsigned long long*)take((size_t)N * 8);
    unsigned short* rank = (unsigned short*)take((size_t)E * 2);
    float* dis     = (float*)take((size_t)N * 4);
    int*   row_ptr = (int*)  take((size_t)(N + 1) * 4);
    int*   bsum    = (int*)  take(1024);
    int*   boff    = (int*)  take(1024);
    float* Z       = (float*)take((size_t)N * 16 * 4);
    float* T1      = (float*)take((size_t)N * 4 * 4);
    float* T2      = (float*)take((size_t)N * 4 * 4);
    unsigned short* Wt0 = (unsigned short*)take(64 * 128 * 2);
    unsigned short* Wt1 = (unsigned short*)take(512 * 128 * 2);
    unsigned short* Wt2 = (unsigned short*)take(512 * 128 * 2);
    unsigned short* Wz  = (unsigned short*)take(16 * 128 * 2);

    // ---- build norm + CSR (one packed atomic pass, atomic-free fill) ----
    hipMemsetAsync(dc, 0, (size_t)N * 8, stream);
    k_edge_deg<<<2048, 256, 0, stream>>>(dst, ew, dc, rank, E);
    int nsb = (N + 1023) / 1024;
    k_scan1<<<nsb, 256, 0, stream>>>(dc, bsum, dis, N);
    k_scan2<<<1, 64, 0, stream>>>(bsum, boff, nsb, &row_ptr[N]);
    k_scan3<<<nsb, 256, 0, stream>>>(dc, boff, row_ptr, N);
    k_fill_csr<<<2048, 256, 0, stream>>>(src, dst, ew, dis, row_ptr, rank, csr, E);

    // ---- weight prep (one kernel) ----
    k_wprep_all<<<(141312 + 255) / 256, 256, 0, stream>>>(W0, W1, W2, W3, Wt0, Wt1, Wt2, Wz);

    int gmfma = (N + 127) / 128;
    int gpw   = (N + 3) / 4;      // one node per wave, 4 waves/block

    // ---- layer 0: 16 -> 128 (bf16 hop chain in S64, stride 64) ----
    k_xcast<<<(N * 16 + 255) / 256, 256, 0, stream>>>(x, S64, N);
    k_prop16b<<<gpw, 256, 0, stream>>>(S64 + 0,  S64 + 16, row_ptr, csr, N);
    k_prop16b<<<gpw, 256, 0, stream>>>(S64 + 16, S64 + 32, row_ptr, csr, N);
    k_prop16b<<<gpw, 256, 0, stream>>>(S64 + 32, S64 + 48, row_ptr, csr, N);
    k_mfma_gemm<false><<<gmfma, 256, 0, stream>>>(S64, 64, nullptr, 0, 64, 64, Wt0, b0, Qa, nullptr, nullptr, N);

    // ---- layer 1: 128 -> 128 ----
    k_prop128b<<<gpw, 256, 0, stream>>>(Qa, 128,      S + 0,   384, row_ptr, csr, N);
    k_prop128b<<<gpw, 256, 0, stream>>>(S + 0, 384,   S + 128, 384, row_ptr, csr, N);
    k_prop128b<<<gpw, 256, 0, stream>>>(S + 128, 384, S + 256, 384, row_ptr, csr, N);
    k_mfma_gemm<false><<<gmfma, 256, 0, stream>>>(Qa, 128, S, 384, 128, 512, Wt1, b1, Qb, nullptr, nullptr, N);

    // ---- layer 2: 128 -> 128, Z fused into epilogue ----
    k_prop128b<<<gpw, 256, 0, stream>>>(Qb, 128,      S + 0,   384, row_ptr, csr, N);
    k_prop128b<<<gpw, 256, 0, stream>>>(S + 0, 384,   S + 128, 384, row_ptr, csr, N);
    k_prop128b<<<gpw, 256, 0, stream>>>(S + 128, 384, S + 256, 384, row_ptr, csr, N);
    k_mfma_gemm<true><<<gmfma, 256, 0, stream>>>(Qb, 128, S, 384, 128, 512, Wt2, b2, nullptr, Wz, Z, N);

    // ---- layer 3: 128 -> 4 via projected Horner (on Z) ----
    {
        int g = (N + 63) / 64;
        k_prop4_add<<<g, 256, 0, stream>>>(Z, 16, 12, Z, 8, nullptr, T1, row_ptr, csr, N);
        k_prop4_add<<<g, 256, 0, stream>>>(T1, 4, 0, Z, 4, nullptr, T2, row_ptr, csr, N);
        k_prop4_add<<<g, 256, 0, stream>>>(T2, 4, 0, Z, 0, b3, out, row_ptr, csr, N);
    }
}

// Round 9
// 1188.990 us; speedup vs baseline: 4.9028x; 1.0722x over previous
//
#include <hip/hip_runtime.h>

// TAGConv L3: N=100000, E=3200000, K=3. dims (16->128)(128->128)(128->128)(128->4).
// R8: compact d=16 hop buffers (stride 16, L2-resident) + 4-pointer layer-0 GEMM staging;
//     Z stored as 4 compact N x 4 planes; prop4_add 16-lanes/node edge-parallel;
//     prop128b 16 edges in flight. CSR via packed-u64 atomic rank; Z-fused layer-2 GEMM.

typedef __attribute__((ext_vector_type(8))) short bf16x8v;   // 8 bf16 = 4 VGPR
typedef __attribute__((ext_vector_type(4))) float f32x4v;

__device__ __forceinline__ float bflo(unsigned int u) { return __uint_as_float(u << 16); }
__device__ __forceinline__ float bfhi(unsigned int u) { return __uint_as_float(u & 0xffff0000u); }
__device__ __forceinline__ unsigned short f2bf(float f) {
    unsigned int u = __float_as_uint(f);
    u = (u + 0x7fff + ((u >> 16) & 1)) >> 16;   // RNE
    return (unsigned short)u;
}
__device__ __forceinline__ unsigned int pack2bf(float lo, float hi) {
    return (unsigned int)f2bf(lo) | ((unsigned int)f2bf(hi) << 16);
}

// ---------------- pass 1: packed deg/count atomic + per-edge rank ----------------
__global__ void k_edge_deg(const int* __restrict__ dst, const float* __restrict__ ew,
                           unsigned long long* __restrict__ dc,
                           unsigned short* __restrict__ rank, int E) {
    int stride = gridDim.x * blockDim.x;
    for (int e = blockIdx.x * blockDim.x + threadIdx.x; e < E; e += stride) {
        int d = dst[e];
        unsigned long long fx = (unsigned long long)(ew[e] * 0x1p40f);
        unsigned long long old = atomicAdd(&dc[d], (fx << 12) | 1ULL);
        rank[e] = (unsigned short)(old & 0xFFFULL);
    }
}

// ---------------- scan phase 1 (+ dis fused) ----------------
__global__ void k_scan1(const unsigned long long* __restrict__ dc, int* __restrict__ bsum,
                        float* __restrict__ dis, int N) {
    __shared__ int s[256];
    int tid = threadIdx.x;
    int base = blockIdx.x * 1024 + tid * 4;
    int t = 0;
    #pragma unroll
    for (int i = 0; i < 4; ++i) {
        int idx = base + i;
        if (idx < N) {
            unsigned long long v = dc[idx];
            t += (int)(v & 0xFFFULL);
            float d = (float)(v >> 12) * 0x1p-40f;
            dis[idx] = d > 0.f ? rsqrtf(d) : 0.f;
        }
    }
    s[tid] = t; __syncthreads();
    for (int off = 128; off > 0; off >>= 1) {
        if (tid < off) s[tid] += s[tid + off];
        __syncthreads();
    }
    if (tid == 0) bsum[blockIdx.x] = s[0];
}

__global__ void k_scan2(const int* __restrict__ bsum, int* __restrict__ boff,
                        int nb, int* __restrict__ row_ptr_last) {
    if (threadIdx.x == 0) {
        int run = 0;
        for (int i = 0; i < nb; ++i) { boff[i] = run; run += bsum[i]; }
        *row_ptr_last = run;
    }
}

__global__ void k_scan3(const unsigned long long* __restrict__ dc, const int* __restrict__ boff,
                        int* __restrict__ row_ptr, int N) {
    __shared__ int s[256];
    int tid = threadIdx.x;
    int base = blockIdx.x * 1024 + tid * 4;
    int v[4]; int t = 0;
    #pragma unroll
    for (int i = 0; i < 4; ++i) { int idx = base + i; v[i] = (idx < N) ? (int)(dc[idx] & 0xFFFULL) : 0; t += v[i]; }
    s[tid] = t; __syncthreads();
    for (int off = 1; off < 256; off <<= 1) {
        int add = (tid >= off) ? s[tid - off] : 0;
        __syncthreads();
        s[tid] += add;
        __syncthreads();
    }
    int g = boff[blockIdx.x] + (s[tid] - t);   // exclusive prefix
    #pragma unroll
    for (int i = 0; i < 4; ++i) {
        int idx = base + i;
        if (idx < N) row_ptr[idx] = g;
        g += v[i];
    }
}

// ---------------- pass 2: atomic-free CSR fill ----------------
__global__ void k_fill_csr(const int* __restrict__ src, const int* __restrict__ dst,
                           const float* __restrict__ ew, const float* __restrict__ dis,
                           const int* __restrict__ row_ptr, const unsigned short* __restrict__ rank,
                           int2* __restrict__ csr, int E) {
    int stride = gridDim.x * blockDim.x;
    for (int e = blockIdx.x * blockDim.x + threadIdx.x; e < E; e += stride) {
        int d = dst[e];
        int s = src[e];
        int pos = row_ptr[d] + rank[e];
        float w = dis[s] * ew[e] * dis[d];
        csr[pos] = make_int2(s, __float_as_int(w));
    }
}

// ---------------- x -> bf16 compact (d=16) ----------------
__global__ void k_xcast(const float* __restrict__ x, unsigned short* __restrict__ h0, int total8) {
    int t = blockIdx.x * blockDim.x + threadIdx.x;
    if (t < total8) {
        float4 v0 = *reinterpret_cast<const float4*>(&x[t * 8]);
        float4 v1 = *reinterpret_cast<const float4*>(&x[t * 8 + 4]);
        uint4 o;
        o.x = pack2bf(v0.x, v0.y); o.y = pack2bf(v0.z, v0.w);
        o.z = pack2bf(v1.x, v1.y); o.w = pack2bf(v1.z, v1.w);
        *reinterpret_cast<uint4*>(&h0[t * 8]) = o;
    }
}

// ---------------- prop d=16: one node/wave, 16 edges x 4 lanes, compact stride 16 ----------------
__global__ __launch_bounds__(256) void k_prop16b(const unsigned short* __restrict__ hin,
                                                 unsigned short* __restrict__ bout,
                                                 const int* __restrict__ row_ptr,
                                                 const int2* __restrict__ csr, int N) {
    int node = blockIdx.x * 4 + (threadIdx.x >> 6);
    if (node >= N) return;
    int lane = threadIdx.x & 63;
    int esub = lane >> 2, f4 = (lane & 3) * 4;
    int s = row_ptr[node], e = row_ptr[node + 1];
    float a0 = 0.f, a1 = 0.f, a2 = 0.f, a3 = 0.f;
    for (int i = s + esub; i < e; i += 16) {
        int2 ed = csr[i];
        float w = __int_as_float(ed.y);
        uint2 r = *reinterpret_cast<const uint2*>(&hin[(size_t)ed.x * 16 + f4]);
        a0 += w * bflo(r.x); a1 += w * bfhi(r.x);
        a2 += w * bflo(r.y); a3 += w * bfhi(r.y);
    }
    #pragma unroll
    for (int m = 4; m <= 32; m <<= 1) {
        a0 += __shfl_xor(a0, m); a1 += __shfl_xor(a1, m);
        a2 += __shfl_xor(a2, m); a3 += __shfl_xor(a3, m);
    }
    if (lane < 4) {
        uint2 ob; ob.x = pack2bf(a0, a1); ob.y = pack2bf(a2, a3);
        *reinterpret_cast<uint2*>(&bout[(size_t)node * 16 + f4]) = ob;
    }
}

// ---------------- prop d=128: one node/wave, 16 edges in flight (4/lane) ----------------
__global__ __launch_bounds__(256) void k_prop128b(const unsigned short* __restrict__ hin, int gs,
                                                  unsigned short* __restrict__ bout, int os,
                                                  const int* __restrict__ row_ptr,
                                                  const int2* __restrict__ csr, int N) {
    int node = blockIdx.x * 4 + (threadIdx.x >> 6);
    if (node >= N) return;
    int lane = threadIdx.x & 63;
    int esub = lane >> 4, f8 = (lane & 15) * 8;
    int s = row_ptr[node], e = row_ptr[node + 1];
    float a0 = 0.f, a1 = 0.f, a2 = 0.f, a3 = 0.f;
    float a4 = 0.f, a5 = 0.f, a6 = 0.f, a7 = 0.f;
    int i = s;
    for (; i + 16 <= e; i += 16) {
        int2 e0 = csr[i + esub], e1 = csr[i + esub + 4];
        int2 e2 = csr[i + esub + 8], e3 = csr[i + esub + 12];
        uint4 r0 = *reinterpret_cast<const uint4*>(&hin[(size_t)e0.x * gs + f8]);
        uint4 r1 = *reinterpret_cast<const uint4*>(&hin[(size_t)e1.x * gs + f8]);
        uint4 r2 = *reinterpret_cast<const uint4*>(&hin[(size_t)e2.x * gs + f8]);
        uint4 r3 = *reinterpret_cast<const uint4*>(&hin[(size_t)e3.x * gs + f8]);
        float w0 = __int_as_float(e0.y), w1 = __int_as_float(e1.y);
        float w2 = __int_as_float(e2.y), w3 = __int_as_float(e3.y);
        a0 += w0 * bflo(r0.x) + w1 * bflo(r1.x) + w2 * bflo(r2.x) + w3 * bflo(r3.x);
        a1 += w0 * bfhi(r0.x) + w1 * bfhi(r1.x) + w2 * bfhi(r2.x) + w3 * bfhi(r3.x);
        a2 += w0 * bflo(r0.y) + w1 * bflo(r1.y) + w2 * bflo(r2.y) + w3 * bflo(r3.y);
        a3 += w0 * bfhi(r0.y) + w1 * bfhi(r1.y) + w2 * bfhi(r2.y) + w3 * bfhi(r3.y);
        a4 += w0 * bflo(r0.z) + w1 * bflo(r1.z) + w2 * bflo(r2.z) + w3 * bflo(r3.z);
        a5 += w0 * bfhi(r0.z) + w1 * bfhi(r1.z) + w2 * bfhi(r2.z) + w3 * bfhi(r3.z);
        a6 += w0 * bflo(r0.w) + w1 * bflo(r1.w) + w2 * bflo(r2.w) + w3 * bflo(r3.w);
        a7 += w0 * bfhi(r0.w) + w1 * bfhi(r1.w) + w2 * bfhi(r2.w) + w3 * bfhi(r3.w);
    }
    for (int ii = i + esub; ii < e; ii += 4) {
        int2 ed = csr[ii];
        float w = __int_as_float(ed.y);
        uint4 r = *reinterpret_cast<const uint4*>(&hin[(size_t)ed.x * gs + f8]);
        a0 += w * bflo(r.x); a1 += w * bfhi(r.x);
        a2 += w * bflo(r.y); a3 += w * bfhi(r.y);
        a4 += w * bflo(r.z); a5 += w * bfhi(r.z);
        a6 += w * bflo(r.w); a7 += w * bfhi(r.w);
    }
    #pragma unroll
    for (int m = 16; m <= 32; m <<= 1) {
        a0 += __shfl_xor(a0, m); a1 += __shfl_xor(a1, m);
        a2 += __shfl_xor(a2, m); a3 += __shfl_xor(a3, m);
        a4 += __shfl_xor(a4, m); a5 += __shfl_xor(a5, m);
        a6 += __shfl_xor(a6, m); a7 += __shfl_xor(a7, m);
    }
    if (lane < 16) {
        uint4 ob;
        ob.x = pack2bf(a0, a1); ob.y = pack2bf(a2, a3);
        ob.z = pack2bf(a4, a5); ob.w = pack2bf(a6, a7);
        *reinterpret_cast<uint4*>(&bout[(size_t)node * os + f8]) = ob;
    }
}

// ---------------- prop d=4 with add: 16 lanes/node, 4 edges parallel ----------------
__global__ __launch_bounds__(256) void k_prop4_add(const float* __restrict__ tin,
                                                   const float* __restrict__ zadd,
                                                   const float* __restrict__ bias,
                                                   float* __restrict__ tout,
                                                   const int* __restrict__ row_ptr,
                                                   const int2* __restrict__ csr, int N) {
    int node = blockIdx.x * 16 + (threadIdx.x >> 4);
    if (node >= N) return;
    int lane = threadIdx.x & 15;
    int esub = lane >> 2, j = lane & 3;
    int s = row_ptr[node], e = row_ptr[node + 1];
    float a = 0.f;
    for (int i = s + esub; i < e; i += 4) {
        int2 ed = csr[i];
        a += __int_as_float(ed.y) * tin[(size_t)ed.x * 4 + j];
    }
    a += __shfl_xor(a, 4);
    a += __shfl_xor(a, 8);
    if (esub == 0) {
        float v = a + zadd[(size_t)node * 4 + j];
        if (bias) v += bias[j];
        tout[(size_t)node * 4 + j] = v;
    }
}

// ---------------- weight prep (all layers in one kernel) ----------------
__global__ void k_wprep_all(const float* __restrict__ W0, const float* __restrict__ W1,
                            const float* __restrict__ W2, const float* __restrict__ W3,
                            unsigned short* __restrict__ Wt0, unsigned short* __restrict__ Wt1,
                            unsigned short* __restrict__ Wt2, unsigned short* __restrict__ Wz) {
    int t = blockIdx.x * blockDim.x + threadIdx.x;
    if (t < 8192) {
        int c = t >> 6, r = t & 63;
        Wt0[t] = f2bf(W0[r * 128 + c]);
    } else if (t < 8192 + 65536) {
        int u = t - 8192; int c = u >> 9, r = u & 511;
        Wt1[u] = f2bf(W1[r * 128 + c]);
    } else if (t < 8192 + 131072) {
        int u = t - (8192 + 65536); int c = u >> 9, r = u & 511;
        Wt2[u] = f2bf(W2[r * 128 + c]);
    } else if (t < 8192 + 131072 + 2048) {
        int u = t - (8192 + 131072); int c = u >> 7, k = u & 127;
        Wz[u] = f2bf(W3[(c >> 2) * 512 + k * 4 + (c & 3)]);
    }
}

// ---------------- MFMA GEMM: C(Mx128)bf16 = relu(A(MxK)bf16 @ Bt(128xK)^T + bias) ----------------
// A from 4 hop buffers: !L0 -> hop = kt>>7 (K=512, per-hop 128 cols); L0 -> hop = off>>4 (K=64, 16 cols each).
// FUSEZ: Z planes (4 x N x 4 fp32) = relu'd-h @ Wz^T via LDS round-trip; Cout write skipped.
template <bool L0, bool FUSEZ>
__global__ __launch_bounds__(256) void k_mfma_gemm(const unsigned short* __restrict__ a0p, int s0,
                                                   const unsigned short* __restrict__ a1p, int s1,
                                                   const unsigned short* __restrict__ a2p, int s2,
                                                   const unsigned short* __restrict__ a3p, int s3,
                                                   int K,
                                                   const unsigned short* __restrict__ Bt,
                                                   const float* __restrict__ bias,
                                                   unsigned short* __restrict__ Coutb,
                                                   const unsigned short* __restrict__ Wzg,
                                                   float* __restrict__ Zout, int M) {
    __shared__ unsigned short smem[19584];   // As[128][72] | Bs[128][72]; reused as Hs[128][136] + WzS[16][136]
    unsigned short (*As)[72] = reinterpret_cast<unsigned short(*)[72]>(smem);
    unsigned short (*Bs)[72] = reinterpret_cast<unsigned short(*)[72]>(smem + 9216);
    const unsigned short* Ab[4] = { a0p, a1p, a2p, a3p };
    int Ast[4] = { s0, s1, s2, s3 };
    int tid = threadIdx.x;
    int r0 = blockIdx.x * 128;
    int wid = tid >> 6, lane = tid & 63;
    int wm = (wid >> 1) * 64, wn = (wid & 1) * 64;
    f32x4v acc[4][4];
    #pragma unroll
    for (int a = 0; a < 4; ++a)
        #pragma unroll
        for (int b = 0; b < 4; ++b) acc[a][b] = (f32x4v){0.f, 0.f, 0.f, 0.f};

    int rsel = lane & 15, ksel = (lane >> 4) * 8;

    for (int kt = 0; kt < K; kt += 64) {
        #pragma unroll
        for (int i = 0; i < 4; ++i) {
            int c = tid + i * 256;
            int row = c >> 3, off = (c & 7) * 8;
            int gr = r0 + row;
            int4 v = make_int4(0, 0, 0, 0);
            if (L0) {
                int hop = off >> 4, col0 = off & 15;
                if (gr < M) v = *reinterpret_cast<const int4*>(Ab[hop] + (size_t)gr * 16 + col0);
            } else {
                int hop = kt >> 7, kb = kt & 127;
                if (gr < M) v = *reinterpret_cast<const int4*>(Ab[hop] + (size_t)gr * Ast[hop] + kb + off);
            }
            *reinterpret_cast<int4*>(&As[row][off]) = v;
            int4 w = *reinterpret_cast<const int4*>(Bt + (size_t)row * K + kt + off);
            *reinterpret_cast<int4*>(&Bs[row][off]) = w;
        }
        __syncthreads();
        #pragma unroll
        for (int kc = 0; kc < 64; kc += 32) {
            bf16x8v af[4], bfv[4];
            #pragma unroll
            for (int f = 0; f < 4; ++f) {
                af[f]  = *reinterpret_cast<const bf16x8v*>(&As[wm + f * 16 + rsel][kc + ksel]);
                bfv[f] = *reinterpret_cast<const bf16x8v*>(&Bs[wn + f * 16 + rsel][kc + ksel]);
            }
            #pragma unroll
            for (int mf = 0; mf < 4; ++mf)
                #pragma unroll
                for (int nf = 0; nf < 4; ++nf)
                    acc[mf][nf] = __builtin_amdgcn_mfma_f32_16x16x32_bf16(af[mf], bfv[nf], acc[mf][nf], 0, 0, 0);
        }
        __syncthreads();
    }
    // epilogue: C/D layout col=lane&15, row=(lane>>4)*4+reg
    int col_l = lane & 15, rgrp = (lane >> 4) * 4;
    unsigned short* Hs = smem;              // [128][136]
    unsigned short* WzS = smem + 17408;     // [16][136]
    #pragma unroll
    for (int nf = 0; nf < 4; ++nf) {
        int col = wn + nf * 16 + col_l;
        float bv = bias[col];
        #pragma unroll
        for (int mf = 0; mf < 4; ++mf) {
            #pragma unroll
            for (int j = 0; j < 4; ++j) {
                int lrow = wm + mf * 16 + rgrp + j;
                float v = fmaxf(acc[mf][nf][j] + bv, 0.f);
                unsigned short hb = f2bf(v);
                if (FUSEZ) {
                    Hs[lrow * 136 + col] = hb;
                } else {
                    int row = r0 + lrow;
                    if (row < M) Coutb[(size_t)row * 128 + col] = hb;
                }
            }
        }
    }
    if (FUSEZ) {
        for (int t = tid; t < 2048; t += 256) {
            WzS[(t >> 7) * 136 + (t & 127)] = Wzg[t];
        }
        __syncthreads();
        int wmz = wid * 32;
        f32x4v z0 = (f32x4v){0.f, 0.f, 0.f, 0.f};
        f32x4v z1 = (f32x4v){0.f, 0.f, 0.f, 0.f};
        #pragma unroll
        for (int kt2 = 0; kt2 < 128; kt2 += 32) {
            bf16x8v aa0 = *reinterpret_cast<const bf16x8v*>(&Hs[(wmz + rsel) * 136 + kt2 + ksel]);
            bf16x8v aa1 = *reinterpret_cast<const bf16x8v*>(&Hs[(wmz + 16 + rsel) * 136 + kt2 + ksel]);
            bf16x8v bz = *reinterpret_cast<const bf16x8v*>(&WzS[rsel * 136 + kt2 + ksel]);
            z0 = __builtin_amdgcn_mfma_f32_16x16x32_bf16(aa0, bz, z0, 0, 0, 0);
            z1 = __builtin_amdgcn_mfma_f32_16x16x32_bf16(aa1, bz, z1, 0, 0, 0);
        }
        // Z planes: plane = col>>2, within-plane col = col&3
        size_t plane = (size_t)(col_l >> 2) * (size_t)M * 4;
        int cj = col_l & 3;
        #pragma unroll
        for (int j = 0; j < 4; ++j) {
            int ra = r0 + wmz + rgrp + j;
            if (ra < M) Zout[plane + (size_t)ra * 4 + cj] = z0[j];
            int rb = r0 + wmz + 16 + rgrp + j;
            if (rb < M) Zout[plane + (size_t)rb * 4 + cj] = z1[j];
        }
    }
}

// ---------------- launch ----------------
extern "C" void kernel_launch(void* const* d_in, const int* in_sizes, int n_in,
                              void* d_out, int out_size, void* d_ws, size_t ws_size,
                              hipStream_t stream) {
    const float* x  = (const float*)d_in[0];
    const int*   ei = (const int*)d_in[1];
    const float* ew = (const float*)d_in[2];
    const float* W0 = (const float*)d_in[3];
    const float* b0 = (const float*)d_in[4];
    const float* W1 = (const float*)d_in[5];
    const float* b1 = (const float*)d_in[6];
    const float* W2 = (const float*)d_in[7];
    const float* b2 = (const float*)d_in[8];
    const float* W3 = (const float*)d_in[9];
    const float* b3 = (const float*)d_in[10];
    float* out = (float*)d_out;

    const int N = in_sizes[0] / 16;   // 100000
    const int E = in_sizes[2];        // 3200000
    const int* src = ei;
    const int* dst = ei + E;

    char* ws = (char*)d_ws;
    size_t off = 0;
    auto take = [&](size_t bytes) -> void* {
        void* p = ws + off;
        off = (off + bytes + 255) & ~(size_t)255;
        return p;
    };
    unsigned short* S   = (unsigned short*)take((size_t)N * 384 * 2);  // hop slots 1..3 (stride 384)
    unsigned short* Qa  = (unsigned short*)take((size_t)N * 128 * 2);
    unsigned short* Qb  = (unsigned short*)take((size_t)N * 128 * 2);
    unsigned short* H0  = (unsigned short*)take((size_t)N * 16 * 2);  // layer-0 compact hops
    unsigned short* H1  = (unsigned short*)take((size_t)N * 16 * 2);
    unsigned short* H2  = (unsigned short*)take((size_t)N * 16 * 2);
    unsigned short* H3  = (unsigned short*)take((size_t)N * 16 * 2);
    int2*  csr     = (int2*) take((size_t)E * 8);
    unsigned long long* dc = (unsigned long long*)take((size_t)N * 8);
    unsigned short* rank = (unsigned short*)take((size_t)E * 2);
    float* dis     = (float*)take((size_t)N * 4);
    int*   row_ptr = (int*)  take((size_t)(N + 1) * 4);
    int*   bsum    = (int*)  take(1024);
    int*   boff    = (int*)  take(1024);
    float* Z       = (float*)take((size_t)N * 16 * 4);   // 4 planes of N x 4
    float* T1      = (float*)take((size_t)N * 4 * 4);
    float* T2      = (float*)take((size_t)N * 4 * 4);
    unsigned short* Wt0 = (unsigned short*)take(64 * 128 * 2);
    unsigned short* Wt1 = (unsigned short*)take(512 * 128 * 2);
    unsigned short* Wt2 = (unsigned short*)take(512 * 128 * 2);
    unsigned short* Wz  = (unsigned short*)take(16 * 128 * 2);

    // ---- build norm + CSR (one packed atomic pass, atomic-free fill) ----
    hipMemsetAsync(dc, 0, (size_t)N * 8, stream);
    k_edge_deg<<<2048, 256, 0, stream>>>(dst, ew, dc, rank, E);
    int nsb = (N + 1023) / 1024;
    k_scan1<<<nsb, 256, 0, stream>>>(dc, bsum, dis, N);
    k_scan2<<<1, 64, 0, stream>>>(bsum, boff, nsb, &row_ptr[N]);
    k_scan3<<<nsb, 256, 0, stream>>>(dc, boff, row_ptr, N);
    k_fill_csr<<<2048, 256, 0, stream>>>(src, dst, ew, dis, row_ptr, rank, csr, E);

    // ---- weight prep (one kernel) ----
    k_wprep_all<<<(141312 + 255) / 256, 256, 0, stream>>>(W0, W1, W2, W3, Wt0, Wt1, Wt2, Wz);

    int gmfma = (N + 127) / 128;
    int gpw   = (N + 3) / 4;      // one node per wave, 4 waves/block
    size_t N4 = (size_t)N * 4;

    // ---- layer 0: 16 -> 128 (compact bf16 hop chain H0..H3) ----
    k_xcast<<<(N * 2 + 255) / 256, 256, 0, stream>>>(x, H0, N * 2);
    k_prop16b<<<gpw, 256, 0, stream>>>(H0, H1, row_ptr, csr, N);
    k_prop16b<<<gpw, 256, 0, stream>>>(H1, H2, row_ptr, csr, N);
    k_prop16b<<<gpw, 256, 0, stream>>>(H2, H3, row_ptr, csr, N);
    k_mfma_gemm<true, false><<<gmfma, 256, 0, stream>>>(H0, 16, H1, 16, H2, 16, H3, 16,
                                                        64, Wt0, b0, Qa, nullptr, nullptr, N);

    // ---- layer 1: 128 -> 128 ----
    k_prop128b<<<gpw, 256, 0, stream>>>(Qa, 128,      S + 0,   384, row_ptr, csr, N);
    k_prop128b<<<gpw, 256, 0, stream>>>(S + 0, 384,   S + 128, 384, row_ptr, csr, N);
    k_prop128b<<<gpw, 256, 0, stream>>>(S + 128, 384, S + 256, 384, row_ptr, csr, N);
    k_mfma_gemm<false, false><<<gmfma, 256, 0, stream>>>(Qa, 128, S + 0, 384, S + 128, 384, S + 256, 384,
                                                         512, Wt1, b1, Qb, nullptr, nullptr, N);

    // ---- layer 2: 128 -> 128, Z fused into epilogue ----
    k_prop128b<<<gpw, 256, 0, stream>>>(Qb, 128,      S + 0,   384, row_ptr, csr, N);
    k_prop128b<<<gpw, 256, 0, stream>>>(S + 0, 384,   S + 128, 384, row_ptr, csr, N);
    k_prop128b<<<gpw, 256, 0, stream>>>(S + 128, 384, S + 256, 384, row_ptr, csr, N);
    k_mfma_gemm<false, true><<<gmfma, 256, 0, stream>>>(Qb, 128, S + 0, 384, S + 128, 384, S + 256, 384,
                                                        512, Wt2, b2, nullptr, Wz, Z, N);

    // ---- layer 3: 128 -> 4 via projected Horner on Z planes ----
    {
        int g = (N + 15) / 16;
        k_prop4_add<<<g, 256, 0, stream>>>(Z + 3 * N4, Z + 2 * N4, nullptr, T1, row_ptr, csr, N);
        k_prop4_add<<<g, 256, 0, stream>>>(T1,         Z + 1 * N4, nullptr, T2, row_ptr, csr, N);
        k_prop4_add<<<g, 256, 0, stream>>>(T2,         Z + 0 * N4, b3,      out, row_ptr, csr, N);
    }
}

// Round 10
// 1163.230 us; speedup vs baseline: 5.0113x; 1.0221x over previous
//
#include <hip/hip_runtime.h>

// TAGConv L3: N=100000, E=3200000, K=3. dims (16->128)(128->128)(128->128)(128->4).
// R9: packed 4-byte CSR entry: (src<<15) | (bf16(w)&0x7FFF)  [w>=0 so bf16 sign=0; src<2^17].
//     Halves CSR stream in all 9 props and halves fill_csr scatter traffic.
//     Otherwise = R8: compact hop buffers, one-node-per-wave props, Z-fused layer-2 GEMM,
//     packed-u64 atomic CSR build, stacked-K bf16 MFMA GEMMs, d=4 Horner layer 3.

typedef __attribute__((ext_vector_type(8))) short bf16x8v;   // 8 bf16 = 4 VGPR
typedef __attribute__((ext_vector_type(4))) float f32x4v;

__device__ __forceinline__ float bflo(unsigned int u) { return __uint_as_float(u << 16); }
__device__ __forceinline__ float bfhi(unsigned int u) { return __uint_as_float(u & 0xffff0000u); }
__device__ __forceinline__ unsigned short f2bf(float f) {
    unsigned int u = __float_as_uint(f);
    u = (u + 0x7fff + ((u >> 16) & 1)) >> 16;   // RNE
    return (unsigned short)u;
}
__device__ __forceinline__ unsigned int pack2bf(float lo, float hi) {
    return (unsigned int)f2bf(lo) | ((unsigned int)f2bf(hi) << 16);
}
// packed CSR decode
__device__ __forceinline__ unsigned int csr_src(unsigned int v) { return v >> 15; }
__device__ __forceinline__ float csr_w(unsigned int v) { return __uint_as_float((v & 0x7FFFu) << 16); }

// ---------------- pass 1: packed deg/count atomic + per-edge rank ----------------
__global__ void k_edge_deg(const int* __restrict__ dst, const float* __restrict__ ew,
                           unsigned long long* __restrict__ dc,
                           unsigned short* __restrict__ rank, int E) {
    int stride = gridDim.x * blockDim.x;
    for (int e = blockIdx.x * blockDim.x + threadIdx.x; e < E; e += stride) {
        int d = dst[e];
        unsigned long long fx = (unsigned long long)(ew[e] * 0x1p40f);
        unsigned long long old = atomicAdd(&dc[d], (fx << 12) | 1ULL);
        rank[e] = (unsigned short)(old & 0xFFFULL);
    }
}

// ---------------- scan phase 1 (+ dis fused) ----------------
__global__ void k_scan1(const unsigned long long* __restrict__ dc, int* __restrict__ bsum,
                        float* __restrict__ dis, int N) {
    __shared__ int s[256];
    int tid = threadIdx.x;
    int base = blockIdx.x * 1024 + tid * 4;
    int t = 0;
    #pragma unroll
    for (int i = 0; i < 4; ++i) {
        int idx = base + i;
        if (idx < N) {
            unsigned long long v = dc[idx];
            t += (int)(v & 0xFFFULL);
            float d = (float)(v >> 12) * 0x1p-40f;
            dis[idx] = d > 0.f ? rsqrtf(d) : 0.f;
        }
    }
    s[tid] = t; __syncthreads();
    for (int off = 128; off > 0; off >>= 1) {
        if (tid < off) s[tid] += s[tid + off];
        __syncthreads();
    }
    if (tid == 0) bsum[blockIdx.x] = s[0];
}

__global__ void k_scan2(const int* __restrict__ bsum, int* __restrict__ boff,
                        int nb, int* __restrict__ row_ptr_last) {
    if (threadIdx.x == 0) {
        int run = 0;
        for (int i = 0; i < nb; ++i) { boff[i] = run; run += bsum[i]; }
        *row_ptr_last = run;
    }
}

__global__ void k_scan3(const unsigned long long* __restrict__ dc, const int* __restrict__ boff,
                        int* __restrict__ row_ptr, int N) {
    __shared__ int s[256];
    int tid = threadIdx.x;
    int base = blockIdx.x * 1024 + tid * 4;
    int v[4]; int t = 0;
    #pragma unroll
    for (int i = 0; i < 4; ++i) { int idx = base + i; v[i] = (idx < N) ? (int)(dc[idx] & 0xFFFULL) : 0; t += v[i]; }
    s[tid] = t; __syncthreads();
    for (int off = 1; off < 256; off <<= 1) {
        int add = (tid >= off) ? s[tid - off] : 0;
        __syncthreads();
        s[tid] += add;
        __syncthreads();
    }
    int g = boff[blockIdx.x] + (s[tid] - t);   // exclusive prefix
    #pragma unroll
    for (int i = 0; i < 4; ++i) {
        int idx = base + i;
        if (idx < N) row_ptr[idx] = g;
        g += v[i];
    }
}

// ---------------- pass 2: atomic-free CSR fill (packed 4B entries) ----------------
__global__ void k_fill_csr(const int* __restrict__ src, const int* __restrict__ dst,
                           const float* __restrict__ ew, const float* __restrict__ dis,
                           const int* __restrict__ row_ptr, const unsigned short* __restrict__ rank,
                           unsigned int* __restrict__ csr, int E) {
    int stride = gridDim.x * blockDim.x;
    for (int e = blockIdx.x * blockDim.x + threadIdx.x; e < E; e += stride) {
        int d = dst[e];
        unsigned int s = (unsigned int)src[e];
        int pos = row_ptr[d] + rank[e];
        float w = dis[s] * ew[e] * dis[d];
        csr[pos] = (s << 15) | ((unsigned int)f2bf(w) & 0x7FFFu);
    }
}

// ---------------- x -> bf16 compact (d=16) ----------------
__global__ void k_xcast(const float* __restrict__ x, unsigned short* __restrict__ h0, int total8) {
    int t = blockIdx.x * blockDim.x + threadIdx.x;
    if (t < total8) {
        float4 v0 = *reinterpret_cast<const float4*>(&x[t * 8]);
        float4 v1 = *reinterpret_cast<const float4*>(&x[t * 8 + 4]);
        uint4 o;
        o.x = pack2bf(v0.x, v0.y); o.y = pack2bf(v0.z, v0.w);
        o.z = pack2bf(v1.x, v1.y); o.w = pack2bf(v1.z, v1.w);
        *reinterpret_cast<uint4*>(&h0[t * 8]) = o;
    }
}

// ---------------- prop d=16: one node/wave, 16 edges x 4 lanes, compact stride 16 ----------------
__global__ __launch_bounds__(256) void k_prop16b(const unsigned short* __restrict__ hin,
                                                 unsigned short* __restrict__ bout,
                                                 const int* __restrict__ row_ptr,
                                                 const unsigned int* __restrict__ csr, int N) {
    int node = blockIdx.x * 4 + (threadIdx.x >> 6);
    if (node >= N) return;
    int lane = threadIdx.x & 63;
    int esub = lane >> 2, f4 = (lane & 3) * 4;
    int s = row_ptr[node], e = row_ptr[node + 1];
    float a0 = 0.f, a1 = 0.f, a2 = 0.f, a3 = 0.f;
    for (int i = s + esub; i < e; i += 16) {
        unsigned int ed = csr[i];
        float w = csr_w(ed);
        uint2 r = *reinterpret_cast<const uint2*>(&hin[(size_t)csr_src(ed) * 16 + f4]);
        a0 += w * bflo(r.x); a1 += w * bfhi(r.x);
        a2 += w * bflo(r.y); a3 += w * bfhi(r.y);
    }
    #pragma unroll
    for (int m = 4; m <= 32; m <<= 1) {
        a0 += __shfl_xor(a0, m); a1 += __shfl_xor(a1, m);
        a2 += __shfl_xor(a2, m); a3 += __shfl_xor(a3, m);
    }
    if (lane < 4) {
        uint2 ob; ob.x = pack2bf(a0, a1); ob.y = pack2bf(a2, a3);
        *reinterpret_cast<uint2*>(&bout[(size_t)node * 16 + f4]) = ob;
    }
}

// ---------------- prop d=128: one node/wave, 16 edges in flight (4/lane) ----------------
__global__ __launch_bounds__(256) void k_prop128b(const unsigned short* __restrict__ hin, int gs,
                                                  unsigned short* __restrict__ bout, int os,
                                                  const int* __restrict__ row_ptr,
                                                  const unsigned int* __restrict__ csr, int N) {
    int node = blockIdx.x * 4 + (threadIdx.x >> 6);
    if (node >= N) return;
    int lane = threadIdx.x & 63;
    int esub = lane >> 4, f8 = (lane & 15) * 8;
    int s = row_ptr[node], e = row_ptr[node + 1];
    float a0 = 0.f, a1 = 0.f, a2 = 0.f, a3 = 0.f;
    float a4 = 0.f, a5 = 0.f, a6 = 0.f, a7 = 0.f;
    int i = s;
    for (; i + 16 <= e; i += 16) {
        unsigned int e0 = csr[i + esub],     e1 = csr[i + esub + 4];
        unsigned int e2 = csr[i + esub + 8], e3 = csr[i + esub + 12];
        uint4 r0 = *reinterpret_cast<const uint4*>(&hin[(size_t)csr_src(e0) * gs + f8]);
        uint4 r1 = *reinterpret_cast<const uint4*>(&hin[(size_t)csr_src(e1) * gs + f8]);
        uint4 r2 = *reinterpret_cast<const uint4*>(&hin[(size_t)csr_src(e2) * gs + f8]);
        uint4 r3 = *reinterpret_cast<const uint4*>(&hin[(size_t)csr_src(e3) * gs + f8]);
        float w0 = csr_w(e0), w1 = csr_w(e1), w2 = csr_w(e2), w3 = csr_w(e3);
        a0 += w0 * bflo(r0.x) + w1 * bflo(r1.x) + w2 * bflo(r2.x) + w3 * bflo(r3.x);
        a1 += w0 * bfhi(r0.x) + w1 * bfhi(r1.x) + w2 * bfhi(r2.x) + w3 * bfhi(r3.x);
        a2 += w0 * bflo(r0.y) + w1 * bflo(r1.y) + w2 * bflo(r2.y) + w3 * bflo(r3.y);
        a3 += w0 * bfhi(r0.y) + w1 * bfhi(r1.y) + w2 * bfhi(r2.y) + w3 * bfhi(r3.y);
        a4 += w0 * bflo(r0.z) + w1 * bflo(r1.z) + w2 * bflo(r2.z) + w3 * bflo(r3.z);
        a5 += w0 * bfhi(r0.z) + w1 * bfhi(r1.z) + w2 * bfhi(r2.z) + w3 * bfhi(r3.z);
        a6 += w0 * bflo(r0.w) + w1 * bflo(r1.w) + w2 * bflo(r2.w) + w3 * bflo(r3.w);
        a7 += w0 * bfhi(r0.w) + w1 * bfhi(r1.w) + w2 * bfhi(r2.w) + w3 * bfhi(r3.w);
    }
    for (int ii = i + esub; ii < e; ii += 4) {
        unsigned int ed = csr[ii];
        float w = csr_w(ed);
        uint4 r = *reinterpret_cast<const uint4*>(&hin[(size_t)csr_src(ed) * gs + f8]);
        a0 += w * bflo(r.x); a1 += w * bfhi(r.x);
        a2 += w * bflo(r.y); a3 += w * bfhi(r.y);
        a4 += w * bflo(r.z); a5 += w * bfhi(r.z);
        a6 += w * bflo(r.w); a7 += w * bfhi(r.w);
    }
    #pragma unroll
    for (int m = 16; m <= 32; m <<= 1) {
        a0 += __shfl_xor(a0, m); a1 += __shfl_xor(a1, m);
        a2 += __shfl_xor(a2, m); a3 += __shfl_xor(a3, m);
        a4 += __shfl_xor(a4, m); a5 += __shfl_xor(a5, m);
        a6 += __shfl_xor(a6, m); a7 += __shfl_xor(a7, m);
    }
    if (lane < 16) {
        uint4 ob;
        ob.x = pack2bf(a0, a1); ob.y = pack2bf(a2, a3);
        ob.z = pack2bf(a4, a5); ob.w = pack2bf(a6, a7);
        *reinterpret_cast<uint4*>(&bout[(size_t)node * os + f8]) = ob;
    }
}

// ---------------- prop d=4 with add: 16 lanes/node, 4 edges parallel ----------------
__global__ __launch_bounds__(256) void k_prop4_add(const float* __restrict__ tin,
                                                   const float* __restrict__ zadd,
                                                   const float* __restrict__ bias,
                                                   float* __restrict__ tout,
                                                   const int* __restrict__ row_ptr,
                                                   const unsigned int* __restrict__ csr, int N) {
    int node = blockIdx.x * 16 + (threadIdx.x >> 4);
    if (node >= N) return;
    int lane = threadIdx.x & 15;
    int esub = lane >> 2, j = lane & 3;
    int s = row_ptr[node], e = row_ptr[node + 1];
    float a = 0.f;
    for (int i = s + esub; i < e; i += 4) {
        unsigned int ed = csr[i];
        a += csr_w(ed) * tin[(size_t)csr_src(ed) * 4 + j];
    }
    a += __shfl_xor(a, 4);
    a += __shfl_xor(a, 8);
    if (esub == 0) {
        float v = a + zadd[(size_t)node * 4 + j];
        if (bias) v += bias[j];
        tout[(size_t)node * 4 + j] = v;
    }
}

// ---------------- weight prep (all layers in one kernel) ----------------
__global__ void k_wprep_all(const float* __restrict__ W0, const float* __restrict__ W1,
                            const float* __restrict__ W2, const float* __restrict__ W3,
                            unsigned short* __restrict__ Wt0, unsigned short* __restrict__ Wt1,
                            unsigned short* __restrict__ Wt2, unsigned short* __restrict__ Wz) {
    int t = blockIdx.x * blockDim.x + threadIdx.x;
    if (t < 8192) {
        int c = t >> 6, r = t & 63;
        Wt0[t] = f2bf(W0[r * 128 + c]);
    } else if (t < 8192 + 65536) {
        int u = t - 8192; int c = u >> 9, r = u & 511;
        Wt1[u] = f2bf(W1[r * 128 + c]);
    } else if (t < 8192 + 131072) {
        int u = t - (8192 + 65536); int c = u >> 9, r = u & 511;
        Wt2[u] = f2bf(W2[r * 128 + c]);
    } else if (t < 8192 + 131072 + 2048) {
        int u = t - (8192 + 131072); int c = u >> 7, k = u & 127;
        Wz[u] = f2bf(W3[(c >> 2) * 512 + k * 4 + (c & 3)]);
    }
}

// ---------------- MFMA GEMM: C(Mx128)bf16 = relu(A(MxK)bf16 @ Bt(128xK)^T + bias) ----------------
// A from 4 hop buffers: !L0 -> hop = kt>>7 (K=512, per-hop 128 cols); L0 -> hop = off>>4 (K=64, 16 cols each).
// FUSEZ: Z planes (4 x N x 4 fp32) = relu'd-h @ Wz^T via LDS round-trip; Cout write skipped.
template <bool L0, bool FUSEZ>
__global__ __launch_bounds__(256) void k_mfma_gemm(const unsigned short* __restrict__ a0p, int s0,
                                                   const unsigned short* __restrict__ a1p, int s1,
                                                   const unsigned short* __restrict__ a2p, int s2,
                                                   const unsigned short* __restrict__ a3p, int s3,
                                                   int K,
                                                   const unsigned short* __restrict__ Bt,
                                                   const float* __restrict__ bias,
                                                   unsigned short* __restrict__ Coutb,
                                                   const unsigned short* __restrict__ Wzg,
                                                   float* __restrict__ Zout, int M) {
    __shared__ unsigned short smem[19584];   // As[128][72] | Bs[128][72]; reused as Hs[128][136] + WzS[16][136]
    unsigned short (*As)[72] = reinterpret_cast<unsigned short(*)[72]>(smem);
    unsigned short (*Bs)[72] = reinterpret_cast<unsigned short(*)[72]>(smem + 9216);
    const unsigned short* Ab[4] = { a0p, a1p, a2p, a3p };
    int Ast[4] = { s0, s1, s2, s3 };
    int tid = threadIdx.x;
    int r0 = blockIdx.x * 128;
    int wid = tid >> 6, lane = tid & 63;
    int wm = (wid >> 1) * 64, wn = (wid & 1) * 64;
    f32x4v acc[4][4];
    #pragma unroll
    for (int a = 0; a < 4; ++a)
        #pragma unroll
        for (int b = 0; b < 4; ++b) acc[a][b] = (f32x4v){0.f, 0.f, 0.f, 0.f};

    int rsel = lane & 15, ksel = (lane >> 4) * 8;

    for (int kt = 0; kt < K; kt += 64) {
        #pragma unroll
        for (int i = 0; i < 4; ++i) {
            int c = tid + i * 256;
            int row = c >> 3, off = (c & 7) * 8;
            int gr = r0 + row;
            int4 v = make_int4(0, 0, 0, 0);
            if (L0) {
                int hop = off >> 4, col0 = off & 15;
                if (gr < M) v = *reinterpret_cast<const int4*>(Ab[hop] + (size_t)gr * 16 + col0);
            } else {
                int hop = kt >> 7, kb = kt & 127;
                if (gr < M) v = *reinterpret_cast<const int4*>(Ab[hop] + (size_t)gr * Ast[hop] + kb + off);
            }
            *reinterpret_cast<int4*>(&As[row][off]) = v;
            int4 w = *reinterpret_cast<const int4*>(Bt + (size_t)row * K + kt + off);
            *reinterpret_cast<int4*>(&Bs[row][off]) = w;
        }
        __syncthreads();
        #pragma unroll
        for (int kc = 0; kc < 64; kc += 32) {
            bf16x8v af[4], bfv[4];
            #pragma unroll
            for (int f = 0; f < 4; ++f) {
                af[f]  = *reinterpret_cast<const bf16x8v*>(&As[wm + f * 16 + rsel][kc + ksel]);
                bfv[f] = *reinterpret_cast<const bf16x8v*>(&Bs[wn + f * 16 + rsel][kc + ksel]);
            }
            #pragma unroll
            for (int mf = 0; mf < 4; ++mf)
                #pragma unroll
                for (int nf = 0; nf < 4; ++nf)
                    acc[mf][nf] = __builtin_amdgcn_mfma_f32_16x16x32_bf16(af[mf], bfv[nf], acc[mf][nf], 0, 0, 0);
        }
        __syncthreads();
    }
    // epilogue: C/D layout col=lane&15, row=(lane>>4)*4+reg
    int col_l = lane & 15, rgrp = (lane >> 4) * 4;
    unsigned short* Hs = smem;              // [128][136]
    unsigned short* WzS = smem + 17408;     // [16][136]
    #pragma unroll
    for (int nf = 0; nf < 4; ++nf) {
        int col = wn + nf * 16 + col_l;
        float bv = bias[col];
        #pragma unroll
        for (int mf = 0; mf < 4; ++mf) {
            #pragma unroll
            for (int j = 0; j < 4; ++j) {
                int lrow = wm + mf * 16 + rgrp + j;
                float v = fmaxf(acc[mf][nf][j] + bv, 0.f);
                unsigned short hb = f2bf(v);
                if (FUSEZ) {
                    Hs[lrow * 136 + col] = hb;
                } else {
                    int row = r0 + lrow;
                    if (row < M) Coutb[(size_t)row * 128 + col] = hb;
                }
            }
        }
    }
    if (FUSEZ) {
        for (int t = tid; t < 2048; t += 256) {
            WzS[(t >> 7) * 136 + (t & 127)] = Wzg[t];
        }
        __syncthreads();
        int wmz = wid * 32;
        f32x4v z0 = (f32x4v){0.f, 0.f, 0.f, 0.f};
        f32x4v z1 = (f32x4v){0.f, 0.f, 0.f, 0.f};
        #pragma unroll
        for (int kt2 = 0; kt2 < 128; kt2 += 32) {
            bf16x8v aa0 = *reinterpret_cast<const bf16x8v*>(&Hs[(wmz + rsel) * 136 + kt2 + ksel]);
            bf16x8v aa1 = *reinterpret_cast<const bf16x8v*>(&Hs[(wmz + 16 + rsel) * 136 + kt2 + ksel]);
            bf16x8v bz = *reinterpret_cast<const bf16x8v*>(&WzS[rsel * 136 + kt2 + ksel]);
            z0 = __builtin_amdgcn_mfma_f32_16x16x32_bf16(aa0, bz, z0, 0, 0, 0);
            z1 = __builtin_amdgcn_mfma_f32_16x16x32_bf16(aa1, bz, z1, 0, 0, 0);
        }
        // Z planes: plane = col>>2, within-plane col = col&3
        size_t plane = (size_t)(col_l >> 2) * (size_t)M * 4;
        int cj = col_l & 3;
        #pragma unroll
        for (int j = 0; j < 4; ++j) {
            int ra = r0 + wmz + rgrp + j;
            if (ra < M) Zout[plane + (size_t)ra * 4 + cj] = z0[j];
            int rb = r0 + wmz + 16 + rgrp + j;
            if (rb < M) Zout[plane + (size_t)rb * 4 + cj] = z1[j];
        }
    }
}

// ---------------- launch ----------------
extern "C" void kernel_launch(void* const* d_in, const int* in_sizes, int n_in,
                              void* d_out, int out_size, void* d_ws, size_t ws_size,
                              hipStream_t stream) {
    const float* x  = (const float*)d_in[0];
    const int*   ei = (const int*)d_in[1];
    const float* ew = (const float*)d_in[2];
    const float* W0 = (const float*)d_in[3];
    const float* b0 = (const float*)d_in[4];
    const float* W1 = (const float*)d_in[5];
    const float* b1 = (const float*)d_in[6];
    const float* W2 = (const float*)d_in[7];
    const float* b2 = (const float*)d_in[8];
    const float* W3 = (const float*)d_in[9];
    const float* b3 = (const float*)d_in[10];
    float* out = (float*)d_out;

    const int N = in_sizes[0] / 16;   // 100000
    const int E = in_sizes[2];        // 3200000
    const int* src = ei;
    const int* dst = ei + E;

    char* ws = (char*)d_ws;
    size_t off = 0;
    auto take = [&](size_t bytes) -> void* {
        void* p = ws + off;
        off = (off + bytes + 255) & ~(size_t)255;
        return p;
    };
    unsigned short* S   = (unsigned short*)take((size_t)N * 384 * 2);  // hop slots 1..3 (stride 384)
    unsigned short* Qa  = (unsigned short*)take((size_t)N * 128 * 2);
    unsigned short* Qb  = (unsigned short*)take((size_t)N * 128 * 2);
    unsigned short* H0  = (unsigned short*)take((size_t)N * 16 * 2);  // layer-0 compact hops
    unsigned short* H1  = (unsigned short*)take((size_t)N * 16 * 2);
    unsigned short* H2  = (unsigned short*)take((size_t)N * 16 * 2);
    unsigned short* H3  = (unsigned short*)take((size_t)N * 16 * 2);
    unsigned int*  csr  = (unsigned int*) take((size_t)E * 4);        // packed (src<<15)|bf16w15
    unsigned long long* dc = (unsigned long long*)take((size_t)N * 8);
    unsigned short* rank = (unsigned short*)take((size_t)E * 2);
    float* dis     = (float*)take((size_t)N * 4);
    int*   row_ptr = (int*)  take((size_t)(N + 1) * 4);
    int*   bsum    = (int*)  take(1024);
    int*   boff    = (int*)  take(1024);
    float* Z       = (float*)take((size_t)N * 16 * 4);   // 4 planes of N x 4
    float* T1      = (float*)take((size_t)N * 4 * 4);
    float* T2      = (float*)take((size_t)N * 4 * 4);
    unsigned short* Wt0 = (unsigned short*)take(64 * 128 * 2);
    unsigned short* Wt1 = (unsigned short*)take(512 * 128 * 2);
    unsigned short* Wt2 = (unsigned short*)take(512 * 128 * 2);
    unsigned short* Wz  = (unsigned short*)take(16 * 128 * 2);

    // ---- build norm + CSR (one packed atomic pass, atomic-free fill) ----
    hipMemsetAsync(dc, 0, (size_t)N * 8, stream);
    k_edge_deg<<<2048, 256, 0, stream>>>(dst, ew, dc, rank, E);
    int nsb = (N + 1023) / 1024;
    k_scan1<<<nsb, 256, 0, stream>>>(dc, bsum, dis, N);
    k_scan2<<<1, 64, 0, stream>>>(bsum, boff, nsb, &row_ptr[N]);
    k_scan3<<<nsb, 256, 0, stream>>>(dc, boff, row_ptr, N);
    k_fill_csr<<<2048, 256, 0, stream>>>(src, dst, ew, dis, row_ptr, rank, csr, E);

    // ---- weight prep (one kernel) ----
    k_wprep_all<<<(141312 + 255) / 256, 256, 0, stream>>>(W0, W1, W2, W3, Wt0, Wt1, Wt2, Wz);

    int gmfma = (N + 127) / 128;
    int gpw   = (N + 3) / 4;      // one node per wave, 4 waves/block
    size_t N4 = (size_t)N * 4;

    // ---- layer 0: 16 -> 128 (compact bf16 hop chain H0..H3) ----
    k_xcast<<<(N * 2 + 255) / 256, 256, 0, stream>>>(x, H0, N * 2);
    k_prop16b<<<gpw, 256, 0, stream>>>(H0, H1, row_ptr, csr, N);
    k_prop16b<<<gpw, 256, 0, stream>>>(H1, H2, row_ptr, csr, N);
    k_prop16b<<<gpw, 256, 0, stream>>>(H2, H3, row_ptr, csr, N);
    k_mfma_gemm<true, false><<<gmfma, 256, 0, stream>>>(H0, 16, H1, 16, H2, 16, H3, 16,
                                                        64, Wt0, b0, Qa, nullptr, nullptr, N);

    // ---- layer 1: 128 -> 128 ----
    k_prop128b<<<gpw, 256, 0, stream>>>(Qa, 128,      S + 0,   384, row_ptr, csr, N);
    k_prop128b<<<gpw, 256, 0, stream>>>(S + 0, 384,   S + 128, 384, row_ptr, csr, N);
    k_prop128b<<<gpw, 256, 0, stream>>>(S + 128, 384, S + 256, 384, row_ptr, csr, N);
    k_mfma_gemm<false, false><<<gmfma, 256, 0, stream>>>(Qa, 128, S + 0, 384, S + 128, 384, S + 256, 384,
                                                         512, Wt1, b1, Qb, nullptr, nullptr, N);

    // ---- layer 2: 128 -> 128, Z fused into epilogue ----
    k_prop128b<<<gpw, 256, 0, stream>>>(Qb, 128,      S + 0,   384, row_ptr, csr, N);
    k_prop128b<<<gpw, 256, 0, stream>>>(S + 0, 384,   S + 128, 384, row_ptr, csr, N);
    k_prop128b<<<gpw, 256, 0, stream>>>(S + 128, 384, S + 256, 384, row_ptr, csr, N);
    k_mfma_gemm<false, true><<<gmfma, 256, 0, stream>>>(Qb, 128, S + 0, 384, S + 128, 384, S + 256, 384,
                                                        512, Wt2, b2, nullptr, Wz, Z, N);

    // ---- layer 3: 128 -> 4 via projected Horner on Z planes ----
    {
        int g = (N + 15) / 16;
        k_prop4_add<<<g, 256, 0, stream>>>(Z + 3 * N4, Z + 2 * N4, nullptr, T1, row_ptr, csr, N);
        k_prop4_add<<<g, 256, 0, stream>>>(T1,         Z + 1 * N4, nullptr, T2, row_ptr, csr, N);
        k_prop4_add<<<g, 256, 0, stream>>>(T2,         Z + 0 * N4, b3,      out, row_ptr, csr, N);
    }
}